// Round 4
// baseline (1592.514 us; speedup 1.0000x reference)
//
#include <hip/hip_runtime.h>
#include <math.h>

#define N_ENT 100000
#define N_USR 50000
#define N_TOT 150000
#define DD 64

#define SCAN_BLK 256
#define SCAN_ITEMS 1024   // elements per scan block

// ---------------------------------------------------------------------------
// Per-relation precompute: u_r = Wk_w[0:64]@r, v_r = Wk_w[64:128]@r, c_r = b@r
// uvr layout: [16][132]: u at 0..63, v at 64..127, c at 128
// ---------------------------------------------------------------------------
__global__ void k_rel(const float* __restrict__ Wk_w, const float* __restrict__ Wk_b,
                      const float* __restrict__ rel, float* __restrict__ uvr) {
    int r = blockIdx.x;   // 16 blocks
    int k = threadIdx.x;  // 128 threads
    const float* rv = rel + r * DD;
    const float* wrow = Wk_w + k * DD;
    float s = 0.f;
    for (int j = 0; j < DD; ++j) s += wrow[j] * rv[j];
    uvr[r * 132 + k] = s;
    if (k == 0) {
        float c = 0.f;
        for (int j = 0; j < DD; ++j) c += Wk_b[j] * rv[j];
        uvr[r * 132 + 128] = c;
    }
}

// ---------------------------------------------------------------------------
// Per-entity projections: Puv[n][r]      = embed[n] . u_r   (r = 0..15)
//                         Puv[n][16 + r] = embed[n] . v_r
// 8 rows per 256-thread block; 32 threads per row (r = sub&15, w = sub>>4).
// ---------------------------------------------------------------------------
__global__ __launch_bounds__(256) void k_proj(const float* __restrict__ embed,
        const float* __restrict__ uvr, float* __restrict__ Puv) {
    __shared__ float suvr[16 * 128];
    for (int i = threadIdx.x; i < 16 * 128; i += 256)
        suvr[i] = uvr[(i >> 7) * 132 + (i & 127)];
    __syncthreads();
    int rowi = threadIdx.x >> 5;
    int sub = threadIdx.x & 31;
    int r = sub & 15, w = sub >> 4;
    int row = blockIdx.x * 8 + rowi;
    if (row >= N_ENT) return;
    const float* er = embed + (size_t)row * DD;
    const float* uv = suvr + r * 128 + w * 64;
    float s = 0.f;
    for (int d = 0; d < DD; ++d) s = fmaf(er[d], uv[d], s);
    Puv[(size_t)row * 32 + sub] = s;
}

// histogram of row indices
__global__ void k_hist(const int* __restrict__ rows, int* __restrict__ cnt, int E) {
    int e = blockIdx.x * blockDim.x + threadIdx.x;
    if (e < E) atomicAdd(cnt + rows[e], 1);
}

// --- multi-block exclusive scan, phase 1: per-chunk partial sums ---
__global__ __launch_bounds__(SCAN_BLK) void k_blocksum(const int* __restrict__ cnt,
                                                       int* __restrict__ bsum, int n) {
    __shared__ int s[SCAN_BLK];
    int base = blockIdx.x * SCAN_ITEMS;
    int sum = 0;
    for (int i = threadIdx.x; i < SCAN_ITEMS; i += SCAN_BLK) {
        int idx = base + i;
        if (idx < n) sum += cnt[idx];
    }
    s[threadIdx.x] = sum;
    __syncthreads();
    for (int off = SCAN_BLK / 2; off; off >>= 1) {
        if (threadIdx.x < off) s[threadIdx.x] += s[threadIdx.x + off];
        __syncthreads();
    }
    if (threadIdx.x == 0) bsum[blockIdx.x] = s[0];
}

// --- phase 2: single-block exclusive scan of partials (nb <= 1024) ---
__global__ __launch_bounds__(1024) void k_bscan(int* __restrict__ bsum, int nb,
                                                int* __restrict__ total_out) {
    __shared__ int s[1024];
    int tid = threadIdx.x;
    int v = (tid < nb) ? bsum[tid] : 0;
    s[tid] = v;
    __syncthreads();
    for (int off = 1; off < 1024; off <<= 1) {
        int t = (tid >= off) ? s[tid - off] : 0;
        __syncthreads();
        s[tid] += t;
        __syncthreads();
    }
    if (tid < nb) bsum[tid] = s[tid] - v;   // exclusive
    if (tid == 1023) *total_out = s[1023];
}

// --- phase 3: block-local scan + offset; writes rowptr and scatter cursor ---
__global__ __launch_bounds__(SCAN_BLK) void k_scan_apply(int* __restrict__ cnt,
        int* __restrict__ rowptr, const int* __restrict__ bsum, int n) {
    __shared__ int s[SCAN_BLK];
    int base = blockIdx.x * SCAN_ITEMS;
    int t = threadIdx.x;
    int idx0 = base + t * 4;
    int v[4];
    int lsum = 0;
#pragma unroll
    for (int k = 0; k < 4; ++k) {
        int idx = idx0 + k;
        v[k] = (idx < n) ? cnt[idx] : 0;
        lsum += v[k];
    }
    s[t] = lsum;
    __syncthreads();
    for (int off = 1; off < SCAN_BLK; off <<= 1) {
        int tv = (t >= off) ? s[t - off] : 0;
        __syncthreads();
        s[t] += tv;
        __syncthreads();
    }
    int pre = (t ? s[t - 1] : 0) + bsum[blockIdx.x];
#pragma unroll
    for (int k = 0; k < 4; ++k) {
        int idx = idx0 + k;
        if (idx < n) { rowptr[idx] = pre; cnt[idx] = pre; }
        pre += v[k];
    }
}

// ---------------------------------------------------------------------------
// Edge logits via Puv (8B gathered per edge); scatter (col, exp) into CSR slot.
// ---------------------------------------------------------------------------
__global__ void k_edge2(const int* __restrict__ kg_h, const int* __restrict__ kg_t,
                        const int* __restrict__ kg_r, const float* __restrict__ Puv,
                        const float* __restrict__ uvr, int* __restrict__ next,
                        int* __restrict__ ecol, float* __restrict__ eval, int E) {
    int e = blockIdx.x * blockDim.x + threadIdx.x;
    if (e >= E) return;
    int h = kg_h[e], t = kg_t[e], r = kg_r[e];
    float lg = Puv[(size_t)t * 32 + r] + Puv[(size_t)h * 32 + 16 + r] + uvr[r * 132 + 128];
    lg = lg >= 0.f ? lg : 0.01f * lg;
    // softmax is shift-invariant; |logit| << 1 so skip segment-max
    float exv = expf(lg);
    int pos = atomicAdd(next + h, 1);
    ecol[pos] = t;
    eval[pos] = exv;
}

// wave per row: normalize eval segment to sum 1 (segment softmax denominator)
__global__ __launch_bounds__(256) void k_rowdiv(const int* __restrict__ rowptr,
                                                float* __restrict__ eval, int n) {
    int wid = (blockIdx.x * blockDim.x + threadIdx.x) >> 6;
    int lane = threadIdx.x & 63;
    if (wid >= n) return;
    int s = rowptr[wid], e = rowptr[wid + 1];
    float sum = 0.f;
    for (int i = s + lane; i < e; i += 64) sum += eval[i];
    for (int off = 32; off; off >>= 1) sum += __shfl_xor(sum, off);
    if (e > s) {
        float inv = 1.f / sum;
        for (int i = s + lane; i < e; i += 64) eval[i] *= inv;
    }
}

// CF edge scatter: 1 thread per edge
__global__ void k_scatter(const int* __restrict__ rows, const int* __restrict__ cols,
                          const float* __restrict__ vals, int* __restrict__ next,
                          int* __restrict__ ecol, float* __restrict__ eval, int E) {
    int e = blockIdx.x * blockDim.x + threadIdx.x;
    if (e >= E) return;
    int r = rows[e];
    int pos = atomicAdd(next + r, 1);
    ecol[pos] = cols[e];
    eval[pos] = vals[e];
}

// ---------------------------------------------------------------------------
// Combined KG+CF CSR SpMM, wave per row, lane = dim, fp16 gather tables.
// rows [0,N_ENT): KG -> kg32 + kg16 ; rows [N_ENT,N_ENT+N_TOT): CF -> ig32
// ---------------------------------------------------------------------------
__global__ __launch_bounds__(256) void k_spmm_dual(
        const int* __restrict__ kg_rowptr, const int* __restrict__ kg_ecol,
        const float* __restrict__ kg_eval, const _Float16* __restrict__ cur16,
        float* __restrict__ kg32, _Float16* __restrict__ kg16o,
        const int* __restrict__ cf_rowptr, const int* __restrict__ cf_ecol,
        const float* __restrict__ cf_eval, const _Float16* __restrict__ dual16,
        float* __restrict__ ig32) {
    int wid = (blockIdx.x * blockDim.x + threadIdx.x) >> 6;
    int lane = threadIdx.x & 63;
    const int* rowptr; const int* ecol; const float* eval; const _Float16* x;
    int row;
    bool is_kg = wid < N_ENT;
    if (is_kg) { rowptr = kg_rowptr; ecol = kg_ecol; eval = kg_eval; x = cur16; row = wid; }
    else if (wid < N_ENT + N_TOT) {
        rowptr = cf_rowptr; ecol = cf_ecol; eval = cf_eval; x = dual16; row = wid - N_ENT;
    } else return;
    int s = rowptr[row], e = rowptr[row + 1];
    float a0 = 0.f, a1 = 0.f, a2 = 0.f, a3 = 0.f;
    int i = s;
    for (; i + 4 <= e; i += 4) {
        int c0 = ecol[i], c1 = ecol[i + 1], c2 = ecol[i + 2], c3 = ecol[i + 3];
        float w0 = eval[i], w1 = eval[i + 1], w2 = eval[i + 2], w3 = eval[i + 3];
        a0 = fmaf(w0, (float)x[(size_t)c0 * DD + lane], a0);
        a1 = fmaf(w1, (float)x[(size_t)c1 * DD + lane], a1);
        a2 = fmaf(w2, (float)x[(size_t)c2 * DD + lane], a2);
        a3 = fmaf(w3, (float)x[(size_t)c3 * DD + lane], a3);
    }
    for (; i < e; ++i)
        a0 = fmaf(eval[i], (float)x[(size_t)ecol[i] * DD + lane], a0);
    float res = (a0 + a1) + (a2 + a3);
    if (is_kg) {
        kg32[(size_t)row * DD + lane] = res;
        kg16o[(size_t)row * DD + lane] = (_Float16)res;
    } else {
        ig32[(size_t)row * DD + lane] = res;
    }
}

// ---------------------------------------------------------------------------
// Gate (entities) + user passthrough, wave per row. dual16 is the next-layer
// CF gather table (fp16); all math and sums stay fp32.
// ---------------------------------------------------------------------------
__global__ __launch_bounds__(256) void k_gate(const float* __restrict__ kg32,
        const float* __restrict__ ig32, const float* __restrict__ Wa,
        const float* __restrict__ Wb, _Float16* __restrict__ dual16,
        float* __restrict__ sums) {
    __shared__ float sW[2 * DD * DD];
    for (int i = threadIdx.x; i < DD * DD; i += 256) {
        sW[i] = Wa[i];
        sW[DD * DD + i] = Wb[i];
    }
    __syncthreads();
    int lane = threadIdx.x & 63;
    int wslot = (blockIdx.x * 256 + threadIdx.x) >> 6;
    int nw = (gridDim.x * 256) >> 6;
    for (int row = wslot; row < N_TOT; row += nw) {
        float cv = ig32[(size_t)row * DD + lane];
        float dv;
        if (row < N_ENT) {
            float kv = kg32[(size_t)row * DD + lane];
            float a = 0.f, b = 0.f;
            for (int k = 0; k < DD; ++k) {
                float kk = __shfl(kv, k);
                float ck = __shfl(cv, k);
                a = fmaf(kk, sW[k * DD + lane], a);
                b = fmaf(ck, sW[DD * DD + k * DD + lane], b);
            }
            float g = 1.f / (1.f + expf(-(a + b)));
            dv = g * kv + (1.f - g) * cv;
        } else {
            dv = cv;
        }
        dual16[(size_t)row * DD + lane] = (_Float16)dv;
        sums[(size_t)row * DD + lane] += cv;
    }
}

// init: sums = embed (fp32), dual16 = fp16(embed)
__global__ void k_init(const float* __restrict__ embed, float* __restrict__ sums,
                       _Float16* __restrict__ dual16) {
    int i = blockIdx.x * blockDim.x + threadIdx.x;
    if (i >= N_TOT * DD) return;
    float v = embed[i];
    sums[i] = v;
    dual16[i] = (_Float16)v;
}

// out[u,j] = sums[user_ids[u]] . sums[item_ids[j]]
// 256 blocks: 128 user-groups (8 users) x 2 item-halves (1024 items)
__global__ __launch_bounds__(256) void k_out(const float* __restrict__ sums,
        const int* __restrict__ user_ids, const int* __restrict__ item_ids,
        float* __restrict__ out) {
    __shared__ float uvec[8 * DD];
    int ub = (blockIdx.x >> 1) * 8;
    int jbase = (blockIdx.x & 1) * 1024;
    for (int i = threadIdx.x; i < 8 * DD; i += blockDim.x) {
        int uu = i >> 6, d = i & 63;
        uvec[i] = sums[(size_t)user_ids[ub + uu] * DD + d];
    }
    __syncthreads();
    for (int j = threadIdx.x; j < 1024; j += blockDim.x) {
        const float* irow = sums + (size_t)item_ids[jbase + j] * DD;
        float acc[8] = {0.f, 0.f, 0.f, 0.f, 0.f, 0.f, 0.f, 0.f};
        for (int d = 0; d < DD; d += 4) {
            float4 iv = *(const float4*)(irow + d);
#pragma unroll
            for (int u = 0; u < 8; ++u) {
                acc[u] = fmaf(iv.x, uvec[u * DD + d + 0], acc[u]);
                acc[u] = fmaf(iv.y, uvec[u * DD + d + 1], acc[u]);
                acc[u] = fmaf(iv.z, uvec[u * DD + d + 2], acc[u]);
                acc[u] = fmaf(iv.w, uvec[u * DD + d + 3], acc[u]);
            }
        }
#pragma unroll
        for (int u = 0; u < 8; ++u)
            out[(size_t)(ub + u) * 2048 + jbase + j] = acc[u];
    }
}

extern "C" void kernel_launch(void* const* d_in, const int* in_sizes, int n_in,
                              void* d_out, int out_size, void* d_ws, size_t ws_size,
                              hipStream_t stream) {
    const float* embed   = (const float*)d_in[0];
    const float* rel     = (const float*)d_in[1];
    const float* Wk_w    = (const float*)d_in[2];
    const float* Wk_b    = (const float*)d_in[3];
    const float* Wa      = (const float*)d_in[4];
    const float* Wb      = (const float*)d_in[5];
    const int*   kg_h    = (const int*)d_in[6];
    const int*   kg_t    = (const int*)d_in[7];
    const int*   kg_r    = (const int*)d_in[8];
    const int*   ain_row = (const int*)d_in[9];
    const int*   ain_col = (const int*)d_in[10];
    const float* ain_val = (const float*)d_in[11];
    const int*   user_ids = (const int*)d_in[12];
    const int*   item_ids = (const int*)d_in[13];
    int E_KG = in_sizes[6];
    int E_CF = in_sizes[9];
    float* out = (float*)d_out;

    float* ws = (float*)d_ws;
    size_t off = 0;
    float* uvr       = ws + off; off += 16 * 132;
    float* Puv       = ws + off; off += (size_t)N_ENT * 32;
    int*   kg_cnt    = (int*)(ws + off); off += N_ENT;       // hist -> scatter cursor
    int*   cf_cnt    = (int*)(ws + off); off += N_TOT;       // adjacent: one memset
    int*   kg_rowptr = (int*)(ws + off); off += N_ENT + 4;
    int*   cf_rowptr = (int*)(ws + off); off += N_TOT + 4;
    int*   kg_bsum   = (int*)(ws + off); off += 1024;
    int*   cf_bsum   = (int*)(ws + off); off += 1024;
    int*   kg_ecol   = (int*)(ws + off); off += (size_t)E_KG;
    float* kg_eval   = ws + off; off += (size_t)E_KG;
    int*   cf_ecol   = (int*)(ws + off); off += (size_t)E_CF;
    float* cf_eval   = ws + off; off += (size_t)E_CF;
    float* kg32      = ws + off; off += (size_t)N_ENT * DD;
    float* ig32      = ws + off; off += (size_t)N_TOT * DD;
    float* sums      = ws + off; off += (size_t)N_TOT * DD;
    _Float16* dual16 = (_Float16*)(ws + off); off += (size_t)N_TOT * DD / 2;
    _Float16* kg16A  = (_Float16*)(ws + off); off += (size_t)N_ENT * DD / 2;
    _Float16* kg16B  = (_Float16*)(ws + off); off += (size_t)N_ENT * DD / 2;

    int kg_nb = (N_ENT + SCAN_ITEMS - 1) / SCAN_ITEMS;   // 98
    int cf_nb = (N_TOT + SCAN_ITEMS - 1) / SCAN_ITEMS;   // 147

    // --- CSR build for both graphs ---
    hipMemsetAsync(kg_cnt, 0, (size_t)(N_ENT + N_TOT) * sizeof(int), stream);
    hipLaunchKernelGGL(k_hist, dim3((E_KG + 255) / 256), dim3(256), 0, stream, kg_h, kg_cnt, E_KG);
    hipLaunchKernelGGL(k_hist, dim3((E_CF + 255) / 256), dim3(256), 0, stream, ain_row, cf_cnt, E_CF);
    hipLaunchKernelGGL(k_blocksum, dim3(kg_nb), dim3(SCAN_BLK), 0, stream, kg_cnt, kg_bsum, N_ENT);
    hipLaunchKernelGGL(k_bscan, dim3(1), dim3(1024), 0, stream, kg_bsum, kg_nb, kg_rowptr + N_ENT);
    hipLaunchKernelGGL(k_scan_apply, dim3(kg_nb), dim3(SCAN_BLK), 0, stream, kg_cnt, kg_rowptr, kg_bsum, N_ENT);
    hipLaunchKernelGGL(k_blocksum, dim3(cf_nb), dim3(SCAN_BLK), 0, stream, cf_cnt, cf_bsum, N_TOT);
    hipLaunchKernelGGL(k_bscan, dim3(1), dim3(1024), 0, stream, cf_bsum, cf_nb, cf_rowptr + N_TOT);
    hipLaunchKernelGGL(k_scan_apply, dim3(cf_nb), dim3(SCAN_BLK), 0, stream, cf_cnt, cf_rowptr, cf_bsum, N_TOT);
    hipLaunchKernelGGL(k_scatter, dim3((E_CF + 255) / 256), dim3(256), 0, stream,
                       ain_row, ain_col, ain_val, cf_cnt, cf_ecol, cf_eval, E_CF);

    // --- attention: rel precompute -> per-entity projections -> per-edge ---
    hipLaunchKernelGGL(k_rel, dim3(16), dim3(128), 0, stream, Wk_w, Wk_b, rel, uvr);
    hipLaunchKernelGGL(k_proj, dim3((N_ENT + 7) / 8), dim3(256), 0, stream, embed, uvr, Puv);
    hipLaunchKernelGGL(k_edge2, dim3((E_KG + 255) / 256), dim3(256), 0, stream,
                       kg_h, kg_t, kg_r, Puv, uvr, kg_cnt, kg_ecol, kg_eval, E_KG);
    hipLaunchKernelGGL(k_rowdiv, dim3((N_ENT * 64 + 255) / 256), dim3(256), 0, stream,
                       kg_rowptr, kg_eval, N_ENT);
    hipLaunchKernelGGL(k_init, dim3((N_TOT * DD + 255) / 256), dim3(256), 0, stream,
                       embed, sums, dual16);

    // --- 3 propagation layers; layer0 KG gather table = dual16 (== fp16 embed) ---
    const _Float16* cur16 = dual16;
    _Float16* kg16o = kg16A;
    _Float16* kg16alt = kg16B;
    int spmm_waves = N_ENT + N_TOT;
    int spmm_blocks = (spmm_waves * 64 + 255) / 256;
    for (int layer = 0; layer < 3; ++layer) {
        hipLaunchKernelGGL(k_spmm_dual, dim3(spmm_blocks), dim3(256), 0, stream,
                           kg_rowptr, kg_ecol, kg_eval, cur16, kg32, kg16o,
                           cf_rowptr, cf_ecol, cf_eval, dual16, ig32);
        hipLaunchKernelGGL(k_gate, dim3(2048), dim3(256), 0, stream,
                           kg32, ig32, Wa, Wb, dual16, sums);
        cur16 = kg16o;
        kg16o = kg16alt;
        kg16alt = (_Float16*)cur16;
    }

    // --- final gather-GEMM 1024 x 2048 x 64 ---
    hipLaunchKernelGGL(k_out, dim3(256), dim3(256), 0, stream, sums, user_ids, item_ids, out);
}

// Round 5
// 1493.761 us; speedup vs baseline: 1.0661x; 1.0661x over previous
//
#include <hip/hip_runtime.h>
#include <math.h>

#define N_ENT 100000
#define N_USR 50000
#define N_TOT 150000
#define DD 64

#define SCAN_BLK 256
#define SCAN_ITEMS 1024   // elements per scan block

// ---------------------------------------------------------------------------
// Per-relation precompute: u_r = Wk_w[0:64]@r, v_r = Wk_w[64:128]@r, c_r = b@r
// uvr layout: [16][132]: u at 0..63, v at 64..127, c at 128
// ---------------------------------------------------------------------------
__global__ void k_rel(const float* __restrict__ Wk_w, const float* __restrict__ Wk_b,
                      const float* __restrict__ rel, float* __restrict__ uvr) {
    int r = blockIdx.x;   // 16 blocks
    int k = threadIdx.x;  // 128 threads
    const float* rv = rel + r * DD;
    const float* wrow = Wk_w + k * DD;
    float s = 0.f;
    for (int j = 0; j < DD; ++j) s += wrow[j] * rv[j];
    uvr[r * 132 + k] = s;
    if (k == 0) {
        float c = 0.f;
        for (int j = 0; j < DD; ++j) c += Wk_b[j] * rv[j];
        uvr[r * 132 + 128] = c;
    }
}

// ---------------------------------------------------------------------------
// Per-entity projections: Puv[n][r]      = embed[n] . u_r   (r = 0..15)
//                         Puv[n][16 + r] = embed[n] . v_r
// ---------------------------------------------------------------------------
__global__ __launch_bounds__(256) void k_proj(const float* __restrict__ embed,
        const float* __restrict__ uvr, float* __restrict__ Puv) {
    __shared__ float suvr[16 * 128];
    for (int i = threadIdx.x; i < 16 * 128; i += 256)
        suvr[i] = uvr[(i >> 7) * 132 + (i & 127)];
    __syncthreads();
    int rowi = threadIdx.x >> 5;
    int sub = threadIdx.x & 31;
    int r = sub & 15, w = sub >> 4;
    int row = blockIdx.x * 8 + rowi;
    if (row >= N_ENT) return;
    const float* er = embed + (size_t)row * DD;
    const float* uv = suvr + r * 128 + w * 64;
    float s = 0.f;
    for (int d = 0; d < DD; ++d) s = fmaf(er[d], uv[d], s);
    Puv[(size_t)row * 32 + sub] = s;
}

// histogram of row indices
__global__ void k_hist(const int* __restrict__ rows, int* __restrict__ cnt, int E) {
    int e = blockIdx.x * blockDim.x + threadIdx.x;
    if (e < E) atomicAdd(cnt + rows[e], 1);
}

// --- multi-block exclusive scan, phase 1: per-chunk partial sums ---
__global__ __launch_bounds__(SCAN_BLK) void k_blocksum(const int* __restrict__ cnt,
                                                       int* __restrict__ bsum, int n) {
    __shared__ int s[SCAN_BLK];
    int base = blockIdx.x * SCAN_ITEMS;
    int sum = 0;
    for (int i = threadIdx.x; i < SCAN_ITEMS; i += SCAN_BLK) {
        int idx = base + i;
        if (idx < n) sum += cnt[idx];
    }
    s[threadIdx.x] = sum;
    __syncthreads();
    for (int off = SCAN_BLK / 2; off; off >>= 1) {
        if (threadIdx.x < off) s[threadIdx.x] += s[threadIdx.x + off];
        __syncthreads();
    }
    if (threadIdx.x == 0) bsum[blockIdx.x] = s[0];
}

// --- phase 2: single-block exclusive scan of partials (nb <= 1024) ---
__global__ __launch_bounds__(1024) void k_bscan(int* __restrict__ bsum, int nb,
                                                int* __restrict__ total_out) {
    __shared__ int s[1024];
    int tid = threadIdx.x;
    int v = (tid < nb) ? bsum[tid] : 0;
    s[tid] = v;
    __syncthreads();
    for (int off = 1; off < 1024; off <<= 1) {
        int t = (tid >= off) ? s[tid - off] : 0;
        __syncthreads();
        s[tid] += t;
        __syncthreads();
    }
    if (tid < nb) bsum[tid] = s[tid] - v;   // exclusive
    if (tid == 1023) *total_out = s[1023];
}

// --- phase 3: block-local scan + offset; writes rowptr and scatter cursor ---
__global__ __launch_bounds__(SCAN_BLK) void k_scan_apply(int* __restrict__ cnt,
        int* __restrict__ rowptr, const int* __restrict__ bsum, int n) {
    __shared__ int s[SCAN_BLK];
    int base = blockIdx.x * SCAN_ITEMS;
    int t = threadIdx.x;
    int idx0 = base + t * 4;
    int v[4];
    int lsum = 0;
#pragma unroll
    for (int k = 0; k < 4; ++k) {
        int idx = idx0 + k;
        v[k] = (idx < n) ? cnt[idx] : 0;
        lsum += v[k];
    }
    s[t] = lsum;
    __syncthreads();
    for (int off = 1; off < SCAN_BLK; off <<= 1) {
        int tv = (t >= off) ? s[t - off] : 0;
        __syncthreads();
        s[t] += tv;
        __syncthreads();
    }
    int pre = (t ? s[t - 1] : 0) + bsum[blockIdx.x];
#pragma unroll
    for (int k = 0; k < 4; ++k) {
        int idx = idx0 + k;
        if (idx < n) { rowptr[idx] = pre; cnt[idx] = pre; }
        pre += v[k];
    }
}

// ---------------------------------------------------------------------------
// Edge logits via Puv (8B gathered per edge); scatter (col, exp) into CSR slot.
// ---------------------------------------------------------------------------
__global__ void k_edge2(const int* __restrict__ kg_h, const int* __restrict__ kg_t,
                        const int* __restrict__ kg_r, const float* __restrict__ Puv,
                        const float* __restrict__ uvr, int* __restrict__ next,
                        int* __restrict__ ecol, float* __restrict__ eval, int E) {
    int e = blockIdx.x * blockDim.x + threadIdx.x;
    if (e >= E) return;
    int h = kg_h[e], t = kg_t[e], r = kg_r[e];
    float lg = Puv[(size_t)t * 32 + r] + Puv[(size_t)h * 32 + 16 + r] + uvr[r * 132 + 128];
    lg = lg >= 0.f ? lg : 0.01f * lg;
    // softmax is shift-invariant; |logit| << 1 so skip segment-max
    float exv = expf(lg);
    int pos = atomicAdd(next + h, 1);
    ecol[pos] = t;
    eval[pos] = exv;
}

// wave per row: normalize eval segment to sum 1 (segment softmax denominator)
__global__ __launch_bounds__(256) void k_rowdiv(const int* __restrict__ rowptr,
                                                float* __restrict__ eval, int n) {
    int wid = (blockIdx.x * blockDim.x + threadIdx.x) >> 6;
    int lane = threadIdx.x & 63;
    if (wid >= n) return;
    int s = rowptr[wid], e = rowptr[wid + 1];
    float sum = 0.f;
    for (int i = s + lane; i < e; i += 64) sum += eval[i];
    for (int off = 32; off; off >>= 1) sum += __shfl_xor(sum, off);
    if (e > s) {
        float inv = 1.f / sum;
        for (int i = s + lane; i < e; i += 64) eval[i] *= inv;
    }
}

// CF edge scatter: 1 thread per edge
__global__ void k_scatter(const int* __restrict__ rows, const int* __restrict__ cols,
                          const float* __restrict__ vals, int* __restrict__ next,
                          int* __restrict__ ecol, float* __restrict__ eval, int E) {
    int e = blockIdx.x * blockDim.x + threadIdx.x;
    if (e >= E) return;
    int r = rows[e];
    int pos = atomicAdd(next + r, 1);
    ecol[pos] = cols[e];
    eval[pos] = vals[e];
}

// ---------------------------------------------------------------------------
// Combined KG+CF CSR SpMM, wave per row, lane = dim, fp16 gather tables.
// Row id forced wave-uniform so rowptr/ecol/eval go down the scalar path;
// only the row gather stays on the vector-memory pipe.
// ---------------------------------------------------------------------------
__global__ __launch_bounds__(256) void k_spmm_dual(
        const int* __restrict__ kg_rowptr, const int* __restrict__ kg_ecol,
        const float* __restrict__ kg_eval, const _Float16* __restrict__ cur16,
        float* __restrict__ kg32, _Float16* __restrict__ kg16o,
        const int* __restrict__ cf_rowptr, const int* __restrict__ cf_ecol,
        const float* __restrict__ cf_eval, const _Float16* __restrict__ dual16,
        float* __restrict__ ig32) {
    int wid0 = (blockIdx.x * blockDim.x + threadIdx.x) >> 6;
    int wid = __builtin_amdgcn_readfirstlane(wid0);
    int lane = threadIdx.x & 63;
    const int* rowptr; const int* ecol; const float* eval; const _Float16* x;
    int row;
    bool is_kg = wid < N_ENT;
    if (is_kg) { rowptr = kg_rowptr; ecol = kg_ecol; eval = kg_eval; x = cur16; row = wid; }
    else if (wid < N_ENT + N_TOT) {
        rowptr = cf_rowptr; ecol = cf_ecol; eval = cf_eval; x = dual16; row = wid - N_ENT;
    } else return;
    int s = rowptr[row], e = rowptr[row + 1];
    float a0 = 0.f, a1 = 0.f, a2 = 0.f, a3 = 0.f;
    int i = s;
    for (; i + 4 <= e; i += 4) {
        int c0 = ecol[i], c1 = ecol[i + 1], c2 = ecol[i + 2], c3 = ecol[i + 3];
        float w0 = eval[i], w1 = eval[i + 1], w2 = eval[i + 2], w3 = eval[i + 3];
        a0 = fmaf(w0, (float)x[(size_t)c0 * DD + lane], a0);
        a1 = fmaf(w1, (float)x[(size_t)c1 * DD + lane], a1);
        a2 = fmaf(w2, (float)x[(size_t)c2 * DD + lane], a2);
        a3 = fmaf(w3, (float)x[(size_t)c3 * DD + lane], a3);
    }
    for (; i < e; ++i)
        a0 = fmaf(eval[i], (float)x[(size_t)ecol[i] * DD + lane], a0);
    float res = (a0 + a1) + (a2 + a3);
    if (is_kg) {
        kg32[(size_t)row * DD + lane] = res;
        kg16o[(size_t)row * DD + lane] = (_Float16)res;
    } else {
        ig32[(size_t)row * DD + lane] = res;
    }
}

// ---------------------------------------------------------------------------
// Entity gate, restructured: one wave handles a 16-row tile; k-chunks of 8.
// W chunk is read from LDS once per chunk per tile (amortized 16x); the
// wave-uniform row values kv[k], cv[k] come in via the SCALAR path (row id is
// readfirstlane-uniform, so s_load + SGPR operand in v_fma). Per row: 8 LDS
// ops + 128 FMA -> VALU-bound instead of LDS-issue-bound.
// ---------------------------------------------------------------------------
__global__ __launch_bounds__(256) void k_gate2(const float* __restrict__ kg32,
        const float* __restrict__ ig32, const float* __restrict__ Wa,
        const float* __restrict__ Wb, _Float16* __restrict__ dual16,
        float* __restrict__ sums) {
    __shared__ float sW[2 * DD * DD];
    for (int i = threadIdx.x; i < DD * DD; i += 256) {
        sW[i] = Wa[i];
        sW[DD * DD + i] = Wb[i];
    }
    __syncthreads();
    int lane = threadIdx.x & 63;
    int wslot0 = (blockIdx.x * 256 + threadIdx.x) >> 6;
    int w = __builtin_amdgcn_readfirstlane(wslot0);
    int row0 = w * 16;
    if (row0 >= N_ENT) return;
    int nrow = N_ENT - row0; if (nrow > 16) nrow = 16;

    float a[16], b[16];
#pragma unroll
    for (int r = 0; r < 16; ++r) { a[r] = 0.f; b[r] = 0.f; }

    for (int c = 0; c < 8; ++c) {           // k = c*8 .. c*8+7
        float wA[8], wB[8];
#pragma unroll
        for (int j = 0; j < 8; ++j) {
            wA[j] = sW[(c * 8 + j) * DD + lane];
            wB[j] = sW[DD * DD + (c * 8 + j) * DD + lane];
        }
        for (int r = 0; r < nrow; ++r) {
            const float* kp = kg32 + (size_t)(row0 + r) * DD + c * 8;
            const float* ip = ig32 + (size_t)(row0 + r) * DD + c * 8;
#pragma unroll
            for (int j = 0; j < 8; ++j) {
                a[r] = fmaf(kp[j], wA[j], a[r]);   // kp[j]/ip[j] wave-uniform -> s_load
                b[r] = fmaf(ip[j], wB[j], b[r]);
            }
        }
    }
    for (int r = 0; r < nrow; ++r) {
        size_t o = (size_t)(row0 + r) * DD + lane;
        float kv = kg32[o];
        float cv = ig32[o];
        float g = 1.f / (1.f + expf(-(a[r] + b[r])));
        dual16[o] = (_Float16)(g * kv + (1.f - g) * cv);
        sums[o] += cv;
    }
}

// user rows: dual16 <- ig, sums += ig
__global__ void k_user2(const float* __restrict__ ig32, _Float16* __restrict__ dual16,
                        float* __restrict__ sums) {
    int i = blockIdx.x * blockDim.x + threadIdx.x;
    if (i >= N_USR * DD) return;
    size_t o = (size_t)N_ENT * DD + i;
    float v = ig32[o];
    dual16[o] = (_Float16)v;
    sums[o] += v;
}

// init: sums = embed (fp32), dual16 = fp16(embed)
__global__ void k_init(const float* __restrict__ embed, float* __restrict__ sums,
                       _Float16* __restrict__ dual16) {
    int i = blockIdx.x * blockDim.x + threadIdx.x;
    if (i >= N_TOT * DD) return;
    float v = embed[i];
    sums[i] = v;
    dual16[i] = (_Float16)v;
}

// out[u,j] = sums[user_ids[u]] . sums[item_ids[j]]
// 256 blocks: 128 user-groups (8 users) x 2 item-halves (1024 items)
__global__ __launch_bounds__(256) void k_out(const float* __restrict__ sums,
        const int* __restrict__ user_ids, const int* __restrict__ item_ids,
        float* __restrict__ out) {
    __shared__ float uvec[8 * DD];
    int ub = (blockIdx.x >> 1) * 8;
    int jbase = (blockIdx.x & 1) * 1024;
    for (int i = threadIdx.x; i < 8 * DD; i += blockDim.x) {
        int uu = i >> 6, d = i & 63;
        uvec[i] = sums[(size_t)user_ids[ub + uu] * DD + d];
    }
    __syncthreads();
    for (int j = threadIdx.x; j < 1024; j += blockDim.x) {
        const float* irow = sums + (size_t)item_ids[jbase + j] * DD;
        float acc[8] = {0.f, 0.f, 0.f, 0.f, 0.f, 0.f, 0.f, 0.f};
        for (int d = 0; d < DD; d += 4) {
            float4 iv = *(const float4*)(irow + d);
#pragma unroll
            for (int u = 0; u < 8; ++u) {
                acc[u] = fmaf(iv.x, uvec[u * DD + d + 0], acc[u]);
                acc[u] = fmaf(iv.y, uvec[u * DD + d + 1], acc[u]);
                acc[u] = fmaf(iv.z, uvec[u * DD + d + 2], acc[u]);
                acc[u] = fmaf(iv.w, uvec[u * DD + d + 3], acc[u]);
            }
        }
#pragma unroll
        for (int u = 0; u < 8; ++u)
            out[(size_t)(ub + u) * 2048 + jbase + j] = acc[u];
    }
}

extern "C" void kernel_launch(void* const* d_in, const int* in_sizes, int n_in,
                              void* d_out, int out_size, void* d_ws, size_t ws_size,
                              hipStream_t stream) {
    const float* embed   = (const float*)d_in[0];
    const float* rel     = (const float*)d_in[1];
    const float* Wk_w    = (const float*)d_in[2];
    const float* Wk_b    = (const float*)d_in[3];
    const float* Wa      = (const float*)d_in[4];
    const float* Wb      = (const float*)d_in[5];
    const int*   kg_h    = (const int*)d_in[6];
    const int*   kg_t    = (const int*)d_in[7];
    const int*   kg_r    = (const int*)d_in[8];
    const int*   ain_row = (const int*)d_in[9];
    const int*   ain_col = (const int*)d_in[10];
    const float* ain_val = (const float*)d_in[11];
    const int*   user_ids = (const int*)d_in[12];
    const int*   item_ids = (const int*)d_in[13];
    int E_KG = in_sizes[6];
    int E_CF = in_sizes[9];
    float* out = (float*)d_out;

    float* ws = (float*)d_ws;
    size_t off = 0;
    float* uvr       = ws + off; off += 16 * 132;
    float* Puv       = ws + off; off += (size_t)N_ENT * 32;
    int*   kg_cnt    = (int*)(ws + off); off += N_ENT;       // hist -> scatter cursor
    int*   cf_cnt    = (int*)(ws + off); off += N_TOT;       // adjacent: one memset
    int*   kg_rowptr = (int*)(ws + off); off += N_ENT + 4;
    int*   cf_rowptr = (int*)(ws + off); off += N_TOT + 4;
    int*   kg_bsum   = (int*)(ws + off); off += 1024;
    int*   cf_bsum   = (int*)(ws + off); off += 1024;
    int*   kg_ecol   = (int*)(ws + off); off += (size_t)E_KG;
    float* kg_eval   = ws + off; off += (size_t)E_KG;
    int*   cf_ecol   = (int*)(ws + off); off += (size_t)E_CF;
    float* cf_eval   = ws + off; off += (size_t)E_CF;
    float* kg32      = ws + off; off += (size_t)N_ENT * DD;
    float* ig32      = ws + off; off += (size_t)N_TOT * DD;
    float* sums      = ws + off; off += (size_t)N_TOT * DD;
    _Float16* dual16 = (_Float16*)(ws + off); off += (size_t)N_TOT * DD / 2;
    _Float16* kg16A  = (_Float16*)(ws + off); off += (size_t)N_ENT * DD / 2;
    _Float16* kg16B  = (_Float16*)(ws + off); off += (size_t)N_ENT * DD / 2;

    int kg_nb = (N_ENT + SCAN_ITEMS - 1) / SCAN_ITEMS;   // 98
    int cf_nb = (N_TOT + SCAN_ITEMS - 1) / SCAN_ITEMS;   // 147

    // --- CSR build for both graphs ---
    hipMemsetAsync(kg_cnt, 0, (size_t)(N_ENT + N_TOT) * sizeof(int), stream);
    hipLaunchKernelGGL(k_hist, dim3((E_KG + 255) / 256), dim3(256), 0, stream, kg_h, kg_cnt, E_KG);
    hipLaunchKernelGGL(k_hist, dim3((E_CF + 255) / 256), dim3(256), 0, stream, ain_row, cf_cnt, E_CF);
    hipLaunchKernelGGL(k_blocksum, dim3(kg_nb), dim3(SCAN_BLK), 0, stream, kg_cnt, kg_bsum, N_ENT);
    hipLaunchKernelGGL(k_bscan, dim3(1), dim3(1024), 0, stream, kg_bsum, kg_nb, kg_rowptr + N_ENT);
    hipLaunchKernelGGL(k_scan_apply, dim3(kg_nb), dim3(SCAN_BLK), 0, stream, kg_cnt, kg_rowptr, kg_bsum, N_ENT);
    hipLaunchKernelGGL(k_blocksum, dim3(cf_nb), dim3(SCAN_BLK), 0, stream, cf_cnt, cf_bsum, N_TOT);
    hipLaunchKernelGGL(k_bscan, dim3(1), dim3(1024), 0, stream, cf_bsum, cf_nb, cf_rowptr + N_TOT);
    hipLaunchKernelGGL(k_scan_apply, dim3(cf_nb), dim3(SCAN_BLK), 0, stream, cf_cnt, cf_rowptr, cf_bsum, N_TOT);
    hipLaunchKernelGGL(k_scatter, dim3((E_CF + 255) / 256), dim3(256), 0, stream,
                       ain_row, ain_col, ain_val, cf_cnt, cf_ecol, cf_eval, E_CF);

    // --- attention: rel precompute -> per-entity projections -> per-edge ---
    hipLaunchKernelGGL(k_rel, dim3(16), dim3(128), 0, stream, Wk_w, Wk_b, rel, uvr);
    hipLaunchKernelGGL(k_proj, dim3((N_ENT + 7) / 8), dim3(256), 0, stream, embed, uvr, Puv);
    hipLaunchKernelGGL(k_edge2, dim3((E_KG + 255) / 256), dim3(256), 0, stream,
                       kg_h, kg_t, kg_r, Puv, uvr, kg_cnt, kg_ecol, kg_eval, E_KG);
    hipLaunchKernelGGL(k_rowdiv, dim3((N_ENT * 64 + 255) / 256), dim3(256), 0, stream,
                       kg_rowptr, kg_eval, N_ENT);
    hipLaunchKernelGGL(k_init, dim3((N_TOT * DD + 255) / 256), dim3(256), 0, stream,
                       embed, sums, dual16);

    // --- 3 propagation layers; layer0 KG gather table = dual16 (== fp16 embed) ---
    const _Float16* cur16 = dual16;
    _Float16* kg16o = kg16A;
    _Float16* kg16alt = kg16B;
    int spmm_waves = N_ENT + N_TOT;
    int spmm_blocks = (spmm_waves * 64 + 255) / 256;
    int gate_waves = (N_ENT + 15) / 16;                  // 6250
    int gate_blocks = (gate_waves + 3) / 4;              // 4 waves/block
    for (int layer = 0; layer < 3; ++layer) {
        hipLaunchKernelGGL(k_spmm_dual, dim3(spmm_blocks), dim3(256), 0, stream,
                           kg_rowptr, kg_ecol, kg_eval, cur16, kg32, kg16o,
                           cf_rowptr, cf_ecol, cf_eval, dual16, ig32);
        hipLaunchKernelGGL(k_gate2, dim3(gate_blocks), dim3(256), 0, stream,
                           kg32, ig32, Wa, Wb, dual16, sums);
        hipLaunchKernelGGL(k_user2, dim3((N_USR * DD + 255) / 256), dim3(256), 0, stream,
                           ig32, dual16, sums);
        cur16 = kg16o;
        kg16o = kg16alt;
        kg16alt = (_Float16*)cur16;
    }

    // --- final gather-GEMM 1024 x 2048 x 64 ---
    hipLaunchKernelGGL(k_out, dim3(256), dim3(256), 0, stream, sums, user_ids, item_ids, out);
}

// Round 6
// 1090.219 us; speedup vs baseline: 1.4607x; 1.3701x over previous
//
#include <hip/hip_runtime.h>
#include <math.h>

#define N_ENT 100000
#define N_USR 50000
#define N_TOT 150000
#define DD 64

#define SCAN_BLK 256
#define SCAN_ITEMS 1024   // elements per scan block

typedef _Float16 half8 __attribute__((ext_vector_type(8)));
typedef float floatx4 __attribute__((ext_vector_type(4)));

// ---------------------------------------------------------------------------
// Per-relation precompute: u_r = Wk_w[0:64]@r, v_r = Wk_w[64:128]@r, c_r = b@r
// uvr layout: [16][132]: u at 0..63, v at 64..127, c at 128
// ---------------------------------------------------------------------------
__global__ void k_rel(const float* __restrict__ Wk_w, const float* __restrict__ Wk_b,
                      const float* __restrict__ rel, float* __restrict__ uvr) {
    int r = blockIdx.x;   // 16 blocks
    int k = threadIdx.x;  // 128 threads
    const float* rv = rel + r * DD;
    const float* wrow = Wk_w + k * DD;
    float s = 0.f;
    for (int j = 0; j < DD; ++j) s += wrow[j] * rv[j];
    uvr[r * 132 + k] = s;
    if (k == 0) {
        float c = 0.f;
        for (int j = 0; j < DD; ++j) c += Wk_b[j] * rv[j];
        uvr[r * 132 + 128] = c;
    }
}

// ---------------------------------------------------------------------------
// Per-entity projections: Puv[n][r] = embed[n].u_r ; Puv[n][16+r] = embed[n].v_r
// ---------------------------------------------------------------------------
__global__ __launch_bounds__(256) void k_proj(const float* __restrict__ embed,
        const float* __restrict__ uvr, float* __restrict__ Puv) {
    __shared__ float suvr[16 * 128];
    for (int i = threadIdx.x; i < 16 * 128; i += 256)
        suvr[i] = uvr[(i >> 7) * 132 + (i & 127)];
    __syncthreads();
    int rowi = threadIdx.x >> 5;
    int sub = threadIdx.x & 31;
    int r = sub & 15, w = sub >> 4;
    int row = blockIdx.x * 8 + rowi;
    if (row >= N_ENT) return;
    const float* er = embed + (size_t)row * DD;
    const float* uv = suvr + r * 128 + w * 64;
    float s = 0.f;
    for (int d = 0; d < DD; ++d) s = fmaf(er[d], uv[d], s);
    Puv[(size_t)row * 32 + sub] = s;
}

// histogram of row indices
__global__ void k_hist(const int* __restrict__ rows, int* __restrict__ cnt, int E) {
    int e = blockIdx.x * blockDim.x + threadIdx.x;
    if (e < E) atomicAdd(cnt + rows[e], 1);
}

// --- multi-block exclusive scan, phase 1: per-chunk partial sums ---
__global__ __launch_bounds__(SCAN_BLK) void k_blocksum(const int* __restrict__ cnt,
                                                       int* __restrict__ bsum, int n) {
    __shared__ int s[SCAN_BLK];
    int base = blockIdx.x * SCAN_ITEMS;
    int sum = 0;
    for (int i = threadIdx.x; i < SCAN_ITEMS; i += SCAN_BLK) {
        int idx = base + i;
        if (idx < n) sum += cnt[idx];
    }
    s[threadIdx.x] = sum;
    __syncthreads();
    for (int off = SCAN_BLK / 2; off; off >>= 1) {
        if (threadIdx.x < off) s[threadIdx.x] += s[threadIdx.x + off];
        __syncthreads();
    }
    if (threadIdx.x == 0) bsum[blockIdx.x] = s[0];
}

// --- phase 2: single-block exclusive scan of partials (nb <= 1024) ---
__global__ __launch_bounds__(1024) void k_bscan(int* __restrict__ bsum, int nb,
                                                int* __restrict__ total_out) {
    __shared__ int s[1024];
    int tid = threadIdx.x;
    int v = (tid < nb) ? bsum[tid] : 0;
    s[tid] = v;
    __syncthreads();
    for (int off = 1; off < 1024; off <<= 1) {
        int t = (tid >= off) ? s[tid - off] : 0;
        __syncthreads();
        s[tid] += t;
        __syncthreads();
    }
    if (tid < nb) bsum[tid] = s[tid] - v;   // exclusive
    if (tid == 1023) *total_out = s[1023];
}

// --- phase 3: block-local scan + offset; writes rowptr and scatter cursor ---
__global__ __launch_bounds__(SCAN_BLK) void k_scan_apply(int* __restrict__ cnt,
        int* __restrict__ rowptr, const int* __restrict__ bsum, int n) {
    __shared__ int s[SCAN_BLK];
    int base = blockIdx.x * SCAN_ITEMS;
    int t = threadIdx.x;
    int idx0 = base + t * 4;
    int v[4];
    int lsum = 0;
#pragma unroll
    for (int k = 0; k < 4; ++k) {
        int idx = idx0 + k;
        v[k] = (idx < n) ? cnt[idx] : 0;
        lsum += v[k];
    }
    s[t] = lsum;
    __syncthreads();
    for (int off = 1; off < SCAN_BLK; off <<= 1) {
        int tv = (t >= off) ? s[t - off] : 0;
        __syncthreads();
        s[t] += tv;
        __syncthreads();
    }
    int pre = (t ? s[t - 1] : 0) + bsum[blockIdx.x];
#pragma unroll
    for (int k = 0; k < 4; ++k) {
        int idx = idx0 + k;
        if (idx < n) { rowptr[idx] = pre; cnt[idx] = pre; }
        pre += v[k];
    }
}

// ---------------------------------------------------------------------------
// Edge logits via Puv (8B gathered per edge); scatter (col, exp) into CSR slot.
// ---------------------------------------------------------------------------
__global__ void k_edge2(const int* __restrict__ kg_h, const int* __restrict__ kg_t,
                        const int* __restrict__ kg_r, const float* __restrict__ Puv,
                        const float* __restrict__ uvr, int* __restrict__ next,
                        int* __restrict__ ecol, float* __restrict__ eval, int E) {
    int e = blockIdx.x * blockDim.x + threadIdx.x;
    if (e >= E) return;
    int h = kg_h[e], t = kg_t[e], r = kg_r[e];
    float lg = Puv[(size_t)t * 32 + r] + Puv[(size_t)h * 32 + 16 + r] + uvr[r * 132 + 128];
    lg = lg >= 0.f ? lg : 0.01f * lg;
    // softmax is shift-invariant; |logit| << 1 so skip segment-max
    float exv = expf(lg);
    int pos = atomicAdd(next + h, 1);
    ecol[pos] = t;
    eval[pos] = exv;
}

// wave per row: normalize eval segment to sum 1 (segment softmax denominator)
__global__ __launch_bounds__(256) void k_rowdiv(const int* __restrict__ rowptr,
                                                float* __restrict__ eval, int n) {
    int wid = (blockIdx.x * blockDim.x + threadIdx.x) >> 6;
    int lane = threadIdx.x & 63;
    if (wid >= n) return;
    int s = rowptr[wid], e = rowptr[wid + 1];
    float sum = 0.f;
    for (int i = s + lane; i < e; i += 64) sum += eval[i];
    for (int off = 32; off; off >>= 1) sum += __shfl_xor(sum, off);
    if (e > s) {
        float inv = 1.f / sum;
        for (int i = s + lane; i < e; i += 64) eval[i] *= inv;
    }
}

// CF edge scatter: 1 thread per edge
__global__ void k_scatter(const int* __restrict__ rows, const int* __restrict__ cols,
                          const float* __restrict__ vals, int* __restrict__ next,
                          int* __restrict__ ecol, float* __restrict__ eval, int E) {
    int e = blockIdx.x * blockDim.x + threadIdx.x;
    if (e >= E) return;
    int r = rows[e];
    int pos = atomicAdd(next + r, 1);
    ecol[pos] = cols[e];
    eval[pos] = vals[e];
}

// ---------------------------------------------------------------------------
// Pack Wa,Wb into fp16 MFMA B-fragment layout:
// wpack[m][kstep][ntile][lane][j] = W_m[kstep*32 + (lane>>4)*8 + j][ntile*16 + (lane&15)]
// sizes: 2 * 2 * 4 * 64 * 8 = 8192 halves (16 KB)
// ---------------------------------------------------------------------------
__global__ void k_wcvt(const float* __restrict__ Wa, const float* __restrict__ Wb,
                       _Float16* __restrict__ wpack) {
    int i = blockIdx.x * 256 + threadIdx.x;
    if (i >= 8192) return;
    int m = i >> 12;
    int rem = i & 4095;
    int kstep = rem >> 11;
    int rem2 = rem & 2047;
    int ntile = rem2 >> 9;
    int rem3 = rem2 & 511;
    int lane = rem3 >> 3;
    int j = rem3 & 7;
    int k = kstep * 32 + (lane >> 4) * 8 + j;
    int n = ntile * 16 + (lane & 15);
    const float* W = m ? Wb : Wa;
    wpack[i] = (_Float16)W[k * 64 + n];
}

// ---------------------------------------------------------------------------
// Combined KG+CF CSR SpMM, wave per row, lane = dim. fp16 in, fp16 out.
// Row id wave-uniform so CSR meta goes down the scalar path.
// ---------------------------------------------------------------------------
__global__ __launch_bounds__(256) void k_spmm_dual(
        const int* __restrict__ kg_rowptr, const int* __restrict__ kg_ecol,
        const float* __restrict__ kg_eval, const _Float16* __restrict__ cur16,
        _Float16* __restrict__ kg16o,
        const int* __restrict__ cf_rowptr, const int* __restrict__ cf_ecol,
        const float* __restrict__ cf_eval, const _Float16* __restrict__ dual16,
        _Float16* __restrict__ ig16) {
    int wid0 = (blockIdx.x * blockDim.x + threadIdx.x) >> 6;
    int wid = __builtin_amdgcn_readfirstlane(wid0);
    int lane = threadIdx.x & 63;
    const int* rowptr; const int* ecol; const float* eval; const _Float16* x;
    _Float16* o;
    int row;
    bool is_kg = wid < N_ENT;
    if (is_kg) { rowptr = kg_rowptr; ecol = kg_ecol; eval = kg_eval; x = cur16; o = kg16o; row = wid; }
    else if (wid < N_ENT + N_TOT) {
        rowptr = cf_rowptr; ecol = cf_ecol; eval = cf_eval; x = dual16; o = ig16; row = wid - N_ENT;
    } else return;
    int s = rowptr[row], e = rowptr[row + 1];
    float a0 = 0.f, a1 = 0.f, a2 = 0.f, a3 = 0.f;
    int i = s;
    for (; i + 4 <= e; i += 4) {
        int c0 = ecol[i], c1 = ecol[i + 1], c2 = ecol[i + 2], c3 = ecol[i + 3];
        float w0 = eval[i], w1 = eval[i + 1], w2 = eval[i + 2], w3 = eval[i + 3];
        a0 = fmaf(w0, (float)x[(size_t)c0 * DD + lane], a0);
        a1 = fmaf(w1, (float)x[(size_t)c1 * DD + lane], a1);
        a2 = fmaf(w2, (float)x[(size_t)c2 * DD + lane], a2);
        a3 = fmaf(w3, (float)x[(size_t)c3 * DD + lane], a3);
    }
    for (; i < e; ++i)
        a0 = fmaf(eval[i], (float)x[(size_t)ecol[i] * DD + lane], a0);
    o[(size_t)row * DD + lane] = (_Float16)((a0 + a1) + (a2 + a3));
}

// ---------------------------------------------------------------------------
// Entity gate via MFMA. One wave = 16 rows (N_ENT = 16*6250 exactly).
// acc = kg@Wa + ig@Wb in ONE accumulator chain (4 mfma per 16-col tile).
// A layout: A[m=lane&15][k=(lane>>4)*8+j]; B pre-packed by k_wcvt;
// C/D: col=lane&15, row=(lane>>4)*4+reg  [m89-verified].
// ---------------------------------------------------------------------------
__global__ __launch_bounds__(256) void k_gate3(const _Float16* __restrict__ kg16,
        const _Float16* __restrict__ ig16, const _Float16* __restrict__ wpack,
        _Float16* __restrict__ dual16, float* __restrict__ sums) {
    __shared__ _Float16 sw[8192];
    for (int i = threadIdx.x * 8; i < 8192; i += 256 * 8)
        *(half8*)(sw + i) = *(const half8*)(wpack + i);
    __syncthreads();
    int lane = threadIdx.x & 63;
    int wv = (blockIdx.x * 256 + threadIdx.x) >> 6;
    int row0 = wv * 16;
    if (row0 >= N_ENT) return;
    int m = lane & 15;
    int quad = lane >> 4;

    const _Float16* kgr = kg16 + (size_t)(row0 + m) * DD + quad * 8;
    const _Float16* igr = ig16 + (size_t)(row0 + m) * DD + quad * 8;
    half8 akg0 = *(const half8*)(kgr);
    half8 akg1 = *(const half8*)(kgr + 32);
    half8 aig0 = *(const half8*)(igr);
    half8 aig1 = *(const half8*)(igr + 32);

    floatx4 acc[4];
#pragma unroll
    for (int t = 0; t < 4; ++t) {
        // sw layout: m*4096 + kstep*2048 + ntile*512 + lane*8
        half8 bA0 = *(const half8*)(sw + 0 * 4096 + 0 * 2048 + t * 512 + lane * 8);
        half8 bA1 = *(const half8*)(sw + 0 * 4096 + 1 * 2048 + t * 512 + lane * 8);
        half8 bB0 = *(const half8*)(sw + 1 * 4096 + 0 * 2048 + t * 512 + lane * 8);
        half8 bB1 = *(const half8*)(sw + 1 * 4096 + 1 * 2048 + t * 512 + lane * 8);
        floatx4 c = {0.f, 0.f, 0.f, 0.f};
        c = __builtin_amdgcn_mfma_f32_16x16x32_f16(akg0, bA0, c, 0, 0, 0);
        c = __builtin_amdgcn_mfma_f32_16x16x32_f16(akg1, bA1, c, 0, 0, 0);
        c = __builtin_amdgcn_mfma_f32_16x16x32_f16(aig0, bB0, c, 0, 0, 0);
        c = __builtin_amdgcn_mfma_f32_16x16x32_f16(aig1, bB1, c, 0, 0, 0);
        acc[t] = c;
    }

#pragma unroll
    for (int t = 0; t < 4; ++t) {
#pragma unroll
        for (int r = 0; r < 4; ++r) {
            int row = quad * 4 + r;
            int col = t * 16 + m;
            size_t o = (size_t)(row0 + row) * DD + col;
            float kv = (float)kg16[o];
            float cv = (float)ig16[o];
            float g = 1.f / (1.f + expf(-acc[t][r]));
            dual16[o] = (_Float16)(g * kv + (1.f - g) * cv);
            sums[o] += cv;
        }
    }
}

// user rows: dual16 <- ig16, sums += ig16
__global__ void k_user2(const _Float16* __restrict__ ig16, _Float16* __restrict__ dual16,
                        float* __restrict__ sums) {
    int i = blockIdx.x * blockDim.x + threadIdx.x;
    if (i >= N_USR * DD) return;
    size_t o = (size_t)N_ENT * DD + i;
    _Float16 v = ig16[o];
    dual16[o] = v;
    sums[o] += (float)v;
}

// init: sums = embed (fp32), dual16 = fp16(embed)
__global__ void k_init(const float* __restrict__ embed, float* __restrict__ sums,
                       _Float16* __restrict__ dual16) {
    int i = blockIdx.x * blockDim.x + threadIdx.x;
    if (i >= N_TOT * DD) return;
    float v = embed[i];
    sums[i] = v;
    dual16[i] = (_Float16)v;
}

// out[u,j] = sums[user_ids[u]] . sums[item_ids[j]]
// 256 blocks: 128 user-groups (8 users) x 2 item-halves (1024 items)
__global__ __launch_bounds__(256) void k_out(const float* __restrict__ sums,
        const int* __restrict__ user_ids, const int* __restrict__ item_ids,
        float* __restrict__ out) {
    __shared__ float uvec[8 * DD];
    int ub = (blockIdx.x >> 1) * 8;
    int jbase = (blockIdx.x & 1) * 1024;
    for (int i = threadIdx.x; i < 8 * DD; i += blockDim.x) {
        int uu = i >> 6, d = i & 63;
        uvec[i] = sums[(size_t)user_ids[ub + uu] * DD + d];
    }
    __syncthreads();
    for (int j = threadIdx.x; j < 1024; j += blockDim.x) {
        const float* irow = sums + (size_t)item_ids[jbase + j] * DD;
        float acc[8] = {0.f, 0.f, 0.f, 0.f, 0.f, 0.f, 0.f, 0.f};
        for (int d = 0; d < DD; d += 4) {
            float4 iv = *(const float4*)(irow + d);
#pragma unroll
            for (int u = 0; u < 8; ++u) {
                acc[u] = fmaf(iv.x, uvec[u * DD + d + 0], acc[u]);
                acc[u] = fmaf(iv.y, uvec[u * DD + d + 1], acc[u]);
                acc[u] = fmaf(iv.z, uvec[u * DD + d + 2], acc[u]);
                acc[u] = fmaf(iv.w, uvec[u * DD + d + 3], acc[u]);
            }
        }
#pragma unroll
        for (int u = 0; u < 8; ++u)
            out[(size_t)(ub + u) * 2048 + jbase + j] = acc[u];
    }
}

extern "C" void kernel_launch(void* const* d_in, const int* in_sizes, int n_in,
                              void* d_out, int out_size, void* d_ws, size_t ws_size,
                              hipStream_t stream) {
    const float* embed   = (const float*)d_in[0];
    const float* rel     = (const float*)d_in[1];
    const float* Wk_w    = (const float*)d_in[2];
    const float* Wk_b    = (const float*)d_in[3];
    const float* Wa      = (const float*)d_in[4];
    const float* Wb      = (const float*)d_in[5];
    const int*   kg_h    = (const int*)d_in[6];
    const int*   kg_t    = (const int*)d_in[7];
    const int*   kg_r    = (const int*)d_in[8];
    const int*   ain_row = (const int*)d_in[9];
    const int*   ain_col = (const int*)d_in[10];
    const float* ain_val = (const float*)d_in[11];
    const int*   user_ids = (const int*)d_in[12];
    const int*   item_ids = (const int*)d_in[13];
    int E_KG = in_sizes[6];
    int E_CF = in_sizes[9];
    float* out = (float*)d_out;

    float* ws = (float*)d_ws;
    size_t off = 0;
    float* uvr       = ws + off; off += 16 * 132;
    float* Puv       = ws + off; off += (size_t)N_ENT * 32;
    int*   kg_cnt    = (int*)(ws + off); off += N_ENT;       // hist -> scatter cursor
    int*   cf_cnt    = (int*)(ws + off); off += N_TOT;       // adjacent: one memset
    int*   kg_rowptr = (int*)(ws + off); off += N_ENT + 4;
    int*   cf_rowptr = (int*)(ws + off); off += N_TOT + 4;
    int*   kg_bsum   = (int*)(ws + off); off += 1024;
    int*   cf_bsum   = (int*)(ws + off); off += 1024;
    int*   kg_ecol   = (int*)(ws + off); off += (size_t)E_KG;
    float* kg_eval   = ws + off; off += (size_t)E_KG;
    int*   cf_ecol   = (int*)(ws + off); off += (size_t)E_CF;
    float* cf_eval   = ws + off; off += (size_t)E_CF;
    float* sums      = ws + off; off += (size_t)N_TOT * DD;
    _Float16* wpack  = (_Float16*)(ws + off); off += 8192 / 2;
    _Float16* dual16 = (_Float16*)(ws + off); off += (size_t)N_TOT * DD / 2;
    _Float16* ig16   = (_Float16*)(ws + off); off += (size_t)N_TOT * DD / 2;
    _Float16* kg16A  = (_Float16*)(ws + off); off += (size_t)N_ENT * DD / 2;
    _Float16* kg16B  = (_Float16*)(ws + off); off += (size_t)N_ENT * DD / 2;

    int kg_nb = (N_ENT + SCAN_ITEMS - 1) / SCAN_ITEMS;   // 98
    int cf_nb = (N_TOT + SCAN_ITEMS - 1) / SCAN_ITEMS;   // 147

    // --- CSR build for both graphs ---
    hipMemsetAsync(kg_cnt, 0, (size_t)(N_ENT + N_TOT) * sizeof(int), stream);
    hipLaunchKernelGGL(k_hist, dim3((E_KG + 255) / 256), dim3(256), 0, stream, kg_h, kg_cnt, E_KG);
    hipLaunchKernelGGL(k_hist, dim3((E_CF + 255) / 256), dim3(256), 0, stream, ain_row, cf_cnt, E_CF);
    hipLaunchKernelGGL(k_blocksum, dim3(kg_nb), dim3(SCAN_BLK), 0, stream, kg_cnt, kg_bsum, N_ENT);
    hipLaunchKernelGGL(k_bscan, dim3(1), dim3(1024), 0, stream, kg_bsum, kg_nb, kg_rowptr + N_ENT);
    hipLaunchKernelGGL(k_scan_apply, dim3(kg_nb), dim3(SCAN_BLK), 0, stream, kg_cnt, kg_rowptr, kg_bsum, N_ENT);
    hipLaunchKernelGGL(k_blocksum, dim3(cf_nb), dim3(SCAN_BLK), 0, stream, cf_cnt, cf_bsum, N_TOT);
    hipLaunchKernelGGL(k_bscan, dim3(1), dim3(1024), 0, stream, cf_bsum, cf_nb, cf_rowptr + N_TOT);
    hipLaunchKernelGGL(k_scan_apply, dim3(cf_nb), dim3(SCAN_BLK), 0, stream, cf_cnt, cf_rowptr, cf_bsum, N_TOT);
    hipLaunchKernelGGL(k_scatter, dim3((E_CF + 255) / 256), dim3(256), 0, stream,
                       ain_row, ain_col, ain_val, cf_cnt, cf_ecol, cf_eval, E_CF);

    // --- attention: rel precompute -> per-entity projections -> per-edge ---
    hipLaunchKernelGGL(k_rel, dim3(16), dim3(128), 0, stream, Wk_w, Wk_b, rel, uvr);
    hipLaunchKernelGGL(k_proj, dim3((N_ENT + 7) / 8), dim3(256), 0, stream, embed, uvr, Puv);
    hipLaunchKernelGGL(k_edge2, dim3((E_KG + 255) / 256), dim3(256), 0, stream,
                       kg_h, kg_t, kg_r, Puv, uvr, kg_cnt, kg_ecol, kg_eval, E_KG);
    hipLaunchKernelGGL(k_rowdiv, dim3((N_ENT * 64 + 255) / 256), dim3(256), 0, stream,
                       kg_rowptr, kg_eval, N_ENT);
    hipLaunchKernelGGL(k_init, dim3((N_TOT * DD + 255) / 256), dim3(256), 0, stream,
                       embed, sums, dual16);
    hipLaunchKernelGGL(k_wcvt, dim3(32), dim3(256), 0, stream, Wa, Wb, wpack);

    // --- 3 propagation layers; layer0 KG gather table = dual16 (== fp16 embed) ---
    const _Float16* cur16 = dual16;
    _Float16* kg16o = kg16A;
    _Float16* kg16alt = kg16B;
    int spmm_waves = N_ENT + N_TOT;
    int spmm_blocks = (spmm_waves * 64 + 255) / 256;
    int gate_blocks = (N_ENT / 16 + 3) / 4;              // 6250 waves, 4/block
    for (int layer = 0; layer < 3; ++layer) {
        hipLaunchKernelGGL(k_spmm_dual, dim3(spmm_blocks), dim3(256), 0, stream,
                           kg_rowptr, kg_ecol, kg_eval, cur16, kg16o,
                           cf_rowptr, cf_ecol, cf_eval, dual16, ig16);
        hipLaunchKernelGGL(k_gate3, dim3(gate_blocks), dim3(256), 0, stream,
                           kg16o, ig16, wpack, dual16, sums);
        hipLaunchKernelGGL(k_user2, dim3((N_USR * DD + 255) / 256), dim3(256), 0, stream,
                           ig16, dual16, sums);
        cur16 = kg16o;
        kg16o = kg16alt;
        kg16alt = (_Float16*)cur16;
    }

    // --- final gather-GEMM 1024 x 2048 x 64 ---
    hipLaunchKernelGGL(k_out, dim3(256), dim3(256), 0, stream, sums, user_ids, item_ids, out);
}

// Round 7
// 994.981 us; speedup vs baseline: 1.6005x; 1.0957x over previous
//
#include <hip/hip_runtime.h>
#include <math.h>

#define N_ENT 100000
#define N_USR 50000
#define N_TOT 150000
#define DD 64

#define SCAN_BLK 256
#define SCAN_ITEMS 1024   // elements per scan block

typedef _Float16 half8 __attribute__((ext_vector_type(8)));
typedef _Float16 half4 __attribute__((ext_vector_type(4)));
typedef float floatx4 __attribute__((ext_vector_type(4)));

// ---------------------------------------------------------------------------
// Per-relation precompute: u_r = Wk_w[0:64]@r, v_r = Wk_w[64:128]@r, c_r = b@r
// uvr layout: [16][132]: u at 0..63, v at 64..127, c at 128
// ---------------------------------------------------------------------------
__global__ void k_rel(const float* __restrict__ Wk_w, const float* __restrict__ Wk_b,
                      const float* __restrict__ rel, float* __restrict__ uvr) {
    int r = blockIdx.x;   // 16 blocks
    int k = threadIdx.x;  // 128 threads
    const float* rv = rel + r * DD;
    const float* wrow = Wk_w + k * DD;
    float s = 0.f;
    for (int j = 0; j < DD; ++j) s += wrow[j] * rv[j];
    uvr[r * 132 + k] = s;
    if (k == 0) {
        float c = 0.f;
        for (int j = 0; j < DD; ++j) c += Wk_b[j] * rv[j];
        uvr[r * 132 + 128] = c;
    }
}

// ---------------------------------------------------------------------------
// Per-entity projections: Puv[n][r] = embed[n].u_r ; Puv[n][16+r] = embed[n].v_r
// ---------------------------------------------------------------------------
__global__ __launch_bounds__(256) void k_proj(const float* __restrict__ embed,
        const float* __restrict__ uvr, float* __restrict__ Puv) {
    __shared__ float suvr[16 * 128];
    for (int i = threadIdx.x; i < 16 * 128; i += 256)
        suvr[i] = uvr[(i >> 7) * 132 + (i & 127)];
    __syncthreads();
    int rowi = threadIdx.x >> 5;
    int sub = threadIdx.x & 31;
    int r = sub & 15, w = sub >> 4;
    int row = blockIdx.x * 8 + rowi;
    if (row >= N_ENT) return;
    const float* er = embed + (size_t)row * DD;
    const float* uv = suvr + r * 128 + w * 64;
    float s = 0.f;
    for (int d = 0; d < DD; ++d) s = fmaf(er[d], uv[d], s);
    Puv[(size_t)row * 32 + sub] = s;
}

// unified histogram: KG rows at [0,N_ENT), CF rows at [N_ENT, N_ENT+N_TOT)
__global__ void k_hist_all(const int* __restrict__ kg_h, const int* __restrict__ ain_row,
                           int* __restrict__ cnt, int E_KG, int E_CF) {
    int e = blockIdx.x * blockDim.x + threadIdx.x;
    if (e < E_KG) atomicAdd(cnt + kg_h[e], 1);
    else if (e < E_KG + E_CF) atomicAdd(cnt + N_ENT + ain_row[e - E_KG], 1);
}

// --- multi-block exclusive scan, phase 1: per-chunk partial sums ---
__global__ __launch_bounds__(SCAN_BLK) void k_blocksum(const int* __restrict__ cnt,
                                                       int* __restrict__ bsum, int n) {
    __shared__ int s[SCAN_BLK];
    int base = blockIdx.x * SCAN_ITEMS;
    int sum = 0;
    for (int i = threadIdx.x; i < SCAN_ITEMS; i += SCAN_BLK) {
        int idx = base + i;
        if (idx < n) sum += cnt[idx];
    }
    s[threadIdx.x] = sum;
    __syncthreads();
    for (int off = SCAN_BLK / 2; off; off >>= 1) {
        if (threadIdx.x < off) s[threadIdx.x] += s[threadIdx.x + off];
        __syncthreads();
    }
    if (threadIdx.x == 0) bsum[blockIdx.x] = s[0];
}

// --- phase 2: single-block exclusive scan of partials (nb <= 1024) ---
__global__ __launch_bounds__(1024) void k_bscan(int* __restrict__ bsum, int nb,
                                                int* __restrict__ total_out) {
    __shared__ int s[1024];
    int tid = threadIdx.x;
    int v = (tid < nb) ? bsum[tid] : 0;
    s[tid] = v;
    __syncthreads();
    for (int off = 1; off < 1024; off <<= 1) {
        int t = (tid >= off) ? s[tid - off] : 0;
        __syncthreads();
        s[tid] += t;
        __syncthreads();
    }
    if (tid < nb) bsum[tid] = s[tid] - v;   // exclusive
    if (tid == 1023) *total_out = s[1023];
}

// --- phase 3: block-local scan + offset; writes rowptr and scatter cursor ---
__global__ __launch_bounds__(SCAN_BLK) void k_scan_apply(int* __restrict__ cnt,
        int* __restrict__ rowptr, const int* __restrict__ bsum, int n) {
    __shared__ int s[SCAN_BLK];
    int base = blockIdx.x * SCAN_ITEMS;
    int t = threadIdx.x;
    int idx0 = base + t * 4;
    int v[4];
    int lsum = 0;
#pragma unroll
    for (int k = 0; k < 4; ++k) {
        int idx = idx0 + k;
        v[k] = (idx < n) ? cnt[idx] : 0;
        lsum += v[k];
    }
    s[t] = lsum;
    __syncthreads();
    for (int off = 1; off < SCAN_BLK; off <<= 1) {
        int tv = (t >= off) ? s[t - off] : 0;
        __syncthreads();
        s[t] += tv;
        __syncthreads();
    }
    int pre = (t ? s[t - 1] : 0) + bsum[blockIdx.x];
#pragma unroll
    for (int k = 0; k < 4; ++k) {
        int idx = idx0 + k;
        if (idx < n) { rowptr[idx] = pre; cnt[idx] = pre; }
        pre += v[k];
    }
}

// KG scatter: ONE 4B store per edge: packed t | (r<<17)  (t < 2^17, r < 16)
__global__ void k_edge_pack(const int* __restrict__ kg_h, const int* __restrict__ kg_t,
                            const int* __restrict__ kg_r, int* __restrict__ cursor,
                            int* __restrict__ kgpk, int E) {
    int e = blockIdx.x * blockDim.x + threadIdx.x;
    if (e >= E) return;
    int h = kg_h[e];
    int pos = atomicAdd(cursor + h, 1);
    kgpk[pos] = kg_t[e] | (kg_r[e] << 17);
}

// CF scatter: ONE 8B store per edge: (col, val)
__global__ void k_cf_scatter(const int* __restrict__ rows, const int* __restrict__ cols,
                             const float* __restrict__ vals, int* __restrict__ cursor,
                             int2* __restrict__ pairbuf, int E) {
    int e = blockIdx.x * blockDim.x + threadIdx.x;
    if (e >= E) return;
    int r = rows[e];
    int pos = atomicAdd(cursor + N_ENT + r, 1);
    pairbuf[pos] = make_int2(cols[e], __float_as_int(vals[e]));
}

// ---------------------------------------------------------------------------
// KG rows: wave per row. Reads packed (t,r) coalesced, computes logit from Puv
// (1 random line per edge + 1 line per row), exp, row-normalizes, writes
// normalized (col, attn) pairs COALESCED into pairbuf.
// ---------------------------------------------------------------------------
__global__ __launch_bounds__(256) void k_rowdiv2(const int* __restrict__ rowptr,
        const int* __restrict__ kgpk, const float* __restrict__ Puv,
        const float* __restrict__ uvr, int2* __restrict__ pairbuf) {
    int wid0 = (blockIdx.x * 256 + threadIdx.x) >> 6;
    int h = __builtin_amdgcn_readfirstlane(wid0);
    if (h >= N_ENT) return;
    int lane = threadIdx.x & 63;
    int s = rowptr[h], e = rowptr[h + 1];
    const float* ph = Puv + (size_t)h * 32 + 16;
    float sum = 0.f;
    for (int i = s + lane; i < e; i += 64) {
        int pk = kgpk[i];
        int t = pk & 0x1FFFF;
        int r = pk >> 17;
        float lg = Puv[(size_t)t * 32 + r] + ph[r] + uvr[r * 132 + 128];
        lg = lg >= 0.f ? lg : 0.01f * lg;
        // softmax is shift-invariant; |logit| << 1 so skip segment-max
        float exv = expf(lg);
        pairbuf[i] = make_int2(t, __float_as_int(exv));
        sum += exv;
    }
    for (int off = 32; off; off >>= 1) sum += __shfl_xor(sum, off);
    if (e > s) {
        float inv = 1.f / sum;
        for (int i = s + lane; i < e; i += 64) {
            int2 p = pairbuf[i];
            p.y = __float_as_int(__int_as_float(p.y) * inv);
            pairbuf[i] = p;
        }
    }
}

// ---------------------------------------------------------------------------
// Pack Wa,Wb into fp16 MFMA B-fragment layout (16 KB).
// ---------------------------------------------------------------------------
__global__ void k_wcvt(const float* __restrict__ Wa, const float* __restrict__ Wb,
                       _Float16* __restrict__ wpack) {
    int i = blockIdx.x * 256 + threadIdx.x;
    if (i >= 8192) return;
    int m = i >> 12;
    int rem = i & 4095;
    int kstep = rem >> 11;
    int rem2 = rem & 2047;
    int ntile = rem2 >> 9;
    int rem3 = rem2 & 511;
    int lane = rem3 >> 3;
    int j = rem3 & 7;
    int k = kstep * 32 + (lane >> 4) * 8 + j;
    int n = ntile * 16 + (lane & 15);
    const float* W = m ? Wb : Wa;
    wpack[i] = (_Float16)W[k * 64 + n];
}

// ---------------------------------------------------------------------------
// Unified KG+CF CSR SpMM, wave per row, lane = dim, fp16 in/out, int2 pairs.
// Rows [0,N_ENT): KG (gather cur16 -> kg16o); [N_ENT,N_ENT+N_TOT): CF
// (gather dual16 -> ig16). Row id wave-uniform -> CSR meta on scalar path.
// ---------------------------------------------------------------------------
__global__ __launch_bounds__(256) void k_spmm_u(const int* __restrict__ rowptr,
        const int2* __restrict__ pairbuf, const _Float16* __restrict__ cur16,
        const _Float16* __restrict__ dual16, _Float16* __restrict__ kg16o,
        _Float16* __restrict__ ig16) {
    int wid0 = (blockIdx.x * 256 + threadIdx.x) >> 6;
    int wid = __builtin_amdgcn_readfirstlane(wid0);
    if (wid >= N_ENT + N_TOT) return;
    int lane = threadIdx.x & 63;
    bool is_kg = wid < N_ENT;
    const _Float16* x = is_kg ? cur16 : dual16;
    int s = rowptr[wid], e = rowptr[wid + 1];
    float a0 = 0.f, a1 = 0.f, a2 = 0.f, a3 = 0.f;
    int i = s;
    for (; i + 4 <= e; i += 4) {
        int2 p0 = pairbuf[i], p1 = pairbuf[i + 1], p2 = pairbuf[i + 2], p3 = pairbuf[i + 3];
        a0 = fmaf(__int_as_float(p0.y), (float)x[(size_t)p0.x * DD + lane], a0);
        a1 = fmaf(__int_as_float(p1.y), (float)x[(size_t)p1.x * DD + lane], a1);
        a2 = fmaf(__int_as_float(p2.y), (float)x[(size_t)p2.x * DD + lane], a2);
        a3 = fmaf(__int_as_float(p3.y), (float)x[(size_t)p3.x * DD + lane], a3);
    }
    for (; i < e; ++i) {
        int2 p = pairbuf[i];
        a0 = fmaf(__int_as_float(p.y), (float)x[(size_t)p.x * DD + lane], a0);
    }
    float res = (a0 + a1) + (a2 + a3);
    _Float16* o = is_kg ? (kg16o + (size_t)wid * DD) : (ig16 + (size_t)(wid - N_ENT) * DD);
    o[lane] = (_Float16)res;
}

// ---------------------------------------------------------------------------
// Entity gate via MFMA. One wave = 16 rows. acc = kg@Wa + ig@Wb in one
// accumulator chain. C/D: col=lane&15, row=(lane>>4)*4+reg [m89-verified].
// No sums update (sums reconstructed in k_out from embed + per-layer ig).
// ---------------------------------------------------------------------------
__global__ __launch_bounds__(256) void k_gate3(const _Float16* __restrict__ kg16,
        const _Float16* __restrict__ ig16, const _Float16* __restrict__ wpack,
        _Float16* __restrict__ dual16) {
    __shared__ _Float16 sw[8192];
    for (int i = threadIdx.x * 8; i < 8192; i += 256 * 8)
        *(half8*)(sw + i) = *(const half8*)(wpack + i);
    __syncthreads();
    int lane = threadIdx.x & 63;
    int wv = (blockIdx.x * 256 + threadIdx.x) >> 6;
    int row0 = wv * 16;
    if (row0 >= N_ENT) return;
    int m = lane & 15;
    int quad = lane >> 4;

    const _Float16* kgr = kg16 + (size_t)(row0 + m) * DD + quad * 8;
    const _Float16* igr = ig16 + (size_t)(row0 + m) * DD + quad * 8;
    half8 akg0 = *(const half8*)(kgr);
    half8 akg1 = *(const half8*)(kgr + 32);
    half8 aig0 = *(const half8*)(igr);
    half8 aig1 = *(const half8*)(igr + 32);

    floatx4 acc[4];
#pragma unroll
    for (int t = 0; t < 4; ++t) {
        half8 bA0 = *(const half8*)(sw + 0 * 4096 + 0 * 2048 + t * 512 + lane * 8);
        half8 bA1 = *(const half8*)(sw + 0 * 4096 + 1 * 2048 + t * 512 + lane * 8);
        half8 bB0 = *(const half8*)(sw + 1 * 4096 + 0 * 2048 + t * 512 + lane * 8);
        half8 bB1 = *(const half8*)(sw + 1 * 4096 + 1 * 2048 + t * 512 + lane * 8);
        floatx4 c = {0.f, 0.f, 0.f, 0.f};
        c = __builtin_amdgcn_mfma_f32_16x16x32_f16(akg0, bA0, c, 0, 0, 0);
        c = __builtin_amdgcn_mfma_f32_16x16x32_f16(akg1, bA1, c, 0, 0, 0);
        c = __builtin_amdgcn_mfma_f32_16x16x32_f16(aig0, bB0, c, 0, 0, 0);
        c = __builtin_amdgcn_mfma_f32_16x16x32_f16(aig1, bB1, c, 0, 0, 0);
        acc[t] = c;
    }

#pragma unroll
    for (int t = 0; t < 4; ++t) {
#pragma unroll
        for (int r = 0; r < 4; ++r) {
            int row = quad * 4 + r;
            int col = t * 16 + m;
            size_t o = (size_t)(row0 + row) * DD + col;
            float kv = (float)kg16[o];
            float cv = (float)ig16[o];
            float g = 1.f / (1.f + expf(-acc[t][r]));
            dual16[o] = (_Float16)(g * kv + (1.f - g) * cv);
        }
    }
}

// user rows: dual16 <- ig16 (vectorized fp16 copy)
__global__ void k_usercopy(const _Float16* __restrict__ ig16, _Float16* __restrict__ dual16) {
    int i = blockIdx.x * 256 + threadIdx.x;
    if (i >= N_USR * DD / 8) return;
    size_t o = (size_t)N_ENT * DD / 8 + i;
    ((half8*)dual16)[o] = ((const half8*)(ig16))[o - (size_t)N_ENT * DD / 8 + (size_t)N_ENT * DD / 8];
}

// init: dual16 = fp16(embed)
__global__ void k_init(const float* __restrict__ embed, _Float16* __restrict__ dual16) {
    int i = blockIdx.x * blockDim.x + threadIdx.x;
    if (i >= N_TOT * DD) return;
    dual16[i] = (_Float16)embed[i];
}

// ---------------------------------------------------------------------------
// out[u,j] = sums[user_ids[u]] . sums[item_ids[j]],
// sums[row] = embed[row] + ig0[row] + ig1[row] + ig2[row]  (reconstructed).
// 256 blocks: 64 user-groups (16 users) x 4 item-quarters (512 items).
// ---------------------------------------------------------------------------
__global__ __launch_bounds__(256) void k_out(const float* __restrict__ embed,
        const _Float16* __restrict__ ig0, const _Float16* __restrict__ ig1,
        const _Float16* __restrict__ ig2, const int* __restrict__ user_ids,
        const int* __restrict__ item_ids, float* __restrict__ out) {
    __shared__ float uvec[16 * DD];
    int ug = blockIdx.x >> 2;
    int qi = blockIdx.x & 3;
    int ub = ug * 16;
    for (int i = threadIdx.x; i < 16 * DD; i += 256) {
        int uu = i >> 6, d = i & 63;
        size_t o = (size_t)user_ids[ub + uu] * DD + d;
        uvec[i] = embed[o] + (float)ig0[o] + (float)ig1[o] + (float)ig2[o];
    }
    __syncthreads();
    int jbase = qi * 512;
    for (int j = threadIdx.x; j < 512; j += 256) {
        size_t ro = (size_t)item_ids[jbase + j] * DD;
        float acc[16];
#pragma unroll
        for (int u = 0; u < 16; ++u) acc[u] = 0.f;
        for (int d = 0; d < DD; d += 4) {
            float4 ev = *(const float4*)(embed + ro + d);
            half4 h0 = *(const half4*)(ig0 + ro + d);
            half4 h1 = *(const half4*)(ig1 + ro + d);
            half4 h2 = *(const half4*)(ig2 + ro + d);
            float iv0 = ev.x + (float)h0[0] + (float)h1[0] + (float)h2[0];
            float iv1 = ev.y + (float)h0[1] + (float)h1[1] + (float)h2[1];
            float iv2 = ev.z + (float)h0[2] + (float)h1[2] + (float)h2[2];
            float iv3 = ev.w + (float)h0[3] + (float)h1[3] + (float)h2[3];
#pragma unroll
            for (int u = 0; u < 16; ++u) {
                acc[u] = fmaf(iv0, uvec[u * DD + d + 0], acc[u]);
                acc[u] = fmaf(iv1, uvec[u * DD + d + 1], acc[u]);
                acc[u] = fmaf(iv2, uvec[u * DD + d + 2], acc[u]);
                acc[u] = fmaf(iv3, uvec[u * DD + d + 3], acc[u]);
            }
        }
#pragma unroll
        for (int u = 0; u < 16; ++u)
            out[(size_t)(ub + u) * 2048 + jbase + j] = acc[u];
    }
}

extern "C" void kernel_launch(void* const* d_in, const int* in_sizes, int n_in,
                              void* d_out, int out_size, void* d_ws, size_t ws_size,
                              hipStream_t stream) {
    const float* embed   = (const float*)d_in[0];
    const float* rel     = (const float*)d_in[1];
    const float* Wk_w    = (const float*)d_in[2];
    const float* Wk_b    = (const float*)d_in[3];
    const float* Wa      = (const float*)d_in[4];
    const float* Wb      = (const float*)d_in[5];
    const int*   kg_h    = (const int*)d_in[6];
    const int*   kg_t    = (const int*)d_in[7];
    const int*   kg_r    = (const int*)d_in[8];
    const int*   ain_row = (const int*)d_in[9];
    const int*   ain_col = (const int*)d_in[10];
    const float* ain_val = (const float*)d_in[11];
    const int*   user_ids = (const int*)d_in[12];
    const int*   item_ids = (const int*)d_in[13];
    int E_KG = in_sizes[6];
    int E_CF = in_sizes[9];
    float* out = (float*)d_out;

    const int N_ROWS = N_ENT + N_TOT;    // unified CSR rows

    float* ws = (float*)d_ws;
    size_t off = 0;
    float* uvr       = ws + off; off += 16 * 132;
    float* Puv       = ws + off; off += (size_t)N_ENT * 32;
    int*   cnt       = (int*)(ws + off); off += N_ROWS;        // hist -> cursor
    int*   rowptr    = (int*)(ws + off); off += N_ROWS + 4;
    int*   bsum      = (int*)(ws + off); off += 1024;
    int*   kgpk      = (int*)(ws + off); off += (size_t)E_KG;
    int2*  pairbuf   = (int2*)(ws + off); off += 2 * ((size_t)E_KG + E_CF);
    _Float16* dual16 = (_Float16*)(ws + off); off += (size_t)N_TOT * DD / 2;
    _Float16* kg16A  = (_Float16*)(ws + off); off += (size_t)N_ENT * DD / 2;
    _Float16* kg16B  = (_Float16*)(ws + off); off += (size_t)N_ENT * DD / 2;
    _Float16* ig16_0 = (_Float16*)(ws + off); off += (size_t)N_TOT * DD / 2;
    _Float16* ig16_1 = (_Float16*)(ws + off); off += (size_t)N_TOT * DD / 2;
    _Float16* ig16_2 = (_Float16*)(ws + off); off += (size_t)N_TOT * DD / 2;
    _Float16* wpack  = (_Float16*)(ws + off); off += 8192 / 2;
    _Float16* ig_l[3] = {ig16_0, ig16_1, ig16_2};

    int nb = (N_ROWS + SCAN_ITEMS - 1) / SCAN_ITEMS;   // 245

    // --- unified CSR build ---
    hipMemsetAsync(cnt, 0, (size_t)N_ROWS * sizeof(int), stream);
    hipLaunchKernelGGL(k_hist_all, dim3((E_KG + E_CF + 255) / 256), dim3(256), 0, stream,
                       kg_h, ain_row, cnt, E_KG, E_CF);
    hipLaunchKernelGGL(k_blocksum, dim3(nb), dim3(SCAN_BLK), 0, stream, cnt, bsum, N_ROWS);
    hipLaunchKernelGGL(k_bscan, dim3(1), dim3(1024), 0, stream, bsum, nb, rowptr + N_ROWS);
    hipLaunchKernelGGL(k_scan_apply, dim3(nb), dim3(SCAN_BLK), 0, stream, cnt, rowptr, bsum, N_ROWS);
    hipLaunchKernelGGL(k_edge_pack, dim3((E_KG + 255) / 256), dim3(256), 0, stream,
                       kg_h, kg_t, kg_r, cnt, kgpk, E_KG);
    hipLaunchKernelGGL(k_cf_scatter, dim3((E_CF + 255) / 256), dim3(256), 0, stream,
                       ain_row, ain_col, ain_val, cnt, pairbuf, E_CF);

    // --- attention: rel -> projections -> per-row logits/softmax/pairs ---
    hipLaunchKernelGGL(k_rel, dim3(16), dim3(128), 0, stream, Wk_w, Wk_b, rel, uvr);
    hipLaunchKernelGGL(k_proj, dim3((N_ENT + 7) / 8), dim3(256), 0, stream, embed, uvr, Puv);
    hipLaunchKernelGGL(k_rowdiv2, dim3((N_ENT * 64 + 255) / 256), dim3(256), 0, stream,
                       rowptr, kgpk, Puv, uvr, pairbuf);
    hipLaunchKernelGGL(k_init, dim3((N_TOT * DD + 255) / 256), dim3(256), 0, stream,
                       embed, dual16);
    hipLaunchKernelGGL(k_wcvt, dim3(32), dim3(256), 0, stream, Wa, Wb, wpack);

    // --- 3 propagation layers ---
    const _Float16* cur16 = dual16;       // layer0 KG gather table = fp16 embed
    _Float16* kg16o = kg16A;
    _Float16* kg16alt = kg16B;
    int spmm_blocks = ((size_t)N_ROWS * 64 + 255) / 256;
    int gate_blocks = (N_ENT / 16 + 3) / 4;
    int uc_blocks = (N_USR * DD / 8 + 255) / 256;
    for (int layer = 0; layer < 3; ++layer) {
        hipLaunchKernelGGL(k_spmm_u, dim3(spmm_blocks), dim3(256), 0, stream,
                           rowptr, pairbuf, cur16, dual16, kg16o, ig_l[layer]);
        hipLaunchKernelGGL(k_gate3, dim3(gate_blocks), dim3(256), 0, stream,
                           kg16o, ig_l[layer], wpack, dual16);
        hipLaunchKernelGGL(k_usercopy, dim3(uc_blocks), dim3(256), 0, stream,
                           ig_l[layer], dual16);
        cur16 = kg16o;
        kg16o = kg16alt;
        kg16alt = (_Float16*)cur16;
    }

    // --- final gather-GEMM 1024 x 2048 x 64 with on-the-fly sums ---
    hipLaunchKernelGGL(k_out, dim3(256), dim3(256), 0, stream,
                       embed, ig16_0, ig16_1, ig16_2, user_ids, item_ids, out);
}

// Round 8
// 740.277 us; speedup vs baseline: 2.1512x; 1.3441x over previous
//
#include <hip/hip_runtime.h>
#include <math.h>

#define N_ENT 100000
#define N_USR 50000
#define N_TOT 150000
#define N_ROWS 250000     // unified rows: KG [0,N_ENT) + CF [N_ENT, N_ENT+N_TOT)
#define DD 64

#define SCAN_BLK 256
#define SCAN_ITEMS 1024   // elements per scan block

#define SORT_T 4096       // edges per phase-1 tile
#define NBUK 512          // buckets (row >> 9), 489 used
#define BUK_SHIFT 9
#define LDSCAP 6912       // phase-2 LDS segment capacity (avg bucket ~6135)

typedef _Float16 half8 __attribute__((ext_vector_type(8)));
typedef _Float16 half4 __attribute__((ext_vector_type(4)));
typedef float floatx4 __attribute__((ext_vector_type(4)));

// ---------------------------------------------------------------------------
// Per-relation precompute: u_r = Wk_w[0:64]@r, v_r = Wk_w[64:128]@r, c_r = b@r
// uvr layout: [16][132]: u at 0..63, v at 64..127, c at 128
// ---------------------------------------------------------------------------
__global__ void k_rel(const float* __restrict__ Wk_w, const float* __restrict__ Wk_b,
                      const float* __restrict__ rel, float* __restrict__ uvr) {
    int r = blockIdx.x;   // 16 blocks
    int k = threadIdx.x;  // 128 threads
    const float* rv = rel + r * DD;
    const float* wrow = Wk_w + k * DD;
    float s = 0.f;
    for (int j = 0; j < DD; ++j) s += wrow[j] * rv[j];
    uvr[r * 132 + k] = s;
    if (k == 0) {
        float c = 0.f;
        for (int j = 0; j < DD; ++j) c += Wk_b[j] * rv[j];
        uvr[r * 132 + 128] = c;
    }
}

// ---------------------------------------------------------------------------
// Per-entity projections: Puv[n][r] = embed[n].u_r ; Puv[n][16+r] = embed[n].v_r
// ---------------------------------------------------------------------------
__global__ __launch_bounds__(256) void k_proj(const float* __restrict__ embed,
        const float* __restrict__ uvr, float* __restrict__ Puv) {
    __shared__ float suvr[16 * 128];
    for (int i = threadIdx.x; i < 16 * 128; i += 256)
        suvr[i] = uvr[(i >> 7) * 132 + (i & 127)];
    __syncthreads();
    int rowi = threadIdx.x >> 5;
    int sub = threadIdx.x & 31;
    int r = sub & 15, w = sub >> 4;
    int row = blockIdx.x * 8 + rowi;
    if (row >= N_ENT) return;
    const float* er = embed + (size_t)row * DD;
    const float* uv = suvr + r * 128 + w * 64;
    float s = 0.f;
    for (int d = 0; d < DD; ++d) s = fmaf(er[d], uv[d], s);
    Puv[(size_t)row * 32 + sub] = s;
}

// ---------------------------------------------------------------------------
// Sort phase 0: per-tile bucket histogram. tilecnt[b * NT + tile] = count.
// Every (b,tile) cell is written -> no memset needed.
// ---------------------------------------------------------------------------
__global__ __launch_bounds__(256) void k_sort_hist(const int* __restrict__ kg_h,
        const int* __restrict__ ain_row, int* __restrict__ tilecnt,
        int E_KG, int E_TOT, int NT) {
    __shared__ int hist[NBUK];
    hist[threadIdx.x] = 0;
    hist[threadIdx.x + 256] = 0;
    __syncthreads();
    int tile = blockIdx.x;
    int base = tile * SORT_T;
#pragma unroll
    for (int k = 0; k < SORT_T / 256; ++k) {
        int e = base + k * 256 + threadIdx.x;
        if (e < E_TOT) {
            int row = (e < E_KG) ? kg_h[e] : (N_ENT + ain_row[e - E_KG]);
            atomicAdd(&hist[row >> BUK_SHIFT], 1);
        }
    }
    __syncthreads();
    tilecnt[threadIdx.x * NT + tile] = hist[threadIdx.x];
    tilecnt[(threadIdx.x + 256) * NT + tile] = hist[threadIdx.x + 256];
}

// --- multi-block exclusive scan, phase 1: per-chunk partial sums ---
__global__ __launch_bounds__(SCAN_BLK) void k_blocksum(const int* __restrict__ cnt,
                                                       int* __restrict__ bsum, int n) {
    __shared__ int s[SCAN_BLK];
    int base = blockIdx.x * SCAN_ITEMS;
    int sum = 0;
    for (int i = threadIdx.x; i < SCAN_ITEMS; i += SCAN_BLK) {
        int idx = base + i;
        if (idx < n) sum += cnt[idx];
    }
    s[threadIdx.x] = sum;
    __syncthreads();
    for (int off = SCAN_BLK / 2; off; off >>= 1) {
        if (threadIdx.x < off) s[threadIdx.x] += s[threadIdx.x + off];
        __syncthreads();
    }
    if (threadIdx.x == 0) bsum[blockIdx.x] = s[0];
}

// --- phase 2: single-block exclusive scan of partials (nb <= 1024) ---
__global__ __launch_bounds__(1024) void k_bscan(int* __restrict__ bsum, int nb,
                                                int* __restrict__ total_out) {
    __shared__ int s[1024];
    int tid = threadIdx.x;
    int v = (tid < nb) ? bsum[tid] : 0;
    s[tid] = v;
    __syncthreads();
    for (int off = 1; off < 1024; off <<= 1) {
        int t = (tid >= off) ? s[tid - off] : 0;
        __syncthreads();
        s[tid] += t;
        __syncthreads();
    }
    if (tid < nb) bsum[tid] = s[tid] - v;   // exclusive
    if (tid == 1023) *total_out = s[1023];
}

// --- phase 3: block-local scan + offset; writes scanned copy + cursor copy ---
__global__ __launch_bounds__(SCAN_BLK) void k_scan_apply(int* __restrict__ cnt,
        int* __restrict__ scanned, const int* __restrict__ bsum, int n) {
    __shared__ int s[SCAN_BLK];
    int base = blockIdx.x * SCAN_ITEMS;
    int t = threadIdx.x;
    int idx0 = base + t * 4;
    int v[4];
    int lsum = 0;
#pragma unroll
    for (int k = 0; k < 4; ++k) {
        int idx = idx0 + k;
        v[k] = (idx < n) ? cnt[idx] : 0;
        lsum += v[k];
    }
    s[t] = lsum;
    __syncthreads();
    for (int off = 1; off < SCAN_BLK; off <<= 1) {
        int tv = (t >= off) ? s[t - off] : 0;
        __syncthreads();
        s[t] += tv;
        __syncthreads();
    }
    int pre = (t ? s[t - 1] : 0) + bsum[blockIdx.x];
#pragma unroll
    for (int k = 0; k < 4; ++k) {
        int idx = idx0 + k;
        if (idx < n) { scanned[idx] = pre; cnt[idx] = pre; }
        pre += v[k];
    }
}

// ---------------------------------------------------------------------------
// Sort phase 1: per-tile LDS sort by bucket, dense run writes into bufA.
// Payload int2: KG: x = t | r<<17 | rlow<<22, y = 0
//               CF: x = col | rlow<<22,       y = bits(val)    (rlow = row&511)
// ---------------------------------------------------------------------------
__global__ __launch_bounds__(256) void k_sort_scatter(const int* __restrict__ kg_h,
        const int* __restrict__ kg_t, const int* __restrict__ kg_r,
        const int* __restrict__ ain_row, const int* __restrict__ ain_col,
        const float* __restrict__ ain_val, const int* __restrict__ tilescan,
        int2* __restrict__ bufA, int E_KG, int E_TOT, int NT) {
    __shared__ int2 pl[SORT_T];                 // 32 KB
    __shared__ unsigned short srcmap[SORT_T];   // 8 KB
    __shared__ unsigned short bko[SORT_T];      // 8 KB
    __shared__ int hist[NBUK];                  // 2 KB
    __shared__ int hscan[NBUK];                 // 2 KB
    __shared__ int cur[NBUK];                   // 2 KB
    __shared__ int gbase[NBUK];                 // 2 KB
    __shared__ int stmp[256];                   // 1 KB

    int tid = threadIdx.x;
    int tile = blockIdx.x;
    hist[tid] = 0; hist[tid + 256] = 0;
    __syncthreads();

    int base = tile * SORT_T;
    int nvalid = E_TOT - base; if (nvalid > SORT_T) nvalid = SORT_T;

    // pass A: build payload + bucket into LDS, histogram
#pragma unroll
    for (int k = 0; k < SORT_T / 256; ++k) {
        int idx = k * 256 + tid;
        int e = base + idx;
        if (e < E_TOT) {
            int row, x, y;
            if (e < E_KG) {
                row = kg_h[e];
                x = kg_t[e] | (kg_r[e] << 17) | ((row & 511) << 22);
                y = 0;
            } else {
                int i = e - E_KG;
                row = N_ENT + ain_row[i];
                x = ain_col[i] | ((row & 511) << 22);
                y = __float_as_int(ain_val[i]);
            }
            int b = row >> BUK_SHIFT;
            pl[idx] = make_int2(x, y);
            bko[idx] = (unsigned short)b;
            atomicAdd(&hist[b], 1);
        } else {
            bko[idx] = 0xFFFF;
        }
    }
    __syncthreads();

    // exclusive scan of hist[512] (2 elems/thread)
    int aL = hist[2 * tid], aR = hist[2 * tid + 1];
    stmp[tid] = aL + aR;
    __syncthreads();
    for (int off = 1; off < 256; off <<= 1) {
        int v = (tid >= off) ? stmp[tid - off] : 0;
        __syncthreads();
        stmp[tid] += v;
        __syncthreads();
    }
    int pre = tid ? stmp[tid - 1] : 0;
    hscan[2 * tid] = pre;
    hscan[2 * tid + 1] = pre + aL;
    cur[2 * tid] = pre;
    cur[2 * tid + 1] = pre + aL;
    gbase[tid] = tilescan[tid * NT + tile];
    gbase[tid + 256] = tilescan[(tid + 256) * NT + tile];
    __syncthreads();

    // pass B: stable-ish in-tile sort (order within bucket irrelevant)
#pragma unroll
    for (int k = 0; k < SORT_T / 256; ++k) {
        int idx = k * 256 + tid;
        unsigned short b = bko[idx];
        if (b != 0xFFFF) {
            int slot = atomicAdd(&cur[b], 1);
            srcmap[slot] = (unsigned short)idx;
        }
    }
    __syncthreads();

    // pass C: dense run writes
    for (int i = tid; i < nvalid; i += 256) {
        int si = srcmap[i];
        int b = bko[si];
        int dest = gbase[b] + (i - hscan[b]);
        bufA[dest] = pl[si];
    }
}

// ---------------------------------------------------------------------------
// Sort phase 2: one block per bucket. Row-hist + scan in LDS, emit rowptr,
// stage row-sorted segment in LDS, write out coalesced.
// ---------------------------------------------------------------------------
__global__ __launch_bounds__(256) void k_sort_fine(const int* __restrict__ tilescan,
        const int2* __restrict__ bufA, int2* __restrict__ pairbuf,
        int* __restrict__ rowptr, int NT) {
    __shared__ int2 seg[LDSCAP];   // 55.3 KB
    __shared__ int rcnt[512];      // 2 KB
    __shared__ int stmp[256];      // 1 KB
    int tid = threadIdx.x;
    int b = blockIdx.x;
    rcnt[tid] = 0; rcnt[tid + 256] = 0;
    __syncthreads();

    int base = tilescan[b * NT];
    int endo = tilescan[(b + 1) * NT];
    int bsize = endo - base;

    // pass 1: row histogram
    for (int i = base + tid; i < endo; i += 256) {
        unsigned rlow = ((unsigned)bufA[i].x) >> 22;
        atomicAdd(&rcnt[rlow], 1);
    }
    __syncthreads();

    // exclusive scan rcnt[512] in place
    int aL = rcnt[2 * tid], aR = rcnt[2 * tid + 1];
    stmp[tid] = aL + aR;
    __syncthreads();
    for (int off = 1; off < 256; off <<= 1) {
        int v = (tid >= off) ? stmp[tid - off] : 0;
        __syncthreads();
        stmp[tid] += v;
        __syncthreads();
    }
    int pre = tid ? stmp[tid - 1] : 0;
    rcnt[2 * tid] = pre;
    rcnt[2 * tid + 1] = pre + aL;
    __syncthreads();

    // emit rowptr (row == N_ROWS sentinel handled naturally: excl == bsize)
#pragma unroll
    for (int k = 0; k < 2; ++k) {
        int j = 2 * tid + k;
        int row = (b << BUK_SHIFT) + j;
        if (row <= N_ROWS) rowptr[row] = base + rcnt[j];
    }
    __syncthreads();

    // pass 2: fine scatter (LDS staged; direct-global fallback on overflow)
    if (bsize <= LDSCAP) {
        for (int i = base + tid; i < endo; i += 256) {
            int2 p = bufA[i];
            unsigned rlow = ((unsigned)p.x) >> 22;
            int slot = atomicAdd(&rcnt[rlow], 1);
            seg[slot] = p;
        }
        __syncthreads();
        for (int i = tid; i < bsize; i += 256)
            pairbuf[base + i] = seg[i];
    } else {
        for (int i = base + tid; i < endo; i += 256) {
            int2 p = bufA[i];
            unsigned rlow = ((unsigned)p.x) >> 22;
            int slot = atomicAdd(&rcnt[rlow], 1);
            pairbuf[base + slot] = p;
        }
    }
}

// ---------------------------------------------------------------------------
// KG rows: wave per row. Computes logit from Puv, exp, row-normalizes,
// writes attn into pairbuf[i].y (KG rows only).
// ---------------------------------------------------------------------------
__global__ __launch_bounds__(256) void k_rowdiv2(const int* __restrict__ rowptr,
        int2* __restrict__ pairbuf, const float* __restrict__ Puv,
        const float* __restrict__ uvr) {
    int wid0 = (blockIdx.x * 256 + threadIdx.x) >> 6;
    int h = __builtin_amdgcn_readfirstlane(wid0);
    if (h >= N_ENT) return;
    int lane = threadIdx.x & 63;
    int s = rowptr[h], e = rowptr[h + 1];
    const float* ph = Puv + (size_t)h * 32 + 16;
    float sum = 0.f;
    for (int i = s + lane; i < e; i += 64) {
        int x = pairbuf[i].x;
        int t = x & 0x1FFFF;
        int r = (x >> 17) & 15;
        float lg = Puv[(size_t)t * 32 + r] + ph[r] + uvr[r * 132 + 128];
        lg = lg >= 0.f ? lg : 0.01f * lg;
        // softmax is shift-invariant; |logit| << 1 so skip segment-max
        float exv = expf(lg);
        pairbuf[i].y = __float_as_int(exv);
        sum += exv;
    }
    for (int off = 32; off; off >>= 1) sum += __shfl_xor(sum, off);
    if (e > s) {
        float inv = 1.f / sum;
        for (int i = s + lane; i < e; i += 64) {
            float v = __int_as_float(pairbuf[i].y);
            pairbuf[i].y = __float_as_int(v * inv);
        }
    }
}

// ---------------------------------------------------------------------------
// Pack Wa,Wb into fp16 MFMA B-fragment layout (16 KB).
// ---------------------------------------------------------------------------
__global__ void k_wcvt(const float* __restrict__ Wa, const float* __restrict__ Wb,
                       _Float16* __restrict__ wpack) {
    int i = blockIdx.x * 256 + threadIdx.x;
    if (i >= 8192) return;
    int m = i >> 12;
    int rem = i & 4095;
    int kstep = rem >> 11;
    int rem2 = rem & 2047;
    int ntile = rem2 >> 9;
    int rem3 = rem2 & 511;
    int lane = rem3 >> 3;
    int j = rem3 & 7;
    int k = kstep * 32 + (lane >> 4) * 8 + j;
    int n = ntile * 16 + (lane & 15);
    const float* W = m ? Wb : Wa;
    wpack[i] = (_Float16)W[k * 64 + n];
}

// ---------------------------------------------------------------------------
// Unified KG+CF CSR SpMM, wave per row, lane = dim, fp16 in/out, int2 pairs.
// ---------------------------------------------------------------------------
__global__ __launch_bounds__(256) void k_spmm_u(const int* __restrict__ rowptr,
        const int2* __restrict__ pairbuf, const _Float16* __restrict__ cur16,
        const _Float16* __restrict__ dual16, _Float16* __restrict__ kg16o,
        _Float16* __restrict__ ig16) {
    int wid0 = (blockIdx.x * 256 + threadIdx.x) >> 6;
    int wid = __builtin_amdgcn_readfirstlane(wid0);
    if (wid >= N_ROWS) return;
    int lane = threadIdx.x & 63;
    bool is_kg = wid < N_ENT;
    const _Float16* x = is_kg ? cur16 : dual16;
    int cmask = is_kg ? 0x1FFFF : 0x3FFFF;
    int s = rowptr[wid], e = rowptr[wid + 1];
    float a0 = 0.f, a1 = 0.f, a2 = 0.f, a3 = 0.f;
    int i = s;
    for (; i + 4 <= e; i += 4) {
        int2 p0 = pairbuf[i], p1 = pairbuf[i + 1], p2 = pairbuf[i + 2], p3 = pairbuf[i + 3];
        a0 = fmaf(__int_as_float(p0.y), (float)x[(size_t)(p0.x & cmask) * DD + lane], a0);
        a1 = fmaf(__int_as_float(p1.y), (float)x[(size_t)(p1.x & cmask) * DD + lane], a1);
        a2 = fmaf(__int_as_float(p2.y), (float)x[(size_t)(p2.x & cmask) * DD + lane], a2);
        a3 = fmaf(__int_as_float(p3.y), (float)x[(size_t)(p3.x & cmask) * DD + lane], a3);
    }
    for (; i < e; ++i) {
        int2 p = pairbuf[i];
        a0 = fmaf(__int_as_float(p.y), (float)x[(size_t)(p.x & cmask) * DD + lane], a0);
    }
    float res = (a0 + a1) + (a2 + a3);
    _Float16* o = is_kg ? (kg16o + (size_t)wid * DD) : (ig16 + (size_t)(wid - N_ENT) * DD);
    o[lane] = (_Float16)res;
}

// ---------------------------------------------------------------------------
// Entity gate via MFMA. One wave = 16 rows. acc = kg@Wa + ig@Wb, one chain.
// C/D: col=lane&15, row=(lane>>4)*4+reg [m89-verified].
// ---------------------------------------------------------------------------
__global__ __launch_bounds__(256) void k_gate3(const _Float16* __restrict__ kg16,
        const _Float16* __restrict__ ig16, const _Float16* __restrict__ wpack,
        _Float16* __restrict__ dual16) {
    __shared__ _Float16 sw[8192];
    for (int i = threadIdx.x * 8; i < 8192; i += 256 * 8)
        *(half8*)(sw + i) = *(const half8*)(wpack + i);
    __syncthreads();
    int lane = threadIdx.x & 63;
    int wv = (blockIdx.x * 256 + threadIdx.x) >> 6;
    int row0 = wv * 16;
    if (row0 >= N_ENT) return;
    int m = lane & 15;
    int quad = lane >> 4;

    const _Float16* kgr = kg16 + (size_t)(row0 + m) * DD + quad * 8;
    const _Float16* igr = ig16 + (size_t)(row0 + m) * DD + quad * 8;
    half8 akg0 = *(const half8*)(kgr);
    half8 akg1 = *(const half8*)(kgr + 32);
    half8 aig0 = *(const half8*)(igr);
    half8 aig1 = *(const half8*)(igr + 32);

    floatx4 acc[4];
#pragma unroll
    for (int t = 0; t < 4; ++t) {
        half8 bA0 = *(const half8*)(sw + 0 * 4096 + 0 * 2048 + t * 512 + lane * 8);
        half8 bA1 = *(const half8*)(sw + 0 * 4096 + 1 * 2048 + t * 512 + lane * 8);
        half8 bB0 = *(const half8*)(sw + 1 * 4096 + 0 * 2048 + t * 512 + lane * 8);
        half8 bB1 = *(const half8*)(sw + 1 * 4096 + 1 * 2048 + t * 512 + lane * 8);
        floatx4 c = {0.f, 0.f, 0.f, 0.f};
        c = __builtin_amdgcn_mfma_f32_16x16x32_f16(akg0, bA0, c, 0, 0, 0);
        c = __builtin_amdgcn_mfma_f32_16x16x32_f16(akg1, bA1, c, 0, 0, 0);
        c = __builtin_amdgcn_mfma_f32_16x16x32_f16(aig0, bB0, c, 0, 0, 0);
        c = __builtin_amdgcn_mfma_f32_16x16x32_f16(aig1, bB1, c, 0, 0, 0);
        acc[t] = c;
    }

#pragma unroll
    for (int t = 0; t < 4; ++t) {
#pragma unroll
        for (int r = 0; r < 4; ++r) {
            int row = quad * 4 + r;
            int col = t * 16 + m;
            size_t o = (size_t)(row0 + row) * DD + col;
            float kv = (float)kg16[o];
            float cv = (float)ig16[o];
            float g = 1.f / (1.f + expf(-acc[t][r]));
            dual16[o] = (_Float16)(g * kv + (1.f - g) * cv);
        }
    }
}

// user rows: dual16 <- ig16 (vectorized fp16 copy)
__global__ void k_usercopy(const _Float16* __restrict__ ig16, _Float16* __restrict__ dual16) {
    int i = blockIdx.x * 256 + threadIdx.x;
    if (i >= N_USR * DD / 8) return;
    size_t o = (size_t)N_ENT * DD / 8 + i;
    ((half8*)dual16)[o] = ((const half8*)ig16)[o];
}

// init: dual16 = fp16(embed)
__global__ void k_init(const float* __restrict__ embed, _Float16* __restrict__ dual16) {
    int i = blockIdx.x * blockDim.x + threadIdx.x;
    if (i >= N_TOT * DD) return;
    dual16[i] = (_Float16)embed[i];
}

// ---------------------------------------------------------------------------
// out[u,j] = sums[user_ids[u]] . sums[item_ids[j]],
// sums[row] = embed[row] + ig0[row] + ig1[row] + ig2[row] (reconstructed).
// 256 blocks: 64 user-groups (16 users) x 4 item-quarters (512 items).
// ---------------------------------------------------------------------------
__global__ __launch_bounds__(256) void k_out(const float* __restrict__ embed,
        const _Float16* __restrict__ ig0, const _Float16* __restrict__ ig1,
        const _Float16* __restrict__ ig2, const int* __restrict__ user_ids,
        const int* __restrict__ item_ids, float* __restrict__ out) {
    __shared__ float uvec[16 * DD];
    int ug = blockIdx.x >> 2;
    int qi = blockIdx.x & 3;
    int ub = ug * 16;
    for (int i = threadIdx.x; i < 16 * DD; i += 256) {
        int uu = i >> 6, d = i & 63;
        size_t o = (size_t)user_ids[ub + uu] * DD + d;
        uvec[i] = embed[o] + (float)ig0[o] + (float)ig1[o] + (float)ig2[o];
    }
    __syncthreads();
    int jbase = qi * 512;
    for (int j = threadIdx.x; j < 512; j += 256) {
        size_t ro = (size_t)item_ids[jbase + j] * DD;
        float acc[16];
#pragma unroll
        for (int u = 0; u < 16; ++u) acc[u] = 0.f;
        for (int d = 0; d < DD; d += 4) {
            float4 ev = *(const float4*)(embed + ro + d);
            half4 h0 = *(const half4*)(ig0 + ro + d);
            half4 h1 = *(const half4*)(ig1 + ro + d);
            half4 h2 = *(const half4*)(ig2 + ro + d);
            float iv0 = ev.x + (float)h0[0] + (float)h1[0] + (float)h2[0];
            float iv1 = ev.y + (float)h0[1] + (float)h1[1] + (float)h2[1];
            float iv2 = ev.z + (float)h0[2] + (float)h1[2] + (float)h2[2];
            float iv3 = ev.w + (float)h0[3] + (float)h1[3] + (float)h2[3];
#pragma unroll
            for (int u = 0; u < 16; ++u) {
                acc[u] = fmaf(iv0, uvec[u * DD + d + 0], acc[u]);
                acc[u] = fmaf(iv1, uvec[u * DD + d + 1], acc[u]);
                acc[u] = fmaf(iv2, uvec[u * DD + d + 2], acc[u]);
                acc[u] = fmaf(iv3, uvec[u * DD + d + 3], acc[u]);
            }
        }
#pragma unroll
        for (int u = 0; u < 16; ++u)
            out[(size_t)(ub + u) * 2048 + jbase + j] = acc[u];
    }
}

extern "C" void kernel_launch(void* const* d_in, const int* in_sizes, int n_in,
                              void* d_out, int out_size, void* d_ws, size_t ws_size,
                              hipStream_t stream) {
    const float* embed   = (const float*)d_in[0];
    const float* rel     = (const float*)d_in[1];
    const float* Wk_w    = (const float*)d_in[2];
    const float* Wk_b    = (const float*)d_in[3];
    const float* Wa      = (const float*)d_in[4];
    const float* Wb      = (const float*)d_in[5];
    const int*   kg_h    = (const int*)d_in[6];
    const int*   kg_t    = (const int*)d_in[7];
    const int*   kg_r    = (const int*)d_in[8];
    const int*   ain_row = (const int*)d_in[9];
    const int*   ain_col = (const int*)d_in[10];
    const float* ain_val = (const float*)d_in[11];
    const int*   user_ids = (const int*)d_in[12];
    const int*   item_ids = (const int*)d_in[13];
    int E_KG = in_sizes[6];
    int E_CF = in_sizes[9];
    int E_TOT = E_KG + E_CF;
    float* out = (float*)d_out;

    int NT  = (E_TOT + SORT_T - 1) / SORT_T;   // phase-1 tiles (733)
    int NTC = NBUK * NT;                        // scan length

    float* ws = (float*)d_ws;
    size_t off = 0;
    float* uvr       = ws + off; off += 16 * 132;
    float* Puv       = ws + off; off += (size_t)N_ENT * 32;
    int*   rowptr    = (int*)(ws + off); off += N_ROWS + 4;
    int*   tilecnt   = (int*)(ws + off); off += (size_t)NTC + 4;
    int*   tilescan  = (int*)(ws + off); off += (size_t)NTC + 4;
    int*   bsum      = (int*)(ws + off); off += 1024;
    int2*  pairbuf   = (int2*)(ws + off); off += 2 * (size_t)E_TOT;   // final (row-sorted)
    _Float16* dual16 = (_Float16*)(ws + off); off += (size_t)N_TOT * DD / 2;
    _Float16* ig16_0 = (_Float16*)(ws + off); off += (size_t)N_TOT * DD / 2;
    _Float16* ig16_1 = (_Float16*)(ws + off); off += (size_t)N_TOT * DD / 2;
    _Float16* ig16_2 = (_Float16*)(ws + off); off += (size_t)N_TOT * DD / 2;
    _Float16* kg16A  = (_Float16*)(ws + off); off += (size_t)N_ENT * DD / 2;
    _Float16* kg16B  = (_Float16*)(ws + off); off += (size_t)N_ENT * DD / 2;
    _Float16* wpack  = (_Float16*)(ws + off); off += 8192 / 2;
    int2*  bufA      = (int2*)kg16A;   // alias: 24MB <= kg16A+kg16B (25.6MB); dead before layer0
    _Float16* ig_l[3] = {ig16_0, ig16_1, ig16_2};

    // --- binning sort: hist -> scan -> tile scatter -> per-bucket fine ---
    hipLaunchKernelGGL(k_sort_hist, dim3(NT), dim3(256), 0, stream,
                       kg_h, ain_row, tilecnt, E_KG, E_TOT, NT);
    int nb = (NTC + SCAN_ITEMS - 1) / SCAN_ITEMS;   // 367
    hipLaunchKernelGGL(k_blocksum, dim3(nb), dim3(SCAN_BLK), 0, stream, tilecnt, bsum, NTC);
    hipLaunchKernelGGL(k_bscan, dim3(1), dim3(1024), 0, stream, bsum, nb, tilescan + NTC);
    hipLaunchKernelGGL(k_scan_apply, dim3(nb), dim3(SCAN_BLK), 0, stream,
                       tilecnt, tilescan, bsum, NTC);
    hipLaunchKernelGGL(k_sort_scatter, dim3(NT), dim3(256), 0, stream,
                       kg_h, kg_t, kg_r, ain_row, ain_col, ain_val, tilescan,
                       bufA, E_KG, E_TOT, NT);
    int nbuk_used = (N_ROWS + (1 << BUK_SHIFT) - 1) >> BUK_SHIFT;   // 489
    hipLaunchKernelGGL(k_sort_fine, dim3(nbuk_used), dim3(256), 0, stream,
                       tilescan, bufA, pairbuf, rowptr, NT);

    // --- attention: rel -> projections -> per-row logits/softmax ---
    hipLaunchKernelGGL(k_rel, dim3(16), dim3(128), 0, stream, Wk_w, Wk_b, rel, uvr);
    hipLaunchKernelGGL(k_proj, dim3((N_ENT + 7) / 8), dim3(256), 0, stream, embed, uvr, Puv);
    hipLaunchKernelGGL(k_rowdiv2, dim3((N_ENT * 64 + 255) / 256), dim3(256), 0, stream,
                       rowptr, pairbuf, Puv, uvr);
    hipLaunchKernelGGL(k_init, dim3((N_TOT * DD + 255) / 256), dim3(256), 0, stream,
                       embed, dual16);
    hipLaunchKernelGGL(k_wcvt, dim3(32), dim3(256), 0, stream, Wa, Wb, wpack);

    // --- 3 propagation layers ---
    const _Float16* cur16 = dual16;       // layer0 KG gather table = fp16 embed
    _Float16* kg16o = kg16A;
    _Float16* kg16alt = kg16B;
    int spmm_blocks = ((size_t)N_ROWS * 64 + 255) / 256;
    int gate_blocks = (N_ENT / 16 + 3) / 4;
    int uc_blocks = (N_USR * DD / 8 + 255) / 256;
    for (int layer = 0; layer < 3; ++layer) {
        hipLaunchKernelGGL(k_spmm_u, dim3(spmm_blocks), dim3(256), 0, stream,
                           rowptr, pairbuf, cur16, dual16, kg16o, ig_l[layer]);
        hipLaunchKernelGGL(k_gate3, dim3(gate_blocks), dim3(256), 0, stream,
                           kg16o, ig_l[layer], wpack, dual16);
        hipLaunchKernelGGL(k_usercopy, dim3(uc_blocks), dim3(256), 0, stream,
                           ig_l[layer], dual16);
        cur16 = kg16o;
        kg16o = kg16alt;
        kg16alt = (_Float16*)cur16;
    }

    // --- final gather-GEMM 1024 x 2048 x 64 with on-the-fly sums ---
    hipLaunchKernelGGL(k_out, dim3(256), dim3(256), 0, stream,
                       embed, ig16_0, ig16_1, ig16_2, user_ids, item_ids, out);
}

// Round 9
// 681.790 us; speedup vs baseline: 2.3358x; 1.0858x over previous
//
#include <hip/hip_runtime.h>
#include <math.h>

#define N_ENT 100000
#define N_USR 50000
#define N_TOT 150000
#define N_ROWS 250000     // unified rows: KG [0,N_ENT) + CF [N_ENT, N_ENT+N_TOT)
#define DD 64

#define SCAN_BLK 256
#define SCAN_ITEMS 1024   // elements per scan block

#define SORT_T 4096       // edges per phase-1 tile
#define BUK_SHIFT 8       // 256 rows per bucket
#define NBUKU 977         // ceil(N_ROWS / 256)
#define LDSCAP 5120       // phase-2 LDS segment capacity (KG bucket mean 3840, std ~62)

typedef _Float16 half8 __attribute__((ext_vector_type(8)));
typedef _Float16 half4 __attribute__((ext_vector_type(4)));
typedef float floatx4 __attribute__((ext_vector_type(4)));

// ---------------------------------------------------------------------------
// Per-relation precompute: u_r = Wk_w[0:64]@r, v_r = Wk_w[64:128]@r, c_r = b@r
// uvr layout: [16][132]: u at 0..63, v at 64..127, c at 128
// ---------------------------------------------------------------------------
__global__ void k_rel(const float* __restrict__ Wk_w, const float* __restrict__ Wk_b,
                      const float* __restrict__ rel, float* __restrict__ uvr) {
    int r = blockIdx.x;   // 16 blocks
    int k = threadIdx.x;  // 128 threads
    const float* rv = rel + r * DD;
    const float* wrow = Wk_w + k * DD;
    float s = 0.f;
    for (int j = 0; j < DD; ++j) s += wrow[j] * rv[j];
    uvr[r * 132 + k] = s;
    if (k == 0) {
        float c = 0.f;
        for (int j = 0; j < DD; ++j) c += Wk_b[j] * rv[j];
        uvr[r * 132 + 128] = c;
    }
}

// ---------------------------------------------------------------------------
// Per-entity projections: Puv[n][r] = embed[n].u_r ; Puv[n][16+r] = embed[n].v_r
// ---------------------------------------------------------------------------
__global__ __launch_bounds__(256) void k_proj(const float* __restrict__ embed,
        const float* __restrict__ uvr, float* __restrict__ Puv) {
    __shared__ float suvr[16 * 128];
    for (int i = threadIdx.x; i < 16 * 128; i += 256)
        suvr[i] = uvr[(i >> 7) * 132 + (i & 127)];
    __syncthreads();
    int rowi = threadIdx.x >> 5;
    int sub = threadIdx.x & 31;
    int r = sub & 15, w = sub >> 4;
    int row = blockIdx.x * 8 + rowi;
    if (row >= N_ENT) return;
    const float* er = embed + (size_t)row * DD;
    const float* uv = suvr + r * 128 + w * 64;
    float s = 0.f;
    for (int d = 0; d < DD; ++d) s = fmaf(er[d], uv[d], s);
    Puv[(size_t)row * 32 + sub] = s;
}

// ---------------------------------------------------------------------------
// Sort phase 0: per-tile bucket histogram. tilecnt[b * NT + tile] = count.
// Every (b,tile) cell written -> no memset needed.
// ---------------------------------------------------------------------------
__global__ __launch_bounds__(256) void k_sort_hist(const int* __restrict__ kg_h,
        const int* __restrict__ ain_row, int* __restrict__ tilecnt,
        int E_KG, int E_TOT, int NT) {
    __shared__ int hist[1024];
#pragma unroll
    for (int k = 0; k < 4; ++k) hist[k * 256 + threadIdx.x] = 0;
    __syncthreads();
    int tile = blockIdx.x;
    int base = tile * SORT_T;
#pragma unroll
    for (int k = 0; k < SORT_T / 256; ++k) {
        int e = base + k * 256 + threadIdx.x;
        if (e < E_TOT) {
            int row = (e < E_KG) ? kg_h[e] : (N_ENT + ain_row[e - E_KG]);
            atomicAdd(&hist[row >> BUK_SHIFT], 1);
        }
    }
    __syncthreads();
    for (int b = threadIdx.x; b < NBUKU; b += 256)
        tilecnt[b * NT + tile] = hist[b];
}

// --- multi-block exclusive scan, phase 1: per-chunk partial sums ---
__global__ __launch_bounds__(SCAN_BLK) void k_blocksum(const int* __restrict__ cnt,
                                                       int* __restrict__ bsum, int n) {
    __shared__ int s[SCAN_BLK];
    int base = blockIdx.x * SCAN_ITEMS;
    int sum = 0;
    for (int i = threadIdx.x; i < SCAN_ITEMS; i += SCAN_BLK) {
        int idx = base + i;
        if (idx < n) sum += cnt[idx];
    }
    s[threadIdx.x] = sum;
    __syncthreads();
    for (int off = SCAN_BLK / 2; off; off >>= 1) {
        if (threadIdx.x < off) s[threadIdx.x] += s[threadIdx.x + off];
        __syncthreads();
    }
    if (threadIdx.x == 0) bsum[blockIdx.x] = s[0];
}

// --- phase 2: single-block exclusive scan of partials (nb <= 1024) ---
__global__ __launch_bounds__(1024) void k_bscan(int* __restrict__ bsum, int nb,
                                                int* __restrict__ total_out) {
    __shared__ int s[1024];
    int tid = threadIdx.x;
    int v = (tid < nb) ? bsum[tid] : 0;
    s[tid] = v;
    __syncthreads();
    for (int off = 1; off < 1024; off <<= 1) {
        int t = (tid >= off) ? s[tid - off] : 0;
        __syncthreads();
        s[tid] += t;
        __syncthreads();
    }
    if (tid < nb) bsum[tid] = s[tid] - v;   // exclusive
    if (tid == 1023) *total_out = s[1023];
}

// --- phase 3: block-local scan + offset; writes scanned values ---
__global__ __launch_bounds__(SCAN_BLK) void k_scan_apply(const int* __restrict__ cnt,
        int* __restrict__ scanned, const int* __restrict__ bsum, int n) {
    __shared__ int s[SCAN_BLK];
    int base = blockIdx.x * SCAN_ITEMS;
    int t = threadIdx.x;
    int idx0 = base + t * 4;
    int v[4];
    int lsum = 0;
#pragma unroll
    for (int k = 0; k < 4; ++k) {
        int idx = idx0 + k;
        v[k] = (idx < n) ? cnt[idx] : 0;
        lsum += v[k];
    }
    s[t] = lsum;
    __syncthreads();
    for (int off = 1; off < SCAN_BLK; off <<= 1) {
        int tv = (t >= off) ? s[t - off] : 0;
        __syncthreads();
        s[t] += tv;
        __syncthreads();
    }
    int pre = (t ? s[t - 1] : 0) + bsum[blockIdx.x];
#pragma unroll
    for (int k = 0; k < 4; ++k) {
        int idx = idx0 + k;
        if (idx < n) scanned[idx] = pre;
        pre += v[k];
    }
}

// ---------------------------------------------------------------------------
// Sort phase 1: direct run writes. Per tile: LDS cursor per bucket; each edge
// writes its int2 payload to gbase[bucket] + slot. Runs (~4 edges) contiguous.
// Payload: KG: x = t | r<<17 | rlow<<22, y = junk (filled by softmax later)
//          CF: x = col | rlow<<22,       y = bits(val)        (rlow = row&255)
// ---------------------------------------------------------------------------
__global__ __launch_bounds__(256) void k_sort_scatter(const int* __restrict__ kg_h,
        const int* __restrict__ kg_t, const int* __restrict__ kg_r,
        const int* __restrict__ ain_row, const int* __restrict__ ain_col,
        const float* __restrict__ ain_val, const int* __restrict__ tilescan,
        int2* __restrict__ bufA, int E_KG, int E_TOT, int NT) {
    __shared__ int cur[1024];
    __shared__ int gbase[1024];
    int tid = threadIdx.x;
    int tile = blockIdx.x;
#pragma unroll
    for (int k = 0; k < 4; ++k) cur[k * 256 + tid] = 0;
    for (int b = tid; b < NBUKU; b += 256) gbase[b] = tilescan[b * NT + tile];
    __syncthreads();
    int base = tile * SORT_T;
#pragma unroll
    for (int k = 0; k < SORT_T / 256; ++k) {
        int e = base + k * 256 + tid;
        if (e < E_TOT) {
            int row, x, y;
            if (e < E_KG) {
                row = kg_h[e];
                x = kg_t[e] | (kg_r[e] << 17) | ((row & 255) << 22);
                y = 0;
            } else {
                int i = e - E_KG;
                row = N_ENT + ain_row[i];
                x = ain_col[i] | ((row & 255) << 22);
                y = __float_as_int(ain_val[i]);
            }
            int b = row >> BUK_SHIFT;
            int slot = atomicAdd(&cur[b], 1);
            bufA[gbase[b] + slot] = make_int2(x, y);
        }
    }
}

// ---------------------------------------------------------------------------
// Sort phase 2 + FUSED SEGMENT SOFTMAX. One block per bucket (256 rows).
// Row-hist + scan in LDS, emit rowptr, row-sort segment in LDS, then for KG
// rows: logits from Puv, exp, per-row LDS sum, scale; coalesced write-out.
// ---------------------------------------------------------------------------
__global__ __launch_bounds__(256) void k_sort_fine(const int* __restrict__ tilescan,
        const int2* __restrict__ bufA, int2* __restrict__ pairbuf,
        int* __restrict__ rowptr, const float* __restrict__ Puv,
        const float* __restrict__ uvr, int NT) {
    __shared__ int2 seg[LDSCAP];    // 40 KB
    __shared__ int rcnt[256];
    __shared__ int rexc[256];
    __shared__ int rcur[256];
    __shared__ float rsum[256];
    __shared__ float c16[16];
    int tid = threadIdx.x;
    int b = blockIdx.x;
    rcnt[tid] = 0;
    rsum[tid] = 0.f;
    if (tid < 16) c16[tid] = uvr[tid * 132 + 128];
    __syncthreads();

    int base = tilescan[b * NT];
    int endo = tilescan[(b + 1) * NT];
    int bsize = endo - base;
    int growbase = b << BUK_SHIFT;

    // pass 1: row histogram
    for (int i = base + tid; i < endo; i += 256) {
        unsigned rlow = ((unsigned)bufA[i].x) >> 22;
        atomicAdd(&rcnt[rlow], 1);
    }
    __syncthreads();

    // exclusive scan of rcnt[256] (Hillis-Steele via rexc)
    {
        int v = rcnt[tid];
        rexc[tid] = v;
        __syncthreads();
        for (int off = 1; off < 256; off <<= 1) {
            int t = (tid >= off) ? rexc[tid - off] : 0;
            __syncthreads();
            rexc[tid] += t;
            __syncthreads();
        }
        int ex = rexc[tid] - v;     // exclusive
        rexc[tid] = ex;
        rcur[tid] = ex;
        int row = growbase + tid;
        if (row <= N_ROWS) rowptr[row] = base + ex;
    }
    __syncthreads();

    if (bsize <= LDSCAP) {
        // fine scatter into LDS
        for (int i = base + tid; i < endo; i += 256) {
            int2 p = bufA[i];
            unsigned rlow = ((unsigned)p.x) >> 22;
            seg[atomicAdd(&rcur[rlow], 1)] = p;
        }
        __syncthreads();
        // softmax numerators for KG rows
        for (int i = tid; i < bsize; i += 256) {
            int2 p = seg[i];
            unsigned rlow = ((unsigned)p.x) >> 22;
            int grow = growbase + (int)rlow;
            if (grow < N_ENT) {
                int t = p.x & 0x1FFFF;
                int r = (p.x >> 17) & 15;
                float lg = Puv[(size_t)t * 32 + r] + Puv[(size_t)grow * 32 + 16 + r] + c16[r];
                lg = lg >= 0.f ? lg : 0.01f * lg;
                // softmax is shift-invariant; |logit| << 1 so skip segment-max
                float exv = expf(lg);
                seg[i].y = __float_as_int(exv);
                atomicAdd(&rsum[rlow], exv);
            }
        }
        __syncthreads();
        rsum[tid] = 1.f / rsum[tid];   // unused for CF/empty rows
        __syncthreads();
        // scaled, coalesced write-out
        for (int i = tid; i < bsize; i += 256) {
            int2 p = seg[i];
            unsigned rlow = ((unsigned)p.x) >> 22;
            if (growbase + (int)rlow < N_ENT)
                p.y = __float_as_int(__int_as_float(p.y) * rsum[rlow]);
            pairbuf[base + i] = p;
        }
    } else {
        // overflow fallback (statistically never): operate on global
        for (int i = base + tid; i < endo; i += 256) {
            int2 p = bufA[i];
            unsigned rlow = ((unsigned)p.x) >> 22;
            int slot = atomicAdd(&rcur[rlow], 1);
            pairbuf[base + slot] = p;
        }
        __syncthreads();
        for (int i = base + tid; i < endo; i += 256) {
            int2 p = pairbuf[i];
            unsigned rlow = ((unsigned)p.x) >> 22;
            int grow = growbase + (int)rlow;
            if (grow < N_ENT) {
                int t = p.x & 0x1FFFF;
                int r = (p.x >> 17) & 15;
                float lg = Puv[(size_t)t * 32 + r] + Puv[(size_t)grow * 32 + 16 + r] + c16[r];
                lg = lg >= 0.f ? lg : 0.01f * lg;
                float exv = expf(lg);
                pairbuf[i].y = __float_as_int(exv);
                atomicAdd(&rsum[rlow], exv);
            }
        }
        __syncthreads();
        rsum[tid] = 1.f / rsum[tid];
        __syncthreads();
        for (int i = base + tid; i < endo; i += 256) {
            int2 p = pairbuf[i];
            unsigned rlow = ((unsigned)p.x) >> 22;
            if (growbase + (int)rlow < N_ENT)
                pairbuf[i].y = __float_as_int(__int_as_float(p.y) * rsum[rlow]);
        }
    }
}

// ---------------------------------------------------------------------------
// Pack Wa,Wb into fp16 MFMA B-fragment layout (16 KB).
// ---------------------------------------------------------------------------
__global__ void k_wcvt(const float* __restrict__ Wa, const float* __restrict__ Wb,
                       _Float16* __restrict__ wpack) {
    int i = blockIdx.x * 256 + threadIdx.x;
    if (i >= 8192) return;
    int m = i >> 12;
    int rem = i & 4095;
    int kstep = rem >> 11;
    int rem2 = rem & 2047;
    int ntile = rem2 >> 9;
    int rem3 = rem2 & 511;
    int lane = rem3 >> 3;
    int j = rem3 & 7;
    int k = kstep * 32 + (lane >> 4) * 8 + j;
    int n = ntile * 16 + (lane & 15);
    const float* W = m ? Wb : Wa;
    wpack[i] = (_Float16)W[k * 64 + n];
}

// ---------------------------------------------------------------------------
// Unified KG+CF CSR SpMM, wave per row, lane = dim, fp16 in/out, int2 pairs.
// row_begin lets layer 2 run the CF half only (layer-2 KG result is dead code).
// ---------------------------------------------------------------------------
__global__ __launch_bounds__(256) void k_spmm_u(const int* __restrict__ rowptr,
        const int2* __restrict__ pairbuf, const _Float16* __restrict__ cur16,
        const _Float16* __restrict__ dual16, _Float16* __restrict__ kg16o,
        _Float16* __restrict__ ig16, int row_begin) {
    int wid0 = row_begin + ((blockIdx.x * 256 + threadIdx.x) >> 6);
    int wid = __builtin_amdgcn_readfirstlane(wid0);
    if (wid >= N_ROWS) return;
    int lane = threadIdx.x & 63;
    bool is_kg = wid < N_ENT;
    const _Float16* x = is_kg ? cur16 : dual16;
    int cmask = is_kg ? 0x1FFFF : 0x3FFFF;
    int s = rowptr[wid], e = rowptr[wid + 1];
    float a0 = 0.f, a1 = 0.f, a2 = 0.f, a3 = 0.f;
    int i = s;
    for (; i + 4 <= e; i += 4) {
        int2 p0 = pairbuf[i], p1 = pairbuf[i + 1], p2 = pairbuf[i + 2], p3 = pairbuf[i + 3];
        a0 = fmaf(__int_as_float(p0.y), (float)x[(size_t)(p0.x & cmask) * DD + lane], a0);
        a1 = fmaf(__int_as_float(p1.y), (float)x[(size_t)(p1.x & cmask) * DD + lane], a1);
        a2 = fmaf(__int_as_float(p2.y), (float)x[(size_t)(p2.x & cmask) * DD + lane], a2);
        a3 = fmaf(__int_as_float(p3.y), (float)x[(size_t)(p3.x & cmask) * DD + lane], a3);
    }
    for (; i < e; ++i) {
        int2 p = pairbuf[i];
        a0 = fmaf(__int_as_float(p.y), (float)x[(size_t)(p.x & cmask) * DD + lane], a0);
    }
    float res = (a0 + a1) + (a2 + a3);
    _Float16* o = is_kg ? (kg16o + (size_t)wid * DD) : (ig16 + (size_t)(wid - N_ENT) * DD);
    o[lane] = (_Float16)res;
}

// ---------------------------------------------------------------------------
// Entity gate via MFMA (one wave = 16 rows), FUSED with user passthrough copy:
// blocks >= ngate copy ig16 user rows into dual16 (half8).
// acc = kg@Wa + ig@Wb in one accumulator chain.
// C/D: col=lane&15, row=(lane>>4)*4+reg [m89-verified].
// ---------------------------------------------------------------------------
__global__ __launch_bounds__(256) void k_gate3(const _Float16* __restrict__ kg16,
        const _Float16* __restrict__ ig16, const _Float16* __restrict__ wpack,
        _Float16* __restrict__ dual16, int ngate) {
    __shared__ _Float16 sw[8192];
    if ((int)blockIdx.x >= ngate) {
        int i = ((int)blockIdx.x - ngate) * 256 + threadIdx.x;
        if (i < N_USR * DD / 8) {
            size_t o = (size_t)N_ENT * DD / 8 + i;
            ((half8*)dual16)[o] = ((const half8*)ig16)[o];
        }
        return;
    }
    for (int i = threadIdx.x * 8; i < 8192; i += 256 * 8)
        *(half8*)(sw + i) = *(const half8*)(wpack + i);
    __syncthreads();
    int lane = threadIdx.x & 63;
    int wv = (blockIdx.x * 256 + threadIdx.x) >> 6;
    int row0 = wv * 16;
    if (row0 >= N_ENT) return;
    int m = lane & 15;
    int quad = lane >> 4;

    const _Float16* kgr = kg16 + (size_t)(row0 + m) * DD + quad * 8;
    const _Float16* igr = ig16 + (size_t)(row0 + m) * DD + quad * 8;
    half8 akg0 = *(const half8*)(kgr);
    half8 akg1 = *(const half8*)(kgr + 32);
    half8 aig0 = *(const half8*)(igr);
    half8 aig1 = *(const half8*)(igr + 32);

    floatx4 acc[4];
#pragma unroll
    for (int t = 0; t < 4; ++t) {
        half8 bA0 = *(const half8*)(sw + 0 * 4096 + 0 * 2048 + t * 512 + lane * 8);
        half8 bA1 = *(const half8*)(sw + 0 * 4096 + 1 * 2048 + t * 512 + lane * 8);
        half8 bB0 = *(const half8*)(sw + 1 * 4096 + 0 * 2048 + t * 512 + lane * 8);
        half8 bB1 = *(const half8*)(sw + 1 * 4096 + 1 * 2048 + t * 512 + lane * 8);
        floatx4 c = {0.f, 0.f, 0.f, 0.f};
        c = __builtin_amdgcn_mfma_f32_16x16x32_f16(akg0, bA0, c, 0, 0, 0);
        c = __builtin_amdgcn_mfma_f32_16x16x32_f16(akg1, bA1, c, 0, 0, 0);
        c = __builtin_amdgcn_mfma_f32_16x16x32_f16(aig0, bB0, c, 0, 0, 0);
        c = __builtin_amdgcn_mfma_f32_16x16x32_f16(aig1, bB1, c, 0, 0, 0);
        acc[t] = c;
    }

#pragma unroll
    for (int t = 0; t < 4; ++t) {
#pragma unroll
        for (int r = 0; r < 4; ++r) {
            int row = quad * 4 + r;
            int col = t * 16 + m;
            size_t o = (size_t)(row0 + row) * DD + col;
            float kv = (float)kg16[o];
            float cv = (float)ig16[o];
            float g = 1.f / (1.f + expf(-acc[t][r]));
            dual16[o] = (_Float16)(g * kv + (1.f - g) * cv);
        }
    }
}

// init: dual16 = fp16(embed)
__global__ void k_init(const float* __restrict__ embed, _Float16* __restrict__ dual16) {
    int i = blockIdx.x * blockDim.x + threadIdx.x;
    if (i >= N_TOT * DD) return;
    dual16[i] = (_Float16)embed[i];
}

// ---------------------------------------------------------------------------
// out[u,j] = sums[user_ids[u]] . sums[item_ids[j]],
// sums[row] = embed[row] + ig0[row] + ig1[row] + ig2[row] (reconstructed).
// 256 blocks: 32 user-groups (32 users) x 8 item-chunks (256 items).
// ---------------------------------------------------------------------------
__global__ __launch_bounds__(256) void k_out(const float* __restrict__ embed,
        const _Float16* __restrict__ ig0, const _Float16* __restrict__ ig1,
        const _Float16* __restrict__ ig2, const int* __restrict__ user_ids,
        const int* __restrict__ item_ids, float* __restrict__ out) {
    __shared__ float uvec[32 * DD];
    int ug = blockIdx.x >> 3;
    int qi = blockIdx.x & 7;
    int ub = ug * 32;
    for (int i = threadIdx.x; i < 32 * DD; i += 256) {
        int uu = i >> 6, d = i & 63;
        size_t o = (size_t)user_ids[ub + uu] * DD + d;
        uvec[i] = embed[o] + (float)ig0[o] + (float)ig1[o] + (float)ig2[o];
    }
    __syncthreads();
    int jbase = qi * 256;
    for (int j = threadIdx.x; j < 256; j += 256) {
        size_t ro = (size_t)item_ids[jbase + j] * DD;
        float acc[32];
#pragma unroll
        for (int u = 0; u < 32; ++u) acc[u] = 0.f;
        for (int d = 0; d < DD; d += 4) {
            float4 ev = *(const float4*)(embed + ro + d);
            half4 h0 = *(const half4*)(ig0 + ro + d);
            half4 h1 = *(const half4*)(ig1 + ro + d);
            half4 h2 = *(const half4*)(ig2 + ro + d);
            float iv0 = ev.x + (float)h0[0] + (float)h1[0] + (float)h2[0];
            float iv1 = ev.y + (float)h0[1] + (float)h1[1] + (float)h2[1];
            float iv2 = ev.z + (float)h0[2] + (float)h1[2] + (float)h2[2];
            float iv3 = ev.w + (float)h0[3] + (float)h1[3] + (float)h2[3];
#pragma unroll
            for (int u = 0; u < 32; ++u) {
                acc[u] = fmaf(iv0, uvec[u * DD + d + 0], acc[u]);
                acc[u] = fmaf(iv1, uvec[u * DD + d + 1], acc[u]);
                acc[u] = fmaf(iv2, uvec[u * DD + d + 2], acc[u]);
                acc[u] = fmaf(iv3, uvec[u * DD + d + 3], acc[u]);
            }
        }
#pragma unroll
        for (int u = 0; u < 32; ++u)
            out[(size_t)(ub + u) * 2048 + jbase + j] = acc[u];
    }
}

extern "C" void kernel_launch(void* const* d_in, const int* in_sizes, int n_in,
                              void* d_out, int out_size, void* d_ws, size_t ws_size,
                              hipStream_t stream) {
    const float* embed   = (const float*)d_in[0];
    const float* rel     = (const float*)d_in[1];
    const float* Wk_w    = (const float*)d_in[2];
    const float* Wk_b    = (const float*)d_in[3];
    const float* Wa      = (const float*)d_in[4];
    const float* Wb      = (const float*)d_in[5];
    const int*   kg_h    = (const int*)d_in[6];
    const int*   kg_t    = (const int*)d_in[7];
    const int*   kg_r    = (const int*)d_in[8];
    const int*   ain_row = (const int*)d_in[9];
    const int*   ain_col = (const int*)d_in[10];
    const float* ain_val = (const float*)d_in[11];
    const int*   user_ids = (const int*)d_in[12];
    const int*   item_ids = (const int*)d_in[13];
    int E_KG = in_sizes[6];
    int E_CF = in_sizes[9];
    int E_TOT = E_KG + E_CF;
    float* out = (float*)d_out;

    int NT  = (E_TOT + SORT_T - 1) / SORT_T;   // phase-1 tiles (733)
    int NTC = NBUKU * NT;                       // scan length (~716K)

    float* ws = (float*)d_ws;
    size_t off = 0;
    float* uvr       = ws + off; off += 16 * 132;
    float* Puv       = ws + off; off += (size_t)N_ENT * 32;
    int*   rowptr    = (int*)(ws + off); off += N_ROWS + 4;
    int*   tilecnt   = (int*)(ws + off); off += (size_t)NTC + 4;
    int*   tilescan  = (int*)(ws + off); off += (size_t)NTC + 4;
    int*   bsum      = (int*)(ws + off); off += 1024;
    int2*  pairbuf   = (int2*)(ws + off); off += 2 * (size_t)E_TOT;   // final (row-sorted)
    _Float16* dual16 = (_Float16*)(ws + off); off += (size_t)N_TOT * DD / 2;
    _Float16* ig16_0 = (_Float16*)(ws + off); off += (size_t)N_TOT * DD / 2;
    _Float16* ig16_1 = (_Float16*)(ws + off); off += (size_t)N_TOT * DD / 2;
    _Float16* ig16_2 = (_Float16*)(ws + off); off += (size_t)N_TOT * DD / 2;
    _Float16* kg16A  = (_Float16*)(ws + off); off += (size_t)N_ENT * DD / 2;
    _Float16* kg16B  = (_Float16*)(ws + off); off += (size_t)N_ENT * DD / 2;
    _Float16* wpack  = (_Float16*)(ws + off); off += 8192 / 2;
    int2*  bufA      = (int2*)kg16A;   // alias: 24MB <= kg16A+kg16B (25.6MB); dead before layer0
    _Float16* ig_l[3] = {ig16_0, ig16_1, ig16_2};

    // --- attention precompute (needed by fused sort+softmax) ---
    hipLaunchKernelGGL(k_rel, dim3(16), dim3(128), 0, stream, Wk_w, Wk_b, rel, uvr);
    hipLaunchKernelGGL(k_proj, dim3((N_ENT + 7) / 8), dim3(256), 0, stream, embed, uvr, Puv);

    // --- binning sort: hist -> scan -> tile scatter -> fine sort + softmax ---
    hipLaunchKernelGGL(k_sort_hist, dim3(NT), dim3(256), 0, stream,
                       kg_h, ain_row, tilecnt, E_KG, E_TOT, NT);
    int nb = (NTC + SCAN_ITEMS - 1) / SCAN_ITEMS;   // ~700
    hipLaunchKernelGGL(k_blocksum, dim3(nb), dim3(SCAN_BLK), 0, stream, tilecnt, bsum, NTC);
    hipLaunchKernelGGL(k_bscan, dim3(1), dim3(1024), 0, stream, bsum, nb, tilescan + NTC);
    hipLaunchKernelGGL(k_scan_apply, dim3(nb), dim3(SCAN_BLK), 0, stream,
                       tilecnt, tilescan, bsum, NTC);
    hipLaunchKernelGGL(k_sort_scatter, dim3(NT), dim3(256), 0, stream,
                       kg_h, kg_t, kg_r, ain_row, ain_col, ain_val, tilescan,
                       bufA, E_KG, E_TOT, NT);
    hipLaunchKernelGGL(k_sort_fine, dim3(NBUKU), dim3(256), 0, stream,
                       tilescan, bufA, pairbuf, rowptr, Puv, uvr, NT);

    hipLaunchKernelGGL(k_init, dim3((N_TOT * DD + 255) / 256), dim3(256), 0, stream,
                       embed, dual16);
    hipLaunchKernelGGL(k_wcvt, dim3(32), dim3(256), 0, stream, Wa, Wb, wpack);

    // --- 3 propagation layers (layer 2: CF half only; KG/gate there are dead) ---
    const _Float16* cur16 = dual16;       // layer0 KG gather table = fp16 embed
    _Float16* kg16o = kg16A;
    _Float16* kg16alt = kg16B;
    int spmm_blocks_all = ((size_t)N_ROWS * 64 + 255) / 256;
    int spmm_blocks_cf  = ((size_t)N_TOT * 64 + 255) / 256;
    int ngate = (N_ENT / 16 + 3) / 4;                 // 1563
    int nuc = (N_USR * DD / 8 + 255) / 256;           // 1563
    for (int layer = 0; layer < 3; ++layer) {
        if (layer < 2) {
            hipLaunchKernelGGL(k_spmm_u, dim3(spmm_blocks_all), dim3(256), 0, stream,
                               rowptr, pairbuf, cur16, dual16, kg16o, ig_l[layer], 0);
            hipLaunchKernelGGL(k_gate3, dim3(ngate + nuc), dim3(256), 0, stream,
                               kg16o, ig_l[layer], wpack, dual16, ngate);
            cur16 = kg16o;
            kg16o = kg16alt;
            kg16alt = (_Float16*)cur16;
        } else {
            hipLaunchKernelGGL(k_spmm_u, dim3(spmm_blocks_cf), dim3(256), 0, stream,
                               rowptr, pairbuf, cur16, dual16, kg16o, ig_l[layer], N_ENT);
        }
    }

    // --- final gather-GEMM 1024 x 2048 x 64 with on-the-fly sums ---
    hipLaunchKernelGGL(k_out, dim3(256), dim3(256), 0, stream,
                       embed, ig16_0, ig16_1, ig16_2, user_ids, item_ids, out);
}

// Round 10
// 680.130 us; speedup vs baseline: 2.3415x; 1.0024x over previous
//
#include <hip/hip_runtime.h>
#include <math.h>

#define N_ENT 100000
#define N_USR 50000
#define N_TOT 150000
#define N_ROWS 250000     // unified rows: KG [0,N_ENT) + CF [N_ENT, N_ENT+N_TOT)
#define DD 64

#define SCAN_BLK 256
#define SCAN_ITEMS 1024   // elements per scan block

#define SORT_T 4096       // edges per phase-1 tile
#define BUK_SHIFT 8       // 256 rows per bucket
#define NBUKU 977         // ceil(N_ROWS / 256)
#define LDSCAP 5120       // phase-2 LDS segment capacity (KG bucket mean 3840, std ~62)

typedef _Float16 half8 __attribute__((ext_vector_type(8)));
typedef _Float16 half4 __attribute__((ext_vector_type(4)));
typedef _Float16 h2v __attribute__((ext_vector_type(2)));
typedef float floatx4 __attribute__((ext_vector_type(4)));

// ---------------------------------------------------------------------------
// Per-relation precompute: u_r = Wk_w[0:64]@r, v_r = Wk_w[64:128]@r, c_r = b@r
// uvr layout: [16][132]: u at 0..63, v at 64..127, c at 128
// ---------------------------------------------------------------------------
__global__ void k_rel(const float* __restrict__ Wk_w, const float* __restrict__ Wk_b,
                      const float* __restrict__ rel, float* __restrict__ uvr) {
    int r = blockIdx.x;   // 16 blocks
    int k = threadIdx.x;  // 128 threads
    const float* rv = rel + r * DD;
    const float* wrow = Wk_w + k * DD;
    float s = 0.f;
    for (int j = 0; j < DD; ++j) s += wrow[j] * rv[j];
    uvr[r * 132 + k] = s;
    if (k == 0) {
        float c = 0.f;
        for (int j = 0; j < DD; ++j) c += Wk_b[j] * rv[j];
        uvr[r * 132 + 128] = c;
    }
}

// ---------------------------------------------------------------------------
// Per-entity projections: Puv[n][r] = embed[n].u_r ; Puv[n][16+r] = embed[n].v_r
// ---------------------------------------------------------------------------
__global__ __launch_bounds__(256) void k_proj(const float* __restrict__ embed,
        const float* __restrict__ uvr, float* __restrict__ Puv) {
    __shared__ float suvr[16 * 128];
    for (int i = threadIdx.x; i < 16 * 128; i += 256)
        suvr[i] = uvr[(i >> 7) * 132 + (i & 127)];
    __syncthreads();
    int rowi = threadIdx.x >> 5;
    int sub = threadIdx.x & 31;
    int r = sub & 15, w = sub >> 4;
    int row = blockIdx.x * 8 + rowi;
    if (row >= N_ENT) return;
    const float* er = embed + (size_t)row * DD;
    const float* uv = suvr + r * 128 + w * 64;
    float s = 0.f;
    for (int d = 0; d < DD; ++d) s = fmaf(er[d], uv[d], s);
    Puv[(size_t)row * 32 + sub] = s;
}

// ---------------------------------------------------------------------------
// Sort phase 0: per-tile bucket histogram. tilecnt[b * NT + tile] = count.
// ---------------------------------------------------------------------------
__global__ __launch_bounds__(256) void k_sort_hist(const int* __restrict__ kg_h,
        const int* __restrict__ ain_row, int* __restrict__ tilecnt,
        int E_KG, int E_TOT, int NT) {
    __shared__ int hist[1024];
#pragma unroll
    for (int k = 0; k < 4; ++k) hist[k * 256 + threadIdx.x] = 0;
    __syncthreads();
    int tile = blockIdx.x;
    int base = tile * SORT_T;
#pragma unroll
    for (int k = 0; k < SORT_T / 256; ++k) {
        int e = base + k * 256 + threadIdx.x;
        if (e < E_TOT) {
            int row = (e < E_KG) ? kg_h[e] : (N_ENT + ain_row[e - E_KG]);
            atomicAdd(&hist[row >> BUK_SHIFT], 1);
        }
    }
    __syncthreads();
    for (int b = threadIdx.x; b < NBUKU; b += 256)
        tilecnt[b * NT + tile] = hist[b];
}

// --- multi-block exclusive scan, phase 1: per-chunk partial sums ---
__global__ __launch_bounds__(SCAN_BLK) void k_blocksum(const int* __restrict__ cnt,
                                                       int* __restrict__ bsum, int n) {
    __shared__ int s[SCAN_BLK];
    int base = blockIdx.x * SCAN_ITEMS;
    int sum = 0;
    for (int i = threadIdx.x; i < SCAN_ITEMS; i += SCAN_BLK) {
        int idx = base + i;
        if (idx < n) sum += cnt[idx];
    }
    s[threadIdx.x] = sum;
    __syncthreads();
    for (int off = SCAN_BLK / 2; off; off >>= 1) {
        if (threadIdx.x < off) s[threadIdx.x] += s[threadIdx.x + off];
        __syncthreads();
    }
    if (threadIdx.x == 0) bsum[blockIdx.x] = s[0];
}

// --- phase 2: single-block exclusive scan of partials (nb <= 1024) ---
__global__ __launch_bounds__(1024) void k_bscan(int* __restrict__ bsum, int nb,
                                                int* __restrict__ total_out) {
    __shared__ int s[1024];
    int tid = threadIdx.x;
    int v = (tid < nb) ? bsum[tid] : 0;
    s[tid] = v;
    __syncthreads();
    for (int off = 1; off < 1024; off <<= 1) {
        int t = (tid >= off) ? s[tid - off] : 0;
        __syncthreads();
        s[tid] += t;
        __syncthreads();
    }
    if (tid < nb) bsum[tid] = s[tid] - v;   // exclusive
    if (tid == 1023) *total_out = s[1023];
}

// --- phase 3: block-local scan + offset; writes scanned values ---
__global__ __launch_bounds__(SCAN_BLK) void k_scan_apply(const int* __restrict__ cnt,
        int* __restrict__ scanned, const int* __restrict__ bsum, int n) {
    __shared__ int s[SCAN_BLK];
    int base = blockIdx.x * SCAN_ITEMS;
    int t = threadIdx.x;
    int idx0 = base + t * 4;
    int v[4];
    int lsum = 0;
#pragma unroll
    for (int k = 0; k < 4; ++k) {
        int idx = idx0 + k;
        v[k] = (idx < n) ? cnt[idx] : 0;
        lsum += v[k];
    }
    s[t] = lsum;
    __syncthreads();
    for (int off = 1; off < SCAN_BLK; off <<= 1) {
        int tv = (t >= off) ? s[t - off] : 0;
        __syncthreads();
        s[t] += tv;
        __syncthreads();
    }
    int pre = (t ? s[t - 1] : 0) + bsum[blockIdx.x];
#pragma unroll
    for (int k = 0; k < 4; ++k) {
        int idx = idx0 + k;
        if (idx < n) scanned[idx] = pre;
        pre += v[k];
    }
}

// ---------------------------------------------------------------------------
// Sort phase 1: direct run writes via LDS cursors.
// Payload: KG: x = t | r<<17 | rlow<<22, y = junk (filled by fused softmax)
//          CF: x = col | rlow<<22,       y = bits(val)        (rlow = row&255)
// ---------------------------------------------------------------------------
__global__ __launch_bounds__(256) void k_sort_scatter(const int* __restrict__ kg_h,
        const int* __restrict__ kg_t, const int* __restrict__ kg_r,
        const int* __restrict__ ain_row, const int* __restrict__ ain_col,
        const float* __restrict__ ain_val, const int* __restrict__ tilescan,
        int2* __restrict__ bufA, int E_KG, int E_TOT, int NT) {
    __shared__ int cur[1024];
    __shared__ int gbase[1024];
    int tid = threadIdx.x;
    int tile = blockIdx.x;
#pragma unroll
    for (int k = 0; k < 4; ++k) cur[k * 256 + tid] = 0;
    for (int b = tid; b < NBUKU; b += 256) gbase[b] = tilescan[b * NT + tile];
    __syncthreads();
    int base = tile * SORT_T;
#pragma unroll
    for (int k = 0; k < SORT_T / 256; ++k) {
        int e = base + k * 256 + tid;
        if (e < E_TOT) {
            int row, x, y;
            if (e < E_KG) {
                row = kg_h[e];
                x = kg_t[e] | (kg_r[e] << 17) | ((row & 255) << 22);
                y = 0;
            } else {
                int i = e - E_KG;
                row = N_ENT + ain_row[i];
                x = ain_col[i] | ((row & 255) << 22);
                y = __float_as_int(ain_val[i]);
            }
            int b = row >> BUK_SHIFT;
            int slot = atomicAdd(&cur[b], 1);
            bufA[gbase[b] + slot] = make_int2(x, y);
        }
    }
}

// ---------------------------------------------------------------------------
// Sort phase 2 + FUSED SEGMENT SOFTMAX. One block per bucket (256 rows).
// ---------------------------------------------------------------------------
__global__ __launch_bounds__(256) void k_sort_fine(const int* __restrict__ tilescan,
        const int2* __restrict__ bufA, int2* __restrict__ pairbuf,
        int* __restrict__ rowptr, const float* __restrict__ Puv,
        const float* __restrict__ uvr, int NT) {
    __shared__ int2 seg[LDSCAP];    // 40 KB
    __shared__ int rcnt[256];
    __shared__ int rexc[256];
    __shared__ int rcur[256];
    __shared__ float rsum[256];
    __shared__ float c16[16];
    int tid = threadIdx.x;
    int b = blockIdx.x;
    rcnt[tid] = 0;
    rsum[tid] = 0.f;
    if (tid < 16) c16[tid] = uvr[tid * 132 + 128];
    __syncthreads();

    int base = tilescan[b * NT];
    int endo = tilescan[(b + 1) * NT];
    int bsize = endo - base;
    int growbase = b << BUK_SHIFT;

    for (int i = base + tid; i < endo; i += 256) {
        unsigned rlow = ((unsigned)bufA[i].x) >> 22;
        atomicAdd(&rcnt[rlow], 1);
    }
    __syncthreads();

    {
        int v = rcnt[tid];
        rexc[tid] = v;
        __syncthreads();
        for (int off = 1; off < 256; off <<= 1) {
            int t = (tid >= off) ? rexc[tid - off] : 0;
            __syncthreads();
            rexc[tid] += t;
            __syncthreads();
        }
        int ex = rexc[tid] - v;     // exclusive
        rexc[tid] = ex;
        rcur[tid] = ex;
        int row = growbase + tid;
        if (row <= N_ROWS) rowptr[row] = base + ex;
    }
    __syncthreads();

    if (bsize <= LDSCAP) {
        for (int i = base + tid; i < endo; i += 256) {
            int2 p = bufA[i];
            unsigned rlow = ((unsigned)p.x) >> 22;
            seg[atomicAdd(&rcur[rlow], 1)] = p;
        }
        __syncthreads();
        for (int i = tid; i < bsize; i += 256) {
            int2 p = seg[i];
            unsigned rlow = ((unsigned)p.x) >> 22;
            int grow = growbase + (int)rlow;
            if (grow < N_ENT) {
                int t = p.x & 0x1FFFF;
                int r = (p.x >> 17) & 15;
                float lg = Puv[(size_t)t * 32 + r] + Puv[(size_t)grow * 32 + 16 + r] + c16[r];
                lg = lg >= 0.f ? lg : 0.01f * lg;
                // softmax is shift-invariant; |logit| << 1 so skip segment-max
                float exv = expf(lg);
                seg[i].y = __float_as_int(exv);
                atomicAdd(&rsum[rlow], exv);
            }
        }
        __syncthreads();
        rsum[tid] = 1.f / rsum[tid];   // unused for CF/empty rows
        __syncthreads();
        for (int i = tid; i < bsize; i += 256) {
            int2 p = seg[i];
            unsigned rlow = ((unsigned)p.x) >> 22;
            if (growbase + (int)rlow < N_ENT)
                p.y = __float_as_int(__int_as_float(p.y) * rsum[rlow]);
            pairbuf[base + i] = p;
        }
    } else {
        for (int i = base + tid; i < endo; i += 256) {
            int2 p = bufA[i];
            unsigned rlow = ((unsigned)p.x) >> 22;
            int slot = atomicAdd(&rcur[rlow], 1);
            pairbuf[base + slot] = p;
        }
        __syncthreads();
        for (int i = base + tid; i < endo; i += 256) {
            int2 p = pairbuf[i];
            unsigned rlow = ((unsigned)p.x) >> 22;
            int grow = growbase + (int)rlow;
            if (grow < N_ENT) {
                int t = p.x & 0x1FFFF;
                int r = (p.x >> 17) & 15;
                float lg = Puv[(size_t)t * 32 + r] + Puv[(size_t)grow * 32 + 16 + r] + c16[r];
                lg = lg >= 0.f ? lg : 0.01f * lg;
                float exv = expf(lg);
                pairbuf[i].y = __float_as_int(exv);
                atomicAdd(&rsum[rlow], exv);
            }
        }
        __syncthreads();
        rsum[tid] = 1.f / rsum[tid];
        __syncthreads();
        for (int i = base + tid; i < endo; i += 256) {
            int2 p = pairbuf[i];
            unsigned rlow = ((unsigned)p.x) >> 22;
            if (growbase + (int)rlow < N_ENT)
                pairbuf[i].y = __float_as_int(__int_as_float(p.y) * rsum[rlow]);
        }
    }
}

// ---------------------------------------------------------------------------
// Pack Wa,Wb into fp16 MFMA B-fragment layout (16 KB).
// ---------------------------------------------------------------------------
__global__ void k_wcvt(const float* __restrict__ Wa, const float* __restrict__ Wb,
                       _Float16* __restrict__ wpack) {
    int i = blockIdx.x * 256 + threadIdx.x;
    if (i >= 8192) return;
    int m = i >> 12;
    int rem = i & 4095;
    int kstep = rem >> 11;
    int rem2 = rem & 2047;
    int ntile = rem2 >> 9;
    int rem3 = rem2 & 511;
    int lane = rem3 >> 3;
    int j = rem3 & 7;
    int k = kstep * 32 + (lane >> 4) * 8 + j;
    int n = ntile * 16 + (lane & 15);
    const float* W = m ? Wb : Wa;
    wpack[i] = (_Float16)W[k * 64 + n];
}

// ---------------------------------------------------------------------------
// PAIRED-ROW CSR SpMM: one wave = 2 rows. Lane covers 2 dims (4B h2v load);
// lanes 0-31 = row 2w, lanes 32-63 = row 2w+1. Each gather instruction fetches
// 256B (2 edges) -> 2x in-flight bytes per wave vs lane-per-dim version.
// Launched separately for the KG half and the CF half (smaller working set).
// Accumulation order per dim identical to previous version (bit-exact).
// ---------------------------------------------------------------------------
__global__ __launch_bounds__(256) void k_spmm_u(const int* __restrict__ rowptr,
        const int2* __restrict__ pairbuf, const _Float16* __restrict__ x,
        _Float16* __restrict__ outbuf, int row_begin, int row_end, int cmask) {
    int wid0 = (blockIdx.x * 256 + threadIdx.x) >> 6;
    int wpair = __builtin_amdgcn_readfirstlane(wid0);
    int lane = threadIdx.x & 63;
    int half = lane >> 5;
    int sub = lane & 31;
    int row = row_begin + wpair * 2 + half;
    if (row >= row_end) return;
    int d0 = sub * 2;
    const _Float16* xb = x + d0;
    int s = rowptr[row], e = rowptr[row + 1];
    float a00 = 0.f, a01 = 0.f, a10 = 0.f, a11 = 0.f;
    float a20 = 0.f, a21 = 0.f, a30 = 0.f, a31 = 0.f;
    int i = s;
    for (; i + 4 <= e; i += 4) {
        int2 p0 = pairbuf[i], p1 = pairbuf[i + 1], p2 = pairbuf[i + 2], p3 = pairbuf[i + 3];
        h2v g0 = *(const h2v*)(xb + (size_t)(p0.x & cmask) * DD);
        h2v g1 = *(const h2v*)(xb + (size_t)(p1.x & cmask) * DD);
        h2v g2 = *(const h2v*)(xb + (size_t)(p2.x & cmask) * DD);
        h2v g3 = *(const h2v*)(xb + (size_t)(p3.x & cmask) * DD);
        float w0 = __int_as_float(p0.y), w1 = __int_as_float(p1.y);
        float w2 = __int_as_float(p2.y), w3 = __int_as_float(p3.y);
        a00 = fmaf(w0, (float)g0[0], a00); a01 = fmaf(w0, (float)g0[1], a01);
        a10 = fmaf(w1, (float)g1[0], a10); a11 = fmaf(w1, (float)g1[1], a11);
        a20 = fmaf(w2, (float)g2[0], a20); a21 = fmaf(w2, (float)g2[1], a21);
        a30 = fmaf(w3, (float)g3[0], a30); a31 = fmaf(w3, (float)g3[1], a31);
    }
    for (; i < e; ++i) {
        int2 p = pairbuf[i];
        h2v g = *(const h2v*)(xb + (size_t)(p.x & cmask) * DD);
        float w = __int_as_float(p.y);
        a00 = fmaf(w, (float)g[0], a00); a01 = fmaf(w, (float)g[1], a01);
    }
    float r0 = (a00 + a10) + (a20 + a30);
    float r1 = (a01 + a11) + (a21 + a31);
    h2v st; st[0] = (_Float16)r0; st[1] = (_Float16)r1;
    *(h2v*)(outbuf + (size_t)(row - row_begin) * DD + d0) = st;
}

// ---------------------------------------------------------------------------
// Entity gate via MFMA (one wave = 16 rows), FUSED with user passthrough copy:
// blocks >= ngate copy ig16 user rows into dual16 (half8).
// acc = kg@Wa + ig@Wb in one accumulator chain.
// C/D: col=lane&15, row=(lane>>4)*4+reg [m89-verified].
// ---------------------------------------------------------------------------
__global__ __launch_bounds__(256) void k_gate3(const _Float16* __restrict__ kg16,
        const _Float16* __restrict__ ig16, const _Float16* __restrict__ wpack,
        _Float16* __restrict__ dual16, int ngate) {
    __shared__ _Float16 sw[8192];
    if ((int)blockIdx.x >= ngate) {
        int i = ((int)blockIdx.x - ngate) * 256 + threadIdx.x;
        if (i < N_USR * DD / 8) {
            size_t o = (size_t)N_ENT * DD / 8 + i;
            ((half8*)dual16)[o] = ((const half8*)ig16)[o];
        }
        return;
    }
    for (int i = threadIdx.x * 8; i < 8192; i += 256 * 8)
        *(half8*)(sw + i) = *(const half8*)(wpack + i);
    __syncthreads();
    int lane = threadIdx.x & 63;
    int wv = (blockIdx.x * 256 + threadIdx.x) >> 6;
    int row0 = wv * 16;
    if (row0 >= N_ENT) return;
    int m = lane & 15;
    int quad = lane >> 4;

    const _Float16* kgr = kg16 + (size_t)(row0 + m) * DD + quad * 8;
    const _Float16* igr = ig16 + (size_t)(row0 + m) * DD + quad * 8;
    half8 akg0 = *(const half8*)(kgr);
    half8 akg1 = *(const half8*)(kgr + 32);
    half8 aig0 = *(const half8*)(igr);
    half8 aig1 = *(const half8*)(igr + 32);

    floatx4 acc[4];
#pragma unroll
    for (int t = 0; t < 4; ++t) {
        half8 bA0 = *(const half8*)(sw + 0 * 4096 + 0 * 2048 + t * 512 + lane * 8);
        half8 bA1 = *(const half8*)(sw + 0 * 4096 + 1 * 2048 + t * 512 + lane * 8);
        half8 bB0 = *(const half8*)(sw + 1 * 4096 + 0 * 2048 + t * 512 + lane * 8);
        half8 bB1 = *(const half8*)(sw + 1 * 4096 + 1 * 2048 + t * 512 + lane * 8);
        floatx4 c = {0.f, 0.f, 0.f, 0.f};
        c = __builtin_amdgcn_mfma_f32_16x16x32_f16(akg0, bA0, c, 0, 0, 0);
        c = __builtin_amdgcn_mfma_f32_16x16x32_f16(akg1, bA1, c, 0, 0, 0);
        c = __builtin_amdgcn_mfma_f32_16x16x32_f16(aig0, bB0, c, 0, 0, 0);
        c = __builtin_amdgcn_mfma_f32_16x16x32_f16(aig1, bB1, c, 0, 0, 0);
        acc[t] = c;
    }

#pragma unroll
    for (int t = 0; t < 4; ++t) {
#pragma unroll
        for (int r = 0; r < 4; ++r) {
            int row = quad * 4 + r;
            int col = t * 16 + m;
            size_t o = (size_t)(row0 + row) * DD + col;
            float kv = (float)kg16[o];
            float cv = (float)ig16[o];
            float g = 1.f / (1.f + expf(-acc[t][r]));
            dual16[o] = (_Float16)(g * kv + (1.f - g) * cv);
        }
    }
}

// init: dual16 = fp16(embed)
__global__ void k_init(const float* __restrict__ embed, _Float16* __restrict__ dual16) {
    int i = blockIdx.x * blockDim.x + threadIdx.x;
    if (i >= N_TOT * DD) return;
    dual16[i] = (_Float16)embed[i];
}

// ---------------------------------------------------------------------------
// out[u,j] = sums[user_ids[u]] . sums[item_ids[j]],
// sums[row] = embed[row] + ig0[row] + ig1[row] + ig2[row] (reconstructed).
// 256 blocks: 32 user-groups (32 users) x 8 item-chunks (256 items).
// ---------------------------------------------------------------------------
__global__ __launch_bounds__(256) void k_out(const float* __restrict__ embed,
        const _Float16* __restrict__ ig0, const _Float16* __restrict__ ig1,
        const _Float16* __restrict__ ig2, const int* __restrict__ user_ids,
        const int* __restrict__ item_ids, float* __restrict__ out) {
    __shared__ float uvec[32 * DD];
    int ug = blockIdx.x >> 3;
    int qi = blockIdx.x & 7;
    int ub = ug * 32;
    for (int i = threadIdx.x; i < 32 * DD; i += 256) {
        int uu = i >> 6, d = i & 63;
        size_t o = (size_t)user_ids[ub + uu] * DD + d;
        uvec[i] = embed[o] + (float)ig0[o] + (float)ig1[o] + (float)ig2[o];
    }
    __syncthreads();
    int jbase = qi * 256;
    for (int j = threadIdx.x; j < 256; j += 256) {
        size_t ro = (size_t)item_ids[jbase + j] * DD;
        float acc[32];
#pragma unroll
        for (int u = 0; u < 32; ++u) acc[u] = 0.f;
        for (int d = 0; d < DD; d += 4) {
            float4 ev = *(const float4*)(embed + ro + d);
            half4 h0 = *(const half4*)(ig0 + ro + d);
            half4 h1 = *(const half4*)(ig1 + ro + d);
            half4 h2 = *(const half4*)(ig2 + ro + d);
            float iv0 = ev.x + (float)h0[0] + (float)h1[0] + (float)h2[0];
            float iv1 = ev.y + (float)h0[1] + (float)h1[1] + (float)h2[1];
            float iv2 = ev.z + (float)h0[2] + (float)h1[2] + (float)h2[2];
            float iv3 = ev.w + (float)h0[3] + (float)h1[3] + (float)h2[3];
#pragma unroll
            for (int u = 0; u < 32; ++u) {
                acc[u] = fmaf(iv0, uvec[u * DD + d + 0], acc[u]);
                acc[u] = fmaf(iv1, uvec[u * DD + d + 1], acc[u]);
                acc[u] = fmaf(iv2, uvec[u * DD + d + 2], acc[u]);
                acc[u] = fmaf(iv3, uvec[u * DD + d + 3], acc[u]);
            }
        }
#pragma unroll
        for (int u = 0; u < 32; ++u)
            out[(size_t)(ub + u) * 2048 + jbase + j] = acc[u];
    }
}

extern "C" void kernel_launch(void* const* d_in, const int* in_sizes, int n_in,
                              void* d_out, int out_size, void* d_ws, size_t ws_size,
                              hipStream_t stream) {
    const float* embed   = (const float*)d_in[0];
    const float* rel     = (const float*)d_in[1];
    const float* Wk_w    = (const float*)d_in[2];
    const float* Wk_b    = (const float*)d_in[3];
    const float* Wa      = (const float*)d_in[4];
    const float* Wb      = (const float*)d_in[5];
    const int*   kg_h    = (const int*)d_in[6];
    const int*   kg_t    = (const int*)d_in[7];
    const int*   kg_r    = (const int*)d_in[8];
    const int*   ain_row = (const int*)d_in[9];
    const int*   ain_col = (const int*)d_in[10];
    const float* ain_val = (const float*)d_in[11];
    const int*   user_ids = (const int*)d_in[12];
    const int*   item_ids = (const int*)d_in[13];
    int E_KG = in_sizes[6];
    int E_CF = in_sizes[9];
    int E_TOT = E_KG + E_CF;
    float* out = (float*)d_out;

    int NT  = (E_TOT + SORT_T - 1) / SORT_T;   // phase-1 tiles (733)
    int NTC = NBUKU * NT;                       // scan length (~716K)

    float* ws = (float*)d_ws;
    size_t off = 0;
    float* uvr       = ws + off; off += 16 * 132;
    float* Puv       = ws + off; off += (size_t)N_ENT * 32;
    int*   rowptr    = (int*)(ws + off); off += N_ROWS + 4;
    int*   tilecnt   = (int*)(ws + off); off += (size_t)NTC + 4;
    int*   tilescan  = (int*)(ws + off); off += (size_t)NTC + 4;
    int*   bsum      = (int*)(ws + off); off += 1024;
    int2*  pairbuf   = (int2*)(ws + off); off += 2 * (size_t)E_TOT;   // final (row-sorted)
    _Float16* dual16 = (_Float16*)(ws + off); off += (size_t)N_TOT * DD / 2;
    _Float16* ig16_0 = (_Float16*)(ws + off); off += (size_t)N_TOT * DD / 2;
    _Float16* ig16_1 = (_Float16*)(ws + off); off += (size_t)N_TOT * DD / 2;
    _Float16* ig16_2 = (_Float16*)(ws + off); off += (size_t)N_TOT * DD / 2;
    _Float16* kg16A  = (_Float16*)(ws + off); off += (size_t)N_ENT * DD / 2;
    _Float16* kg16B  = (_Float16*)(ws + off); off += (size_t)N_ENT * DD / 2;
    _Float16* wpack  = (_Float16*)(ws + off); off += 8192 / 2;
    int2*  bufA      = (int2*)kg16A;   // alias: 24MB <= kg16A+kg16B (25.6MB); dead before layer0
    _Float16* ig_l[3] = {ig16_0, ig16_1, ig16_2};

    // --- attention precompute (needed by fused sort+softmax) ---
    hipLaunchKernelGGL(k_rel, dim3(16), dim3(128), 0, stream, Wk_w, Wk_b, rel, uvr);
    hipLaunchKernelGGL(k_proj, dim3((N_ENT + 7) / 8), dim3(256), 0, stream, embed, uvr, Puv);

    // --- binning sort: hist -> scan -> tile scatter -> fine sort + softmax ---
    hipLaunchKernelGGL(k_sort_hist, dim3(NT), dim3(256), 0, stream,
                       kg_h, ain_row, tilecnt, E_KG, E_TOT, NT);
    int nb = (NTC + SCAN_ITEMS - 1) / SCAN_ITEMS;   // ~700
    hipLaunchKernelGGL(k_blocksum, dim3(nb), dim3(SCAN_BLK), 0, stream, tilecnt, bsum, NTC);
    hipLaunchKernelGGL(k_bscan, dim3(1), dim3(1024), 0, stream, bsum, nb, tilescan + NTC);
    hipLaunchKernelGGL(k_scan_apply, dim3(nb), dim3(SCAN_BLK), 0, stream,
                       tilecnt, tilescan, bsum, NTC);
    hipLaunchKernelGGL(k_sort_scatter, dim3(NT), dim3(256), 0, stream,
                       kg_h, kg_t, kg_r, ain_row, ain_col, ain_val, tilescan,
                       bufA, E_KG, E_TOT, NT);
    hipLaunchKernelGGL(k_sort_fine, dim3(NBUKU), dim3(256), 0, stream,
                       tilescan, bufA, pairbuf, rowptr, Puv, uvr, NT);

    hipLaunchKernelGGL(k_init, dim3((N_TOT * DD + 255) / 256), dim3(256), 0, stream,
                       embed, dual16);
    hipLaunchKernelGGL(k_wcvt, dim3(32), dim3(256), 0, stream, Wa, Wb, wpack);

    // --- 3 propagation layers; KG and CF SpMM halves launched separately
    //     (smaller concurrent gather working set per dispatch) ---
    const _Float16* cur16 = dual16;       // layer0 KG gather table = fp16 embed
    _Float16* kg16o = kg16A;
    _Float16* kg16alt = kg16B;
    int kg_blocks = ((N_ENT / 2) * 64 + 255) / 256;     // 12500
    int cf_blocks = ((N_TOT / 2) * 64 + 255) / 256;     // 18750
    int ngate = (N_ENT / 16 + 3) / 4;                   // 1563
    int nuc = (N_USR * DD / 8 + 255) / 256;             // 1563
    for (int layer = 0; layer < 3; ++layer) {
        if (layer < 2) {
            hipLaunchKernelGGL(k_spmm_u, dim3(kg_blocks), dim3(256), 0, stream,
                               rowptr, pairbuf, cur16, kg16o, 0, N_ENT, 0x1FFFF);
            hipLaunchKernelGGL(k_spmm_u, dim3(cf_blocks), dim3(256), 0, stream,
                               rowptr, pairbuf, dual16, ig_l[layer], N_ENT, N_ROWS, 0x3FFFF);
            hipLaunchKernelGGL(k_gate3, dim3(ngate + nuc), dim3(256), 0, stream,
                               kg16o, ig_l[layer], wpack, dual16, ngate);
            cur16 = kg16o;
            kg16o = kg16alt;
            kg16alt = (_Float16*)cur16;
        } else {
            hipLaunchKernelGGL(k_spmm_u, dim3(cf_blocks), dim3(256), 0, stream,
                               rowptr, pairbuf, dual16, ig_l[layer], N_ENT, N_ROWS, 0x3FFFF);
        }
    }

    // --- final gather-GEMM 1024 x 2048 x 64 with on-the-fly sums ---
    hipLaunchKernelGGL(k_out, dim3(256), dim3(256), 0, stream,
                       embed, ig16_0, ig16_1, ig16_2, user_ids, item_ids, out);
}

// Round 11
// 642.814 us; speedup vs baseline: 2.4774x; 1.0581x over previous
//
#include <hip/hip_runtime.h>
#include <math.h>

#define N_ENT 100000
#define N_USR 50000
#define N_TOT 150000
#define N_ROWS 250000     // unified rows: KG [0,N_ENT) + CF [N_ENT, N_ENT+N_TOT)
#define DD 64

#define SCAN_BLK 256
#define SCAN_ITEMS 1024   // elements per scan block

#define SORT_T 4096       // edges per phase-1 tile
#define BUK_SHIFT 8       // 256 rows per bucket
#define NBUKU 977         // ceil(N_ROWS / 256)
#define LDSCAP 5120       // phase-2 LDS segment capacity (KG bucket mean 3840, std ~62)

typedef _Float16 half8 __attribute__((ext_vector_type(8)));
typedef _Float16 half4 __attribute__((ext_vector_type(4)));
typedef _Float16 h2v __attribute__((ext_vector_type(2)));
typedef float floatx4 __attribute__((ext_vector_type(4)));

// ---------------------------------------------------------------------------
// Per-relation precompute: u_r = Wk_w[0:64]@r, v_r = Wk_w[64:128]@r, c_r = b@r
// uvr layout: [16][132]: u at 0..63, v at 64..127, c at 128
// ---------------------------------------------------------------------------
__global__ void k_rel(const float* __restrict__ Wk_w, const float* __restrict__ Wk_b,
                      const float* __restrict__ rel, float* __restrict__ uvr) {
    int r = blockIdx.x;   // 16 blocks
    int k = threadIdx.x;  // 128 threads
    const float* rv = rel + r * DD;
    const float* wrow = Wk_w + k * DD;
    float s = 0.f;
    for (int j = 0; j < DD; ++j) s += wrow[j] * rv[j];
    uvr[r * 132 + k] = s;
    if (k == 0) {
        float c = 0.f;
        for (int j = 0; j < DD; ++j) c += Wk_b[j] * rv[j];
        uvr[r * 132 + 128] = c;
    }
}

// ---------------------------------------------------------------------------
// Per-entity projections: Puv[n][r] = embed[n].u_r ; Puv[n][16+r] = embed[n].v_r
// LDS layout TRANSPOSED to [d][sub]: at step d the 32 lanes of each half-wave
// read suvr[d*32 .. d*32+31] -> banks 0..31 conflict-free (was 32-way conflict:
// r*128 + w*64 are multiples of 32 words, all (r,w) hit bank d&31 -> 4.8e7
// SQ_LDS_BANK_CONFLICT, 95us). Same values, same order -> bit-exact.
// ---------------------------------------------------------------------------
__global__ __launch_bounds__(256) void k_proj(const float* __restrict__ embed,
        const float* __restrict__ uvr, float* __restrict__ Puv) {
    __shared__ float suvr[64 * 32];   // [d][sub], sub = r + 16*w
    for (int i = threadIdx.x; i < 64 * 32; i += 256) {
        int d = i >> 5, sub = i & 31;
        suvr[i] = uvr[(sub & 15) * 132 + (sub >> 4) * 64 + d];
    }
    __syncthreads();
    int rowi = threadIdx.x >> 5;
    int sub = threadIdx.x & 31;
    int row = blockIdx.x * 8 + rowi;
    if (row >= N_ENT) return;
    const float* er = embed + (size_t)row * DD;
    float s = 0.f;
    for (int d = 0; d < DD; ++d) s = fmaf(er[d], suvr[d * 32 + sub], s);
    Puv[(size_t)row * 32 + sub] = s;
}

// ---------------------------------------------------------------------------
// Sort phase 0: per-tile bucket histogram. tilecnt[b * NT + tile] = count.
// ---------------------------------------------------------------------------
__global__ __launch_bounds__(256) void k_sort_hist(const int* __restrict__ kg_h,
        const int* __restrict__ ain_row, int* __restrict__ tilecnt,
        int E_KG, int E_TOT, int NT) {
    __shared__ int hist[1024];
#pragma unroll
    for (int k = 0; k < 4; ++k) hist[k * 256 + threadIdx.x] = 0;
    __syncthreads();
    int tile = blockIdx.x;
    int base = tile * SORT_T;
#pragma unroll
    for (int k = 0; k < SORT_T / 256; ++k) {
        int e = base + k * 256 + threadIdx.x;
        if (e < E_TOT) {
            int row = (e < E_KG) ? kg_h[e] : (N_ENT + ain_row[e - E_KG]);
            atomicAdd(&hist[row >> BUK_SHIFT], 1);
        }
    }
    __syncthreads();
    for (int b = threadIdx.x; b < NBUKU; b += 256)
        tilecnt[b * NT + tile] = hist[b];
}

// --- multi-block exclusive scan, phase 1: per-chunk partial sums ---
__global__ __launch_bounds__(SCAN_BLK) void k_blocksum(const int* __restrict__ cnt,
                                                       int* __restrict__ bsum, int n) {
    __shared__ int s[SCAN_BLK];
    int base = blockIdx.x * SCAN_ITEMS;
    int sum = 0;
    for (int i = threadIdx.x; i < SCAN_ITEMS; i += SCAN_BLK) {
        int idx = base + i;
        if (idx < n) sum += cnt[idx];
    }
    s[threadIdx.x] = sum;
    __syncthreads();
    for (int off = SCAN_BLK / 2; off; off >>= 1) {
        if (threadIdx.x < off) s[threadIdx.x] += s[threadIdx.x + off];
        __syncthreads();
    }
    if (threadIdx.x == 0) bsum[blockIdx.x] = s[0];
}

// --- phase 2: single-block exclusive scan of partials (nb <= 1024) ---
__global__ __launch_bounds__(1024) void k_bscan(int* __restrict__ bsum, int nb,
                                                int* __restrict__ total_out) {
    __shared__ int s[1024];
    int tid = threadIdx.x;
    int v = (tid < nb) ? bsum[tid] : 0;
    s[tid] = v;
    __syncthreads();
    for (int off = 1; off < 1024; off <<= 1) {
        int t = (tid >= off) ? s[tid - off] : 0;
        __syncthreads();
        s[tid] += t;
        __syncthreads();
    }
    if (tid < nb) bsum[tid] = s[tid] - v;   // exclusive
    if (tid == 1023) *total_out = s[1023];
}

// --- phase 3: block-local scan + offset; writes scanned values ---
__global__ __launch_bounds__(SCAN_BLK) void k_scan_apply(const int* __restrict__ cnt,
        int* __restrict__ scanned, const int* __restrict__ bsum, int n) {
    __shared__ int s[SCAN_BLK];
    int base = blockIdx.x * SCAN_ITEMS;
    int t = threadIdx.x;
    int idx0 = base + t * 4;
    int v[4];
    int lsum = 0;
#pragma unroll
    for (int k = 0; k < 4; ++k) {
        int idx = idx0 + k;
        v[k] = (idx < n) ? cnt[idx] : 0;
        lsum += v[k];
    }
    s[t] = lsum;
    __syncthreads();
    for (int off = 1; off < SCAN_BLK; off <<= 1) {
        int tv = (t >= off) ? s[t - off] : 0;
        __syncthreads();
        s[t] += tv;
        __syncthreads();
    }
    int pre = (t ? s[t - 1] : 0) + bsum[blockIdx.x];
#pragma unroll
    for (int k = 0; k < 4; ++k) {
        int idx = idx0 + k;
        if (idx < n) scanned[idx] = pre;
        pre += v[k];
    }
}

// ---------------------------------------------------------------------------
// Sort phase 1: direct run writes via LDS cursors.
// Payload: KG: x = t | r<<17 | rlow<<22, y = junk (filled by fused softmax)
//          CF: x = col | rlow<<22,       y = bits(val)        (rlow = row&255)
// ---------------------------------------------------------------------------
__global__ __launch_bounds__(256) void k_sort_scatter(const int* __restrict__ kg_h,
        const int* __restrict__ kg_t, const int* __restrict__ kg_r,
        const int* __restrict__ ain_row, const int* __restrict__ ain_col,
        const float* __restrict__ ain_val, const int* __restrict__ tilescan,
        int2* __restrict__ bufA, int E_KG, int E_TOT, int NT) {
    __shared__ int cur[1024];
    __shared__ int gbase[1024];
    int tid = threadIdx.x;
    int tile = blockIdx.x;
#pragma unroll
    for (int k = 0; k < 4; ++k) cur[k * 256 + tid] = 0;
    for (int b = tid; b < NBUKU; b += 256) gbase[b] = tilescan[b * NT + tile];
    __syncthreads();
    int base = tile * SORT_T;
#pragma unroll
    for (int k = 0; k < SORT_T / 256; ++k) {
        int e = base + k * 256 + tid;
        if (e < E_TOT) {
            int row, x, y;
            if (e < E_KG) {
                row = kg_h[e];
                x = kg_t[e] | (kg_r[e] << 17) | ((row & 255) << 22);
                y = 0;
            } else {
                int i = e - E_KG;
                row = N_ENT + ain_row[i];
                x = ain_col[i] | ((row & 255) << 22);
                y = __float_as_int(ain_val[i]);
            }
            int b = row >> BUK_SHIFT;
            int slot = atomicAdd(&cur[b], 1);
            bufA[gbase[b] + slot] = make_int2(x, y);
        }
    }
}

// ---------------------------------------------------------------------------
// Sort phase 2 + FUSED SEGMENT SOFTMAX. One block per bucket (256 rows).
// ---------------------------------------------------------------------------
__global__ __launch_bounds__(256) void k_sort_fine(const int* __restrict__ tilescan,
        const int2* __restrict__ bufA, int2* __restrict__ pairbuf,
        int* __restrict__ rowptr, const float* __restrict__ Puv,
        const float* __restrict__ uvr, int NT) {
    __shared__ int2 seg[LDSCAP];    // 40 KB
    __shared__ int rcnt[256];
    __shared__ int rexc[256];
    __shared__ int rcur[256];
    __shared__ float rsum[256];
    __shared__ float c16[16];
    int tid = threadIdx.x;
    int b = blockIdx.x;
    rcnt[tid] = 0;
    rsum[tid] = 0.f;
    if (tid < 16) c16[tid] = uvr[tid * 132 + 128];
    __syncthreads();

    int base = tilescan[b * NT];
    int endo = tilescan[(b + 1) * NT];
    int bsize = endo - base;
    int growbase = b << BUK_SHIFT;

    for (int i = base + tid; i < endo; i += 256) {
        unsigned rlow = ((unsigned)bufA[i].x) >> 22;
        atomicAdd(&rcnt[rlow], 1);
    }
    __syncthreads();

    {
        int v = rcnt[tid];
        rexc[tid] = v;
        __syncthreads();
        for (int off = 1; off < 256; off <<= 1) {
            int t = (tid >= off) ? rexc[tid - off] : 0;
            __syncthreads();
            rexc[tid] += t;
            __syncthreads();
        }
        int ex = rexc[tid] - v;     // exclusive
        rexc[tid] = ex;
        rcur[tid] = ex;
        int row = growbase + tid;
        if (row <= N_ROWS) rowptr[row] = base + ex;
    }
    __syncthreads();

    if (bsize <= LDSCAP) {
        for (int i = base + tid; i < endo; i += 256) {
            int2 p = bufA[i];
            unsigned rlow = ((unsigned)p.x) >> 22;
            seg[atomicAdd(&rcur[rlow], 1)] = p;
        }
        __syncthreads();
        for (int i = tid; i < bsize; i += 256) {
            int2 p = seg[i];
            unsigned rlow = ((unsigned)p.x) >> 22;
            int grow = growbase + (int)rlow;
            if (grow < N_ENT) {
                int t = p.x & 0x1FFFF;
                int r = (p.x >> 17) & 15;
                float lg = Puv[(size_t)t * 32 + r] + Puv[(size_t)grow * 32 + 16 + r] + c16[r];
                lg = lg >= 0.f ? lg : 0.01f * lg;
                // softmax is shift-invariant; |logit| << 1 so skip segment-max
                float exv = expf(lg);
                seg[i].y = __float_as_int(exv);
                atomicAdd(&rsum[rlow], exv);
            }
        }
        __syncthreads();
        rsum[tid] = 1.f / rsum[tid];   // unused for CF/empty rows
        __syncthreads();
        for (int i = tid; i < bsize; i += 256) {
            int2 p = seg[i];
            unsigned rlow = ((unsigned)p.x) >> 22;
            if (growbase + (int)rlow < N_ENT)
                p.y = __float_as_int(__int_as_float(p.y) * rsum[rlow]);
            pairbuf[base + i] = p;
        }
    } else {
        for (int i = base + tid; i < endo; i += 256) {
            int2 p = bufA[i];
            unsigned rlow = ((unsigned)p.x) >> 22;
            int slot = atomicAdd(&rcur[rlow], 1);
            pairbuf[base + slot] = p;
        }
        __syncthreads();
        for (int i = base + tid; i < endo; i += 256) {
            int2 p = pairbuf[i];
            unsigned rlow = ((unsigned)p.x) >> 22;
            int grow = growbase + (int)rlow;
            if (grow < N_ENT) {
                int t = p.x & 0x1FFFF;
                int r = (p.x >> 17) & 15;
                float lg = Puv[(size_t)t * 32 + r] + Puv[(size_t)grow * 32 + 16 + r] + c16[r];
                lg = lg >= 0.f ? lg : 0.01f * lg;
                float exv = expf(lg);
                pairbuf[i].y = __float_as_int(exv);
                atomicAdd(&rsum[rlow], exv);
            }
        }
        __syncthreads();
        rsum[tid] = 1.f / rsum[tid];
        __syncthreads();
        for (int i = base + tid; i < endo; i += 256) {
            int2 p = pairbuf[i];
            unsigned rlow = ((unsigned)p.x) >> 22;
            if (growbase + (int)rlow < N_ENT)
                pairbuf[i].y = __float_as_int(__int_as_float(p.y) * rsum[rlow]);
        }
    }
}

// ---------------------------------------------------------------------------
// Pack Wa,Wb into fp16 MFMA B-fragment layout (16 KB).
// ---------------------------------------------------------------------------
__global__ void k_wcvt(const float* __restrict__ Wa, const float* __restrict__ Wb,
                       _Float16* __restrict__ wpack) {
    int i = blockIdx.x * 256 + threadIdx.x;
    if (i >= 8192) return;
    int m = i >> 12;
    int rem = i & 4095;
    int kstep = rem >> 11;
    int rem2 = rem & 2047;
    int ntile = rem2 >> 9;
    int rem3 = rem2 & 511;
    int lane = rem3 >> 3;
    int j = rem3 & 7;
    int k = kstep * 32 + (lane >> 4) * 8 + j;
    int n = ntile * 16 + (lane & 15);
    const float* W = m ? Wb : Wa;
    wpack[i] = (_Float16)W[k * 64 + n];
}

// ---------------------------------------------------------------------------
// PAIRED-ROW CSR SpMM: one wave = 2 rows. Lane covers 2 dims (4B h2v load);
// lanes 0-31 = row 2w, lanes 32-63 = row 2w+1.
// Launched separately for the KG half and the CF half.
// ---------------------------------------------------------------------------
__global__ __launch_bounds__(256) void k_spmm_u(const int* __restrict__ rowptr,
        const int2* __restrict__ pairbuf, const _Float16* __restrict__ x,
        _Float16* __restrict__ outbuf, int row_begin, int row_end, int cmask) {
    int wid0 = (blockIdx.x * 256 + threadIdx.x) >> 6;
    int wpair = __builtin_amdgcn_readfirstlane(wid0);
    int lane = threadIdx.x & 63;
    int half = lane >> 5;
    int sub = lane & 31;
    int row = row_begin + wpair * 2 + half;
    if (row >= row_end) return;
    int d0 = sub * 2;
    const _Float16* xb = x + d0;
    int s = rowptr[row], e = rowptr[row + 1];
    float a00 = 0.f, a01 = 0.f, a10 = 0.f, a11 = 0.f;
    float a20 = 0.f, a21 = 0.f, a30 = 0.f, a31 = 0.f;
    int i = s;
    for (; i + 4 <= e; i += 4) {
        int2 p0 = pairbuf[i], p1 = pairbuf[i + 1], p2 = pairbuf[i + 2], p3 = pairbuf[i + 3];
        h2v g0 = *(const h2v*)(xb + (size_t)(p0.x & cmask) * DD);
        h2v g1 = *(const h2v*)(xb + (size_t)(p1.x & cmask) * DD);
        h2v g2 = *(const h2v*)(xb + (size_t)(p2.x & cmask) * DD);
        h2v g3 = *(const h2v*)(xb + (size_t)(p3.x & cmask) * DD);
        float w0 = __int_as_float(p0.y), w1 = __int_as_float(p1.y);
        float w2 = __int_as_float(p2.y), w3 = __int_as_float(p3.y);
        a00 = fmaf(w0, (float)g0[0], a00); a01 = fmaf(w0, (float)g0[1], a01);
        a10 = fmaf(w1, (float)g1[0], a10); a11 = fmaf(w1, (float)g1[1], a11);
        a20 = fmaf(w2, (float)g2[0], a20); a21 = fmaf(w2, (float)g2[1], a21);
        a30 = fmaf(w3, (float)g3[0], a30); a31 = fmaf(w3, (float)g3[1], a31);
    }
    for (; i < e; ++i) {
        int2 p = pairbuf[i];
        h2v g = *(const h2v*)(xb + (size_t)(p.x & cmask) * DD);
        float w = __int_as_float(p.y);
        a00 = fmaf(w, (float)g[0], a00); a01 = fmaf(w, (float)g[1], a01);
    }
    float r0 = (a00 + a10) + (a20 + a30);
    float r1 = (a01 + a11) + (a21 + a31);
    h2v st; st[0] = (_Float16)r0; st[1] = (_Float16)r1;
    *(h2v*)(outbuf + (size_t)(row - row_begin) * DD + d0) = st;
}

// ---------------------------------------------------------------------------
// Entity gate via MFMA (one wave = 16 rows), FUSED with user passthrough copy:
// blocks >= ngate copy ig16 user rows into dual16 (half8).
// acc = kg@Wa + ig@Wb in one accumulator chain.
// C/D: col=lane&15, row=(lane>>4)*4+reg [m89-verified].
// ---------------------------------------------------------------------------
__global__ __launch_bounds__(256) void k_gate3(const _Float16* __restrict__ kg16,
        const _Float16* __restrict__ ig16, const _Float16* __restrict__ wpack,
        _Float16* __restrict__ dual16, int ngate) {
    __shared__ _Float16 sw[8192];
    if ((int)blockIdx.x >= ngate) {
        int i = ((int)blockIdx.x - ngate) * 256 + threadIdx.x;
        if (i < N_USR * DD / 8) {
            size_t o = (size_t)N_ENT * DD / 8 + i;
            ((half8*)dual16)[o] = ((const half8*)ig16)[o];
        }
        return;
    }
    for (int i = threadIdx.x * 8; i < 8192; i += 256 * 8)
        *(half8*)(sw + i) = *(const half8*)(wpack + i);
    __syncthreads();
    int lane = threadIdx.x & 63;
    int wv = (blockIdx.x * 256 + threadIdx.x) >> 6;
    int row0 = wv * 16;
    if (row0 >= N_ENT) return;
    int m = lane & 15;
    int quad = lane >> 4;

    const _Float16* kgr = kg16 + (size_t)(row0 + m) * DD + quad * 8;
    const _Float16* igr = ig16 + (size_t)(row0 + m) * DD + quad * 8;
    half8 akg0 = *(const half8*)(kgr);
    half8 akg1 = *(const half8*)(kgr + 32);
    half8 aig0 = *(const half8*)(igr);
    half8 aig1 = *(const half8*)(igr + 32);

    floatx4 acc[4];
#pragma unroll
    for (int t = 0; t < 4; ++t) {
        half8 bA0 = *(const half8*)(sw + 0 * 4096 + 0 * 2048 + t * 512 + lane * 8);
        half8 bA1 = *(const half8*)(sw + 0 * 4096 + 1 * 2048 + t * 512 + lane * 8);
        half8 bB0 = *(const half8*)(sw + 1 * 4096 + 0 * 2048 + t * 512 + lane * 8);
        half8 bB1 = *(const half8*)(sw + 1 * 4096 + 1 * 2048 + t * 512 + lane * 8);
        floatx4 c = {0.f, 0.f, 0.f, 0.f};
        c = __builtin_amdgcn_mfma_f32_16x16x32_f16(akg0, bA0, c, 0, 0, 0);
        c = __builtin_amdgcn_mfma_f32_16x16x32_f16(akg1, bA1, c, 0, 0, 0);
        c = __builtin_amdgcn_mfma_f32_16x16x32_f16(aig0, bB0, c, 0, 0, 0);
        c = __builtin_amdgcn_mfma_f32_16x16x32_f16(aig1, bB1, c, 0, 0, 0);
        acc[t] = c;
    }

#pragma unroll
    for (int t = 0; t < 4; ++t) {
#pragma unroll
        for (int r = 0; r < 4; ++r) {
            int row = quad * 4 + r;
            int col = t * 16 + m;
            size_t o = (size_t)(row0 + row) * DD + col;
            float kv = (float)kg16[o];
            float cv = (float)ig16[o];
            float g = 1.f / (1.f + expf(-acc[t][r]));
            dual16[o] = (_Float16)(g * kv + (1.f - g) * cv);
        }
    }
}

// init: dual16 = fp16(embed)
__global__ void k_init(const float* __restrict__ embed, _Float16* __restrict__ dual16) {
    int i = blockIdx.x * blockDim.x + threadIdx.x;
    if (i >= N_TOT * DD) return;
    dual16[i] = (_Float16)embed[i];
}

// ---------------------------------------------------------------------------
// out[u,j] = sums[user_ids[u]] . sums[item_ids[j]],
// sums[row] = embed[row] + ig0[row] + ig1[row] + ig2[row] (reconstructed).
// 256 blocks: 32 user-groups (32 users) x 8 item-chunks (256 items).
// ---------------------------------------------------------------------------
__global__ __launch_bounds__(256) void k_out(const float* __restrict__ embed,
        const _Float16* __restrict__ ig0, const _Float16* __restrict__ ig1,
        const _Float16* __restrict__ ig2, const int* __restrict__ user_ids,
        const int* __restrict__ item_ids, float* __restrict__ out) {
    __shared__ float uvec[32 * DD];
    int ug = blockIdx.x >> 3;
    int qi = blockIdx.x & 7;
    int ub = ug * 32;
    for (int i = threadIdx.x; i < 32 * DD; i += 256) {
        int uu = i >> 6, d = i & 63;
        size_t o = (size_t)user_ids[ub + uu] * DD + d;
        uvec[i] = embed[o] + (float)ig0[o] + (float)ig1[o] + (float)ig2[o];
    }
    __syncthreads();
    int jbase = qi * 256;
    for (int j = threadIdx.x; j < 256; j += 256) {
        size_t ro = (size_t)item_ids[jbase + j] * DD;
        float acc[32];
#pragma unroll
        for (int u = 0; u < 32; ++u) acc[u] = 0.f;
        for (int d = 0; d < DD; d += 4) {
            float4 ev = *(const float4*)(embed + ro + d);
            half4 h0 = *(const half4*)(ig0 + ro + d);
            half4 h1 = *(const half4*)(ig1 + ro + d);
            half4 h2 = *(const half4*)(ig2 + ro + d);
            float iv0 = ev.x + (float)h0[0] + (float)h1[0] + (float)h2[0];
            float iv1 = ev.y + (float)h0[1] + (float)h1[1] + (float)h2[1];
            float iv2 = ev.z + (float)h0[2] + (float)h1[2] + (float)h2[2];
            float iv3 = ev.w + (float)h0[3] + (float)h1[3] + (float)h2[3];
#pragma unroll
            for (int u = 0; u < 32; ++u) {
                acc[u] = fmaf(iv0, uvec[u * DD + d + 0], acc[u]);
                acc[u] = fmaf(iv1, uvec[u * DD + d + 1], acc[u]);
                acc[u] = fmaf(iv2, uvec[u * DD + d + 2], acc[u]);
                acc[u] = fmaf(iv3, uvec[u * DD + d + 3], acc[u]);
            }
        }
#pragma unroll
        for (int u = 0; u < 32; ++u)
            out[(size_t)(ub + u) * 2048 + jbase + j] = acc[u];
    }
}

extern "C" void kernel_launch(void* const* d_in, const int* in_sizes, int n_in,
                              void* d_out, int out_size, void* d_ws, size_t ws_size,
                              hipStream_t stream) {
    const float* embed   = (const float*)d_in[0];
    const float* rel     = (const float*)d_in[1];
    const float* Wk_w    = (const float*)d_in[2];
    const float* Wk_b    = (const float*)d_in[3];
    const float* Wa      = (const float*)d_in[4];
    const float* Wb      = (const float*)d_in[5];
    const int*   kg_h    = (const int*)d_in[6];
    const int*   kg_t    = (const int*)d_in[7];
    const int*   kg_r    = (const int*)d_in[8];
    const int*   ain_row = (const int*)d_in[9];
    const int*   ain_col = (const int*)d_in[10];
    const float* ain_val = (const float*)d_in[11];
    const int*   user_ids = (const int*)d_in[12];
    const int*   item_ids = (const int*)d_in[13];
    int E_KG = in_sizes[6];
    int E_CF = in_sizes[9];
    int E_TOT = E_KG + E_CF;
    float* out = (float*)d_out;

    int NT  = (E_TOT + SORT_T - 1) / SORT_T;   // phase-1 tiles (733)
    int NTC = NBUKU * NT;                       // scan length (~716K)

    float* ws = (float*)d_ws;
    size_t off = 0;
    float* uvr       = ws + off; off += 16 * 132;
    float* Puv       = ws + off; off += (size_t)N_ENT * 32;
    int*   rowptr    = (int*)(ws + off); off += N_ROWS + 4;
    int*   tilecnt   = (int*)(ws + off); off += (size_t)NTC + 4;
    int*   tilescan  = (int*)(ws + off); off += (size_t)NTC + 4;
    int*   bsum      = (int*)(ws + off); off += 1024;
    int2*  pairbuf   = (int2*)(ws + off); off += 2 * (size_t)E_TOT;   // final (row-sorted)
    _Float16* dual16 = (_Float16*)(ws + off); off += (size_t)N_TOT * DD / 2;
    _Float16* ig16_0 = (_Float16*)(ws + off); off += (size_t)N_TOT * DD / 2;
    _Float16* ig16_1 = (_Float16*)(ws + off); off += (size_t)N_TOT * DD / 2;
    _Float16* ig16_2 = (_Float16*)(ws + off); off += (size_t)N_TOT * DD / 2;
    _Float16* kg16A  = (_Float16*)(ws + off); off += (size_t)N_ENT * DD / 2;
    _Float16* kg16B  = (_Float16*)(ws + off); off += (size_t)N_ENT * DD / 2;
    _Float16* wpack  = (_Float16*)(ws + off); off += 8192 / 2;
    int2*  bufA      = (int2*)kg16A;   // alias: 24MB <= kg16A+kg16B (25.6MB); dead before layer0
    _Float16* ig_l[3] = {ig16_0, ig16_1, ig16_2};

    // --- attention precompute (needed by fused sort+softmax) ---
    hipLaunchKernelGGL(k_rel, dim3(16), dim3(128), 0, stream, Wk_w, Wk_b, rel, uvr);
    hipLaunchKernelGGL(k_proj, dim3((N_ENT + 7) / 8), dim3(256), 0, stream, embed, uvr, Puv);

    // --- binning sort: hist -> scan -> tile scatter -> fine sort + softmax ---
    hipLaunchKernelGGL(k_sort_hist, dim3(NT), dim3(256), 0, stream,
                       kg_h, ain_row, tilecnt, E_KG, E_TOT, NT);
    int nb = (NTC + SCAN_ITEMS - 1) / SCAN_ITEMS;   // ~700
    hipLaunchKernelGGL(k_blocksum, dim3(nb), dim3(SCAN_BLK), 0, stream, tilecnt, bsum, NTC);
    hipLaunchKernelGGL(k_bscan, dim3(1), dim3(1024), 0, stream, bsum, nb, tilescan + NTC);
    hipLaunchKernelGGL(k_scan_apply, dim3(nb), dim3(SCAN_BLK), 0, stream,
                       tilecnt, tilescan, bsum, NTC);
    hipLaunchKernelGGL(k_sort_scatter, dim3(NT), dim3(256), 0, stream,
                       kg_h, kg_t, kg_r, ain_row, ain_col, ain_val, tilescan,
                       bufA, E_KG, E_TOT, NT);
    hipLaunchKernelGGL(k_sort_fine, dim3(NBUKU), dim3(256), 0, stream,
                       tilescan, bufA, pairbuf, rowptr, Puv, uvr, NT);

    hipLaunchKernelGGL(k_init, dim3((N_TOT * DD + 255) / 256), dim3(256), 0, stream,
                       embed, dual16);
    hipLaunchKernelGGL(k_wcvt, dim3(32), dim3(256), 0, stream, Wa, Wb, wpack);

    // --- 3 propagation layers; KG and CF SpMM halves launched separately ---
    const _Float16* cur16 = dual16;       // layer0 KG gather table = fp16 embed
    _Float16* kg16o = kg16A;
    _Float16* kg16alt = kg16B;
    int kg_blocks = ((N_ENT / 2) * 64 + 255) / 256;     // 12500
    int cf_blocks = ((N_TOT / 2) * 64 + 255) / 256;     // 18750
    int ngate = (N_ENT / 16 + 3) / 4;                   // 1563
    int nuc = (N_USR * DD / 8 + 255) / 256;             // 1563
    for (int layer = 0; layer < 3; ++layer) {
        if (layer < 2) {
            hipLaunchKernelGGL(k_spmm_u, dim3(kg_blocks), dim3(256), 0, stream,
                               rowptr, pairbuf, cur16, kg16o, 0, N_ENT, 0x1FFFF);
            hipLaunchKernelGGL(k_spmm_u, dim3(cf_blocks), dim3(256), 0, stream,
                               rowptr, pairbuf, dual16, ig_l[layer], N_ENT, N_ROWS, 0x3FFFF);
            hipLaunchKernelGGL(k_gate3, dim3(ngate + nuc), dim3(256), 0, stream,
                               kg16o, ig_l[layer], wpack, dual16, ngate);
            cur16 = kg16o;
            kg16o = kg16alt;
            kg16alt = (_Float16*)cur16;
        } else {
            hipLaunchKernelGGL(k_spmm_u, dim3(cf_blocks), dim3(256), 0, stream,
                               rowptr, pairbuf, dual16, ig_l[layer], N_ENT, N_ROWS, 0x3FFFF);
        }
    }

    // --- final gather-GEMM 1024 x 2048 x 64 with on-the-fly sums ---
    hipLaunchKernelGGL(k_out, dim3(256), dim3(256), 0, stream,
                       embed, ig16_0, ig16_1, ig16_2, user_ids, item_ids, out);
}